// Round 4
// baseline (1368.419 us; speedup 1.0000x reference)
//
#include <hip/hip_runtime.h>
#include <math.h>

// ---------------- problem constants ----------------
constexpr int B    = 16;
constexpr int L    = 2499;        // conv-stem output length
constexpr int DIN  = 512;         // d_inner
constexpr int NH   = 8;
constexpr int DS   = 128;         // d_state
constexpr int NC   = 20;          // ceil(2499/128) chunks
constexpr int XBCD = 768;         // DIN + 2*DS
constexpr int FLAT = 19992;
constexpr long ROWS = (long)B * L;   // 39984

// ---------------- workspace layout (BYTE offsets) — 121.15 MiB total ----------------
// SEG_S: smalls (dtv/cs/stats/wpk/halo)
constexpr size_t S_DTV  = 0;          // fp32 ROWS*8        = 1,279,488 B
constexpr size_t S_CS   = 1279488;    // fp32 16*8*20*128   = 1,310,720 B
constexpr size_t S_STAT = 2590208;    // fp32 1024          = 4,096 B
constexpr size_t S_WPK  = 2594304;    // fp32 128*256       = 131,072 B
constexpr size_t S_HALO = 2725376;    // bf16 16*20*3*768   = 1,474,560 B  (ends 4,199,936)
constexpr size_t OFF_HT  = 4199936;   // bf16 ROWS*256 = 20,471,808 B  (ht; later yproj)
constexpr size_t OFF_XBC = 24671744;  // bf16 ROWS*768 = 61,415,424 B  (xbc/y; later G fp32 ROWS*128)
constexpr size_t OFF_CBST= 86087168;  // 40,943,616 B: {cb+st half-batch} -> {z bf16} -> {fbuf+MLP}
constexpr size_t CB_OFF  = 0;         // bf16 8*20*128*128 = 5,242,880 B
constexpr size_t ST_OFF  = 5242880;   // bf16 8*20*8*8192  = 20,971,520 B
constexpr size_t Z_OFF   = 0;         // bf16 ROWS*512     = 40,943,616 B
constexpr size_t F_OFF   = 0;         // fp32 16*19992     = 1,279,488 B
constexpr size_t O1_OFF  = 1279488;   // fp32 16*512
constexpr size_t O2_OFF  = 1312256;   // fp32 16*256
constexpr size_t O3_OFF  = 1328640;   // fp32 16*64
constexpr size_t WS_NEEDED = 127030784;

// ---------------- bf16 helpers (storage = unsigned short) ----------------
typedef unsigned short u16;
__device__ __forceinline__ float bf2f(unsigned int u) {
    return __uint_as_float(u << 16);
}
__device__ __forceinline__ u16 f2bf(float f) {
    unsigned int x = __float_as_uint(f);
    unsigned int r = x + 0x7fffu + ((x >> 16) & 1u);
    return (u16)(r >> 16);
}
__device__ __forceinline__ unsigned int pk2(float a, float b) {
    return (unsigned int)f2bf(a) | ((unsigned int)f2bf(b) << 16);
}
__device__ __forceinline__ void ld8bf(const u16* p, float* o) {
    uint4 v = *(const uint4*)p;
    o[0]=bf2f(v.x&0xffffu); o[1]=bf2f(v.x>>16);
    o[2]=bf2f(v.y&0xffffu); o[3]=bf2f(v.y>>16);
    o[4]=bf2f(v.z&0xffffu); o[5]=bf2f(v.z>>16);
    o[6]=bf2f(v.w&0xffffu); o[7]=bf2f(v.w>>16);
}
__device__ __forceinline__ void ld4bf(const u16* p, float* o) {
    uint2 v = *(const uint2*)p;
    o[0]=bf2f(v.x&0xffffu); o[1]=bf2f(v.x>>16);
    o[2]=bf2f(v.y&0xffffu); o[3]=bf2f(v.y>>16);
}
__device__ __forceinline__ void st8bf(u16* p, const float* s) {
    uint4 v;
    v.x = pk2(s[0],s[1]); v.y = pk2(s[2],s[3]);
    v.z = pk2(s[4],s[5]); v.w = pk2(s[6],s[7]);
    *(uint4*)p = v;
}
__device__ __forceinline__ float siluf(float x) { return x / (1.f + expf(-x)); }

// ---------------- zero-init ----------------
__global__ __launch_bounds__(256) void k_zero(float* __restrict__ p, int n) {
    int i = blockIdx.x * 256 + threadIdx.x;
    if (i < n) p[i] = 0.f;
}

// ---------------- GEMM: C[M,N] = act(A)[M,K] @ W[N,K]^T ----------------
// A: bf16 (lda) or fused-im2col from fp32 x. W fp32. C bf16 or fp32.
// FUSE: a = relu(a*scale[k]+shift[k])  (BN+ReLU on the A operand).
template <bool FUSE, bool BF16OUT, bool IM2COL>
__global__ __launch_bounds__(256) void gemm_nt(const void* __restrict__ Ap,
                                               const float* __restrict__ W,
                                               void* __restrict__ Cp,
                                               int M, int N, int K, int lda, int ldc,
                                               const float* __restrict__ scale,
                                               const float* __restrict__ shift) {
    __shared__ float As[16][68];
    __shared__ float Ws[16][68];
    int tid = threadIdx.x;
    int tx = tid & 15, ty = tid >> 4;
    int m0 = blockIdx.x * 64, n0 = blockIdx.y * 64;
    int lr = tid >> 2, lc = (tid & 3) * 4;

    float acc[4][4] = {};

    for (int k0 = 0; k0 < K; k0 += 16) {
        int am = m0 + lr;
        float a4[4] = {0.f, 0.f, 0.f, 0.f};
        if (am < M) {
            if (IM2COL) {
                // stem conv A-row: (b,l) window; col j -> ic=j>>4, k=j&15
                const float* x = (const float*)Ap;
                int b = am / L, l = am - b * L;
                int j = k0 + lc;
                int ic = j >> 4, kk = j & 15;
                float4 v = *(const float4*)(x + ((long)(b * 4 + ic)) * 20000 + l * 8 + kk);
                a4[0] = v.x; a4[1] = v.y; a4[2] = v.z; a4[3] = v.w;
            } else {
                ld4bf((const u16*)Ap + (long)am * lda + k0 + lc, a4);
            }
        }
        if (FUSE) {
            float4 sc = *(const float4*)(scale + k0 + lc);
            float4 sh = *(const float4*)(shift + k0 + lc);
            a4[0] = fmaxf(fmaf(a4[0], sc.x, sh.x), 0.f);
            a4[1] = fmaxf(fmaf(a4[1], sc.y, sh.y), 0.f);
            a4[2] = fmaxf(fmaf(a4[2], sc.z, sh.z), 0.f);
            a4[3] = fmaxf(fmaf(a4[3], sc.w, sh.w), 0.f);
        }
        As[lc + 0][lr] = a4[0]; As[lc + 1][lr] = a4[1];
        As[lc + 2][lr] = a4[2]; As[lc + 3][lr] = a4[3];

        int wn = n0 + lr;
        float4 wv = make_float4(0.f, 0.f, 0.f, 0.f);
        if (wn < N) wv = *(const float4*)(W + (long)wn * K + k0 + lc);
        Ws[lc + 0][lr] = wv.x; Ws[lc + 1][lr] = wv.y;
        Ws[lc + 2][lr] = wv.z; Ws[lc + 3][lr] = wv.w;
        __syncthreads();

        #pragma unroll
        for (int kk = 0; kk < 16; ++kk) {
            float a[4], w[4];
            *(float4*)a = *(const float4*)&As[kk][ty * 4];
            *(float4*)w = *(const float4*)&Ws[kk][tx * 4];
            #pragma unroll
            for (int i = 0; i < 4; ++i)
                #pragma unroll
                for (int j = 0; j < 4; ++j)
                    acc[i][j] = fmaf(a[i], w[j], acc[i][j]);
        }
        __syncthreads();
    }

    #pragma unroll
    for (int i = 0; i < 4; ++i) {
        int m = m0 + ty * 4 + i;
        if (m >= M) continue;
        if (BF16OUT) {
            u16* Cb = (u16*)Cp;
            int n = n0 + tx * 4;          // N is a multiple of 64 in all uses
            *(unsigned int*)(Cb + (long)m * ldc + n)     = pk2(acc[i][0], acc[i][1]);
            *(unsigned int*)(Cb + (long)m * ldc + n + 2) = pk2(acc[i][2], acc[i][3]);
        } else {
            float* Cf = (float*)Cp;
            #pragma unroll
            for (int j = 0; j < 4; ++j) {
                int n = n0 + tx * 4 + j;
                if (n < N) Cf[(long)m * ldc + n] = acc[i][j];
            }
        }
    }
}

// ---------------- BN batch stats (from bf16 h) ----------------
__global__ __launch_bounds__(256) void k_bnstats(const u16* __restrict__ h,
                                                 float* __restrict__ sums,
                                                 float* __restrict__ sumsq) {
    int c = threadIdx.x;
    float s = 0.f, s2 = 0.f;
    for (long r = blockIdx.x; r < ROWS; r += gridDim.x) {
        float v = bf2f(h[r * 256 + c]);
        s += v; s2 += v * v;
    }
    atomicAdd(&sums[c], s);
    atomicAdd(&sumsq[c], s2);
}

__global__ __launch_bounds__(256) void k_bnfinal(const float* __restrict__ sums,
                                                 const float* __restrict__ sumsq,
                                                 const float* __restrict__ bn_w,
                                                 const float* __restrict__ bn_b,
                                                 float* __restrict__ scale,
                                                 float* __restrict__ shift) {
    int c = threadIdx.x;
    float mean = sums[c] / (float)ROWS;
    float var  = sumsq[c] / (float)ROWS - mean * mean;
    float inv  = rsqrtf(var + 1e-5f);
    float sc   = bn_w[c] * inv;
    scale[c] = sc;
    shift[c] = bn_b[c] - mean * sc;
}

// ---------------- dt = softplus(u @ Wdt^T + dt_bias) ----------------
__global__ __launch_bounds__(256) void k_dtproj(const u16* __restrict__ ht,
                                                const float* __restrict__ in_proj_w,
                                                const float* __restrict__ dt_bias,
                                                const float* __restrict__ scale,
                                                const float* __restrict__ shift,
                                                float* __restrict__ dtv) {
    long idx = (long)blockIdx.x * 256 + threadIdx.x;
    if (idx >= ROWS * 8) return;
    int h = (int)(idx & 7);
    long row = idx >> 3;
    const float* wr = in_proj_w + (long)(1280 + h) * 256;
    const u16* ar = ht + row * 256;
    float acc = dt_bias[h];
    for (int k = 0; k < 256; ++k) {
        float u = fmaxf(fmaf(bf2f(ar[k]), scale[k], shift[k]), 0.f);
        acc = fmaf(u, wr[k], acc);
    }
    dtv[idx] = (acc > 20.f) ? acc : log1pf(expf(acc));
}

// ---------------- save 3-row halos at tile boundaries (pre-conv xBC) ----------------
__global__ __launch_bounds__(256) void k_halo(const u16* __restrict__ xbc,
                                              u16* __restrict__ halo) {
    long idx = (long)blockIdx.x * 256 + threadIdx.x;
    if (idx >= 16L * 19 * 3 * 768) return;
    int ch = (int)(idx % 768);
    long t1 = idx / 768;
    int j = (int)(t1 % 3);
    long t2 = t1 / 3;
    int t = (int)(t2 % 19) + 1;       // tiles 1..19
    int b = (int)(t2 / 19);
    halo[(((long)b * 20 + t) * 3 + j) * 768 + ch] =
        xbc[((long)b * L + t * 128 - 3 + j) * 768 + ch];
}

// ---------------- in-place depthwise causal conv1d + SiLU (bf16) ----------------
__global__ __launch_bounds__(256) void k_dwip(u16* __restrict__ xbc,
                                              const u16* __restrict__ halo,
                                              const float* __restrict__ w,
                                              const float* __restrict__ bias) {
    int cg = blockIdx.x % 3;
    int t  = (blockIdx.x / 3) % 20;
    int b  = blockIdx.x / 60;
    int ch = cg * 256 + threadIdx.x;
    int l0 = t * 128, l1 = min(l0 + 128, L);
    float W0 = w[ch*4+0], W1 = w[ch*4+1], W2 = w[ch*4+2], W3 = w[ch*4+3];
    float bs = bias[ch];
    float p0 = 0.f, p1 = 0.f, p2 = 0.f;
    if (t > 0) {
        const u16* hp = halo + (((long)b * 20 + t) * 3) * 768 + ch;
        p0 = bf2f(hp[0]); p1 = bf2f(hp[768]); p2 = bf2f(hp[1536]);
    }
    u16* base = xbc + ((long)b * L + l0) * 768 + ch;
    for (int l = l0; l < l1; ++l) {
        float p3 = bf2f(*base);
        float acc = fmaf(p0, W0, fmaf(p1, W1, fmaf(p2, W2, fmaf(p3, W3, bs))));
        *base = f2bf(siluf(acc));
        p0 = p1; p1 = p2; p2 = p3;
        base += 768;
    }
}

// ---------------- per-chunk inclusive cumsum of dA ----------------
__global__ __launch_bounds__(128) void k_cs(const float* __restrict__ dtv,
                                            const float* __restrict__ A_log,
                                            float* __restrict__ cs) {
    int c = blockIdx.x % NC;
    int h = (blockIdx.x / NC) % NH;
    int b = blockIdx.x / (NC * NH);
    int q = threadIdx.x;
    int lg = c * 128 + q;
    float Av = -expf(A_log[h]);
    float dA = 0.f;
    if (lg < L) dA = dtv[((long)b * L + lg) * 8 + h] * Av;
    __shared__ float buf[128];
    buf[q] = dA;
    __syncthreads();
    for (int off = 1; off < 128; off <<= 1) {
        float add = (q >= off) ? buf[q - off] : 0.f;
        __syncthreads();
        buf[q] += add;
        __syncthreads();
    }
    cs[(long)blockIdx.x * 128 + q] = buf[q];
}

// ---------------- cb[bl,c,l,s] = C[l]·B[s]  (half-batch, local bl) ----------------
__global__ __launch_bounds__(256) void k_cb(const u16* __restrict__ xbc,
                                            u16* __restrict__ cb, int bo) {
    int c = blockIdx.x % NC, bl = blockIdx.x / NC;
    int b = bo + bl;
    long bcl = blockIdx.x;   // bl*NC + c
    __shared__ float Ct[16][132];
    __shared__ float Bt[16][132];
    int tid = threadIdx.x;
    int lrow = tid >> 1, off8 = (tid & 1) * 8;
    int ti = tid >> 4, tj = tid & 15;
    float acc[8][8] = {};
    long baseRow = (long)b * L;

    for (int nk = 0; nk < 128; nk += 16) {
        int lg = c * 128 + lrow;
        float cv[8] = {0,0,0,0,0,0,0,0}, bv[8] = {0,0,0,0,0,0,0,0};
        if (lg < L) {
            const u16* p = xbc + (baseRow + lg) * XBCD;
            ld8bf(p + 640 + nk + off8, cv);
            ld8bf(p + 512 + nk + off8, bv);
        }
        #pragma unroll
        for (int i = 0; i < 8; ++i) { Ct[off8+i][lrow] = cv[i]; Bt[off8+i][lrow] = bv[i]; }
        __syncthreads();
        #pragma unroll
        for (int kk = 0; kk < 16; ++kk) {
            float ci[8], bj[8];
            *(float4*)ci     = *(const float4*)&Ct[kk][ti*8];
            *(float4*)(ci+4) = *(const float4*)&Ct[kk][ti*8+4];
            *(float4*)bj     = *(const float4*)&Bt[kk][tj*8];
            *(float4*)(bj+4) = *(const float4*)&Bt[kk][tj*8+4];
            #pragma unroll
            for (int i = 0; i < 8; ++i)
                #pragma unroll
                for (int j = 0; j < 8; ++j)
                    acc[i][j] = fmaf(ci[i], bj[j], acc[i][j]);
        }
        __syncthreads();
    }
    #pragma unroll
    for (int i = 0; i < 8; ++i)
        st8bf(cb + ((bcl * 128 + ti * 8 + i) * 128 + tj * 8), acc[i]);
}

// ---------------- states S[n,p] = sum_l B[l,n]*exp(csL-cs[l])*xw[l,p] ----------------
__global__ __launch_bounds__(256) void k_states(const u16* __restrict__ xbc,
                                                const float* __restrict__ dtv,
                                                const float* __restrict__ cs,
                                                u16* __restrict__ st, int bo) {
    int h = blockIdx.x & 7;
    int c = (blockIdx.x >> 3) % NC;
    int bl = blockIdx.x / (8 * NC);
    int b = bo + bl;
    __shared__ float Bs[16][132];
    __shared__ float Xs[16][68];
    long csbase = (((long)b * 8 + h) * NC + c) * 128;
    float csLast = cs[csbase + 127];
    int tid = threadIdx.x;
    int tn = tid >> 3, tp = tid & 7;
    int lk = tid >> 4, n8 = (tid & 15) * 8, p4 = (tid & 15) * 4;
    float acc[4][8] = {};

    for (int s0 = 0; s0 < 128; s0 += 16) {
        int lg = c * 128 + s0 + lk;
        float bv[8] = {0,0,0,0,0,0,0,0}, xv[4] = {0,0,0,0};
        if (lg < L) {
            long row = (long)b * L + lg;
            float wl = expf(csLast - cs[csbase + s0 + lk]);
            const u16* p = xbc + row * XBCD;
            ld8bf(p + 512 + n8, bv);
            #pragma unroll
            for (int i = 0; i < 8; ++i) bv[i] *= wl;
            float dt = dtv[row * 8 + h];
            ld4bf(p + h * 64 + p4, xv);
            #pragma unroll
            for (int i = 0; i < 4; ++i) xv[i] *= dt;
        }
        #pragma unroll
        for (int i = 0; i < 8; ++i) Bs[lk][n8+i] = bv[i];
        *(float4*)&Xs[lk][p4] = make_float4(xv[0], xv[1], xv[2], xv[3]);
        __syncthreads();
        #pragma unroll
        for (int kk = 0; kk < 16; ++kk) {
            float a[4], bb[8];
            *(float4*)a      = *(const float4*)&Bs[kk][tn*4];
            *(float4*)bb     = *(const float4*)&Xs[kk][tp*8];
            *(float4*)(bb+4) = *(const float4*)&Xs[kk][tp*8+4];
            #pragma unroll
            for (int i = 0; i < 4; ++i)
                #pragma unroll
                for (int j = 0; j < 8; ++j)
                    acc[i][j] = fmaf(a[i], bb[j], acc[i][j]);
        }
        __syncthreads();
    }
    long base = (long)blockIdx.x * 8192;   // (bl*NC+c)*8+h ordering
    #pragma unroll
    for (int i = 0; i < 4; ++i)
        st8bf(st + base + (tn * 4 + i) * 64 + tp * 8, acc[i]);
}

// ---------------- inter-chunk scan (in place; slot c becomes prev state) ----------------
__global__ __launch_bounds__(256) void k_scan(const float* __restrict__ cs,
                                              u16* __restrict__ st, int bo) {
    int h = blockIdx.x & 7, bl = blockIdx.x >> 3;
    int b = bo + bl;
    int tid = threadIdx.x;
    float carry[32];
    #pragma unroll
    for (int i = 0; i < 32; ++i) carry[i] = 0.f;
    long csbase = ((long)b * 8 + h) * NC * 128;
    for (int c = 0; c < NC; ++c) {
        float cd = expf(cs[csbase + c * 128 + 127]);
        u16* p = st + (((long)bl * NC + c) * 8 + h) * 8192;
        #pragma unroll
        for (int i = 0; i < 32; ++i) {
            int e = tid + i * 256;
            float v = bf2f(p[e]);
            p[e] = f2bf(carry[i]);
            carry[i] = carry[i] * cd + v;
        }
    }
}

// ---------------- Ydiag + Yoff + D-skip -> y overwrites x-part of xbc ----------------
__global__ __launch_bounds__(256) void k_yout(u16* __restrict__ xbc,
                                              const float* __restrict__ dtv,
                                              const float* __restrict__ cs,
                                              const u16* __restrict__ cb,
                                              const u16* __restrict__ st,
                                              const float* __restrict__ Dv, int bo) {
    int h = blockIdx.x & 7;
    int c = (blockIdx.x >> 3) % NC;
    int bl = blockIdx.x / (8 * NC);
    int b = bo + bl;
    long bcl = (long)bl * NC + c;
    __shared__ float As[16][132];
    __shared__ float Bs[16][68];
    __shared__ float csb[128], ecs[128];
    int tid = threadIdx.x;
    long csbase = (((long)b * 8 + h) * NC + c) * 128;
    if (tid < 128) {
        float v = cs[csbase + tid];
        csb[tid] = v;
        ecs[tid] = expf(v);
    }
    __syncthreads();
    int ti = tid >> 3, tp = tid & 7;
    int lrow = tid >> 1, s8 = (tid & 1) * 8;
    int lk = tid >> 4, p4 = (tid & 15) * 4;
    float acc[4][8] = {};

    // phase 1: Ydiag = (mask(l>=s) * cb * exp(cs[l]-cs[s])) @ xw
    for (int s0 = 0; s0 < 128; s0 += 16) {
        {
            float a[8];
            ld8bf(cb + ((bcl * 128 + lrow) * 128 + s0 + s8), a);
            #pragma unroll
            for (int i = 0; i < 8; ++i) {
                int s = s0 + s8 + i;
                float w = (s <= lrow) ? expf(csb[lrow] - csb[s]) : 0.f;
                As[s8 + i][lrow] = a[i] * w;
            }
        }
        {
            int lg = c * 128 + s0 + lk;
            float xv[4] = {0,0,0,0};
            if (lg < L) {
                long row = (long)b * L + lg;
                float dt = dtv[row * 8 + h];
                ld4bf(xbc + row * XBCD + h * 64 + p4, xv);
                #pragma unroll
                for (int i = 0; i < 4; ++i) xv[i] *= dt;
            }
            *(float4*)&Bs[lk][p4] = make_float4(xv[0], xv[1], xv[2], xv[3]);
        }
        __syncthreads();
        #pragma unroll
        for (int kk = 0; kk < 16; ++kk) {
            float a[4], bb[8];
            *(float4*)a      = *(const float4*)&As[kk][ti*4];
            *(float4*)bb     = *(const float4*)&Bs[kk][tp*8];
            *(float4*)(bb+4) = *(const float4*)&Bs[kk][tp*8+4];
            #pragma unroll
            for (int i = 0; i < 4; ++i)
                #pragma unroll
                for (int j = 0; j < 8; ++j)
                    acc[i][j] = fmaf(a[i], bb[j], acc[i][j]);
        }
        __syncthreads();
    }

    // phase 2: Yoff = (C * exp(cs[l])) @ prev
    for (int n0 = 0; n0 < 128; n0 += 16) {
        {
            int lg = c * 128 + lrow;
            float a[8] = {0,0,0,0,0,0,0,0};
            if (lg < L) {
                ld8bf(xbc + ((long)b * L + lg) * XBCD + 640 + n0 + s8, a);
                float e = ecs[lrow];
                #pragma unroll
                for (int i = 0; i < 8; ++i) a[i] *= e;
            }
            #pragma unroll
            for (int i = 0; i < 8; ++i) As[s8 + i][lrow] = a[i];
        }
        {
            int n = n0 + lk;
            float sv[4];
            ld4bf(st + (bcl * 8 + h) * 8192 + (long)n * 64 + p4, sv);
            *(float4*)&Bs[lk][p4] = make_float4(sv[0], sv[1], sv[2], sv[3]);
        }
        __syncthreads();
        #pragma unroll
        for (int kk = 0; kk < 16; ++kk) {
            float a[4], bb[8];
            *(float4*)a      = *(const float4*)&As[kk][ti*4];
            *(float4*)bb     = *(const float4*)&Bs[kk][tp*8];
            *(float4*)(bb+4) = *(const float4*)&Bs[kk][tp*8+4];
            #pragma unroll
            for (int i = 0; i < 4; ++i)
                #pragma unroll
                for (int j = 0; j < 8; ++j)
                    acc[i][j] = fmaf(a[i], bb[j], acc[i][j]);
        }
        __syncthreads();
    }

    // epilogue: + D*xh, overwrite x-part in place (block owns these h-columns)
    float Dh = Dv[h];
    #pragma unroll
    for (int i = 0; i < 4; ++i) {
        int l = ti * 4 + i;
        int lg = c * 128 + l;
        if (lg >= L) continue;
        long row = (long)b * L + lg;
        u16* xp = xbc + row * XBCD + h * 64 + tp * 8;
        float xo[8], yo[8];
        ld8bf(xp, xo);
        #pragma unroll
        for (int j = 0; j < 8; ++j) yo[j] = fmaf(Dh, xo[j], acc[i][j]);
        st8bf(xp, yo);
    }
}

// ---------------- gated RMSNorm (y strided 768 in xbc x-part, in place) ----------------
__global__ __launch_bounds__(256) void k_rmsnorm(u16* __restrict__ y,
                                                 const u16* __restrict__ z,
                                                 const float* __restrict__ nw) {
    long r = blockIdx.x;
    int tid = threadIdx.x;
    float v0 = bf2f(y[r * XBCD + tid]), v1 = bf2f(y[r * XBCD + 256 + tid]);
    float z0 = bf2f(z[r * DIN + tid]),  z1 = bf2f(z[r * DIN + 256 + tid]);
    v0 *= siluf(z0);
    v1 *= siluf(z1);
    __shared__ float red[256];
    red[tid] = v0 * v0 + v1 * v1;
    __syncthreads();
    for (int s = 128; s > 0; s >>= 1) {
        if (tid < s) red[tid] += red[tid + s];
        __syncthreads();
    }
    float sc = rsqrtf(red[0] / 512.f + 1e-5f);
    y[r * XBCD + tid]       = f2bf(v0 * sc * nw[tid]);
    y[r * XBCD + 256 + tid] = f2bf(v1 * sc * nw[256 + tid]);
}

// ---------------- repack conv1_w [8,256,16] -> [128,256] (row = s*16+k) ----------------
__global__ __launch_bounds__(256) void k_wpack(const float* __restrict__ w,
                                               float* __restrict__ wp) {
    int idx = blockIdx.x * 256 + threadIdx.x;
    if (idx >= 8 * 256 * 16) return;
    int k = idx & 15;
    int cidx = (idx >> 4) & 255;
    int s = idx >> 12;
    wp[(s * 16 + k) * 256 + cidx] = w[idx];
}

// ---------------- conv1 combine: f[b,s*L+l] = bias[s] + sum_k G[b,l+k-7,s*16+k] ----------------
__global__ __launch_bounds__(256) void k_conv1(const float* __restrict__ G,
                                               const float* __restrict__ bias,
                                               float* __restrict__ f) {
    long idx = (long)blockIdx.x * 256 + threadIdx.x;
    if (idx >= (long)B * 8 * L) return;
    int l = (int)(idx % L);
    long t = idx / L;
    int s = (int)(t & 7);
    int b = (int)(t >> 3);
    float acc = bias[s];
    #pragma unroll
    for (int k = 0; k < 16; ++k) {
        int ls = l + k - 7;
        if (ls >= 0 && ls < L)
            acc += G[((long)b * L + ls) * 128 + s * 16 + k];
    }
    f[(long)b * FLAT + s * L + l] = acc;
}

// ---------------- MLP ----------------
__global__ __launch_bounds__(256) void k_mlp1(const float* __restrict__ f,
                                              const float* __restrict__ w1,
                                              const float* __restrict__ b1,
                                              float* __restrict__ out1) {
    int n = blockIdx.x;
    int tid = threadIdx.x;
    float acc[16];
    #pragma unroll
    for (int i = 0; i < 16; ++i) acc[i] = 0.f;
    const float* wr = w1 + (long)n * FLAT;
    for (int k = tid; k < FLAT; k += 256) {
        float wv = wr[k];
        #pragma unroll
        for (int b = 0; b < 16; ++b) acc[b] = fmaf(wv, f[(long)b * FLAT + k], acc[b]);
    }
    __shared__ float red[16][257];
    #pragma unroll
    for (int b = 0; b < 16; ++b) red[b][tid] = acc[b];
    __syncthreads();
    for (int s = 128; s > 0; s >>= 1) {
        if (tid < s)
            #pragma unroll
            for (int b = 0; b < 16; ++b) red[b][tid] += red[b][tid + s];
        __syncthreads();
    }
    if (tid < 16) out1[(long)tid * 512 + n] = fmaxf(red[tid][0] + b1[n], 0.f);
}

__global__ __launch_bounds__(256) void k_mlp2(const float* __restrict__ in,
                                              const float* __restrict__ w,
                                              const float* __restrict__ bias,
                                              float* __restrict__ out) {
    int b = blockIdx.x, n = threadIdx.x;
    const float* ir = in + b * 512;
    const float* wr = w + (long)n * 512;
    float acc = 0.f;
    for (int k = 0; k < 512; ++k) acc = fmaf(ir[k], wr[k], acc);
    out[b * 256 + n] = fmaxf(acc + bias[n], 0.f);
}

__global__ __launch_bounds__(64) void k_mlp3(const float* __restrict__ in,
                                             const float* __restrict__ w,
                                             const float* __restrict__ bias,
                                             float* __restrict__ out) {
    int b = blockIdx.x, n = threadIdx.x;
    const float* ir = in + b * 256;
    const float* wr = w + (long)n * 256;
    float acc = 0.f;
    for (int k = 0; k < 256; ++k) acc = fmaf(ir[k], wr[k], acc);
    out[b * 64 + n] = fmaxf(acc + bias[n], 0.f);
}

__global__ __launch_bounds__(64) void k_mlp4(const float* __restrict__ in,
                                             const float* __restrict__ w4,
                                             const float* __restrict__ b4,
                                             float* __restrict__ dout) {
    int b = blockIdx.x, k = threadIdx.x;
    float v = in[b * 64 + k] * w4[k];
    #pragma unroll
    for (int off = 32; off > 0; off >>= 1) v += __shfl_down(v, off);
    if (k == 0) dout[b] = v + b4[0];
}

// ---------------- host launcher ----------------
extern "C" void kernel_launch(void* const* d_in, const int* in_sizes, int n_in,
                              void* d_out, int out_size, void* d_ws, size_t ws_size,
                              hipStream_t stream) {
    (void)in_sizes; (void)n_in; (void)out_size;
    if (ws_size < WS_NEEDED) return;   // bail (wrong answer, not a fault) if scratch too small

    const float* x         = (const float*)d_in[0];
    const float* conv_w    = (const float*)d_in[1];
    // conv_b (d_in[2]) cancels under batch-stat BN — unused
    const float* bn_w      = (const float*)d_in[3];
    const float* bn_b      = (const float*)d_in[4];
    const float* in_proj_w = (const float*)d_in[5];
    const float* conv1d_w  = (const float*)d_in[6];
    const float* conv1d_b  = (const float*)d_in[7];
    const float* dt_bias   = (const float*)d_in[8];
    const float* A_log     = (const float*)d_in[9];
    const float* Dp        = (const float*)d_in[10];
    const float* norm_w    = (const float*)d_in[11];
    const float* out_proj_w= (const float*)d_in[12];
    const float* conv1_w   = (const float*)d_in[13];
    const float* conv1_b   = (const float*)d_in[14];
    const float* w1 = (const float*)d_in[15]; const float* b1 = (const float*)d_in[16];
    const float* w2 = (const float*)d_in[17]; const float* b2 = (const float*)d_in[18];
    const float* w3 = (const float*)d_in[19]; const float* b3 = (const float*)d_in[20];
    const float* w4 = (const float*)d_in[21]; const float* b4 = (const float*)d_in[22];

    char* base = (char*)d_ws;
    float* dtv  = (float*)(base + S_DTV);
    float* cs   = (float*)(base + S_CS);
    float* sums = (float*)(base + S_STAT);
    float* sumsq= sums + 256;
    float* scale= sums + 512;
    float* shift= sums + 768;
    float* wpk  = (float*)(base + S_WPK);
    u16*   halo = (u16*)(base + S_HALO);
    u16*   ht   = (u16*)(base + OFF_HT);     // later yproj
    u16*   xbc  = (u16*)(base + OFF_XBC);    // xBC -> y(x-part); later G (fp32)
    u16*   cb   = (u16*)(base + OFF_CBST + CB_OFF);
    u16*   st   = (u16*)(base + OFF_CBST + ST_OFF);
    u16*   zb   = (u16*)(base + OFF_CBST + Z_OFF);   // after SSD
    float* G    = (float*)(base + OFF_XBC);          // after out_proj
    float* fbuf = (float*)(base + OFF_CBST + F_OFF); // after rmsnorm
    float* o1   = (float*)(base + OFF_CBST + O1_OFF);
    float* o2   = (float*)(base + OFF_CBST + O2_OFF);
    float* o3   = (float*)(base + OFF_CBST + O3_OFF);
    u16*   yproj= ht;

    // 1-2. stem conv as fused-im2col GEMM (conv bias cancels in BN)
    gemm_nt<false, true, true><<<dim3(625, 4), 256, 0, stream>>>(
        x, conv_w, ht, (int)ROWS, 256, 64, 0, 256, nullptr, nullptr);

    // 3. BN batch stats
    k_zero<<<2, 256, 0, stream>>>(sums, 512);
    k_bnstats<<<256, 256, 0, stream>>>(ht, sums, sumsq);
    k_bnfinal<<<1, 256, 0, stream>>>(sums, sumsq, bn_w, bn_b, scale, shift);

    // 4. xBC projection (fused BN+ReLU on A); dt projection
    gemm_nt<true, true, false><<<dim3(625, 12), 256, 0, stream>>>(
        ht, in_proj_w + 512L * 256, xbc, (int)ROWS, 768, 256, 256, 768, scale, shift);
    k_dtproj<<<1250, 256, 0, stream>>>(ht, in_proj_w, dt_bias, scale, shift, dtv);

    // 5. in-place depthwise conv + SiLU (halo first); per-chunk cumsum
    k_halo<<<2736, 256, 0, stream>>>(xbc, halo);
    k_dwip<<<960, 256, 0, stream>>>(xbc, halo, conv1d_w, conv1d_b);
    k_cs<<<2560, 128, 0, stream>>>(dtv, A_log, cs);

    // 6. SSD in two half-batches (cb/st buffers sized for 8 batches)
    for (int bh = 0; bh < 2; ++bh) {
        int bo = bh * 8;
        k_cb<<<160, 256, 0, stream>>>(xbc, cb, bo);
        k_states<<<1280, 256, 0, stream>>>(xbc, dtv, cs, st, bo);
        k_scan<<<64, 256, 0, stream>>>(cs, st, bo);
        k_yout<<<1280, 256, 0, stream>>>(xbc, dtv, cs, cb, st, Dp, bo);
    }

    // 6.9. z projection (into the dead cb+st segment)
    gemm_nt<true, true, false><<<dim3(625, 8), 256, 0, stream>>>(
        ht, in_proj_w, zb, (int)ROWS, 512, 256, 256, 512, scale, shift);

    // 7-8. gated RMSNorm (y strided in xbc) + out_proj (ht segment becomes yproj)
    k_rmsnorm<<<39984, 256, 0, stream>>>(xbc, zb, norm_w);
    gemm_nt<false, true, false><<<dim3(625, 4), 256, 0, stream>>>(
        xbc, out_proj_w, yproj, (int)ROWS, 256, 512, 768, 256, nullptr, nullptr);

    // 9. conv1 as GEMM (G fp32 overwrites xbc segment) + shifted gather
    k_wpack<<<128, 256, 0, stream>>>(conv1_w, wpk);
    gemm_nt<false, false, false><<<dim3(625, 2), 256, 0, stream>>>(
        yproj, wpk, G, (int)ROWS, 128, 256, 256, 128, nullptr, nullptr);
    k_conv1<<<1250, 256, 0, stream>>>(G, conv1_b, fbuf);

    // 10. MLP head
    k_mlp1<<<512, 256, 0, stream>>>(fbuf, w1, b1, o1);
    k_mlp2<<<16, 256, 0, stream>>>(o1, w2, b2, o2);
    k_mlp3<<<16, 64, 0, stream>>>(o2, w3, b3, o3);
    k_mlp4<<<16, 64, 0, stream>>>(o3, w4, b4, (float*)d_out);
}

// Round 5
// 915.478 us; speedup vs baseline: 1.4948x; 1.4948x over previous
//
#include <hip/hip_runtime.h>
#include <math.h>

// ---------------- problem constants ----------------
constexpr int B    = 16;
constexpr int L    = 2499;        // conv-stem output length
constexpr int DIN  = 512;         // d_inner
constexpr int NH   = 8;
constexpr int DS   = 128;         // d_state
constexpr int NC   = 20;          // ceil(2499/128) chunks
constexpr int XBCD = 768;         // DIN + 2*DS
constexpr int FLAT = 19992;
constexpr long ROWS = (long)B * L;   // 39984

// ---------------- workspace layout (BYTE offsets) — identical to passing round ----------------
constexpr size_t S_DTV  = 0;          // fp32 ROWS*8        = 1,279,488 B
constexpr size_t S_CS   = 1279488;    // fp32 16*8*20*128   = 1,310,720 B
constexpr size_t S_STAT = 2590208;    // fp32 1024
constexpr size_t S_WPK  = 2594304;    // 131,072 B: conv_w bf16 (32,768 B used)
constexpr size_t S_HALO = 2725376;    // 1,474,560 B: xbcw-bf16 -> halo -> zw/outw/wpk bf16
constexpr size_t OFF_HT  = 4199936;   // bf16 ROWS*256 (ht -> u -> yproj)
constexpr size_t OFF_XBC = 24671744;  // bf16 ROWS*768 (xbc/y); later G fp32 ROWS*128
constexpr size_t OFF_CBST= 86087168;  // cb+st -> z bf16 -> fbuf+MLP
constexpr size_t CB_OFF  = 0;         // bf16 8*20*128*128
constexpr size_t ST_OFF  = 5242880;   // bf16 8*20*8*8192
constexpr size_t Z_OFF   = 0;         // bf16 ROWS*512
constexpr size_t F_OFF   = 0;         // fp32 16*19992
constexpr size_t O1_OFF  = 1279488;
constexpr size_t O2_OFF  = 1312256;
constexpr size_t O3_OFF  = 1328640;
constexpr size_t WS_NEEDED = 127030784;

// ---------------- bf16 helpers ----------------
typedef unsigned short u16;
typedef __attribute__((ext_vector_type(8))) short bf16x8;
typedef __attribute__((ext_vector_type(4))) float f32x4;

__device__ __forceinline__ float bf2f(unsigned int u) {
    return __uint_as_float(u << 16);
}
__device__ __forceinline__ u16 f2bf(float f) {
    unsigned int x = __float_as_uint(f);
    unsigned int r = x + 0x7fffu + ((x >> 16) & 1u);
    return (u16)(r >> 16);
}
__device__ __forceinline__ unsigned int pk2(float a, float b) {
    return (unsigned int)f2bf(a) | ((unsigned int)f2bf(b) << 16);
}
__device__ __forceinline__ void ld8bf(const u16* p, float* o) {
    uint4 v = *(const uint4*)p;
    o[0]=bf2f(v.x&0xffffu); o[1]=bf2f(v.x>>16);
    o[2]=bf2f(v.y&0xffffu); o[3]=bf2f(v.y>>16);
    o[4]=bf2f(v.z&0xffffu); o[5]=bf2f(v.z>>16);
    o[6]=bf2f(v.w&0xffffu); o[7]=bf2f(v.w>>16);
}
__device__ __forceinline__ void ld4bf(const u16* p, float* o) {
    uint2 v = *(const uint2*)p;
    o[0]=bf2f(v.x&0xffffu); o[1]=bf2f(v.x>>16);
    o[2]=bf2f(v.y&0xffffu); o[3]=bf2f(v.y>>16);
}
__device__ __forceinline__ void st8bf(u16* p, const float* s) {
    uint4 v;
    v.x = pk2(s[0],s[1]); v.y = pk2(s[2],s[3]);
    v.z = pk2(s[4],s[5]); v.w = pk2(s[6],s[7]);
    *(uint4*)p = v;
}
__device__ __forceinline__ float siluf(float x) { return x / (1.f + expf(-x)); }

// ---------------- zero-init ----------------
__global__ __launch_bounds__(256) void k_zero(float* __restrict__ p, int n) {
    int i = blockIdx.x * 256 + threadIdx.x;
    if (i < n) p[i] = 0.f;
}

// ---------------- fp32 -> bf16 weight convert ----------------
__global__ __launch_bounds__(256) void k_wcvt(const float* __restrict__ src,
                                              u16* __restrict__ dst, int n) {
    int i = blockIdx.x * 256 + threadIdx.x;
    if (i < n) dst[i] = f2bf(src[i]);
}

// ---------------- MFMA GEMM: C[M,N] = A[M,K](bf16) @ Wb[N,K](bf16)^T ----------------
// 128x128 tile, BK=32, 4 waves (each 64x64 via 4x4 frags of 16x16x32).
// LDS rows padded to 40 u16 (80 B) -> 2-way bank aliasing on ds_read_b128 (free).
template <bool IM2COL, bool BF16OUT>
__global__ __launch_bounds__(256) void gemm_mfma(const void* __restrict__ Ap,
                                                 const u16* __restrict__ Wb,
                                                 void* __restrict__ Cp,
                                                 int M, int N, int K, int lda, int ldc) {
    __shared__ u16 Als[128 * 40];
    __shared__ u16 Bls[128 * 40];
    int tid = threadIdx.x;
    int wave = tid >> 6, lane = tid & 63;
    int wr = wave >> 1, wc = wave & 1;
    int m0 = blockIdx.x * 128, n0 = blockIdx.y * 128;
    int l15 = lane & 15, l4 = lane >> 4;
    int srow = tid >> 1, scol = (tid & 1) * 16;

    f32x4 acc[4][4];
    #pragma unroll
    for (int i = 0; i < 4; ++i)
        #pragma unroll
        for (int j = 0; j < 4; ++j)
            acc[i][j] = (f32x4){0.f, 0.f, 0.f, 0.f};

    for (int k0 = 0; k0 < K; k0 += 32) {
        // stage A tile [128][32]
        {
            int am = m0 + srow;
            uint4 v0 = {0,0,0,0}, v1 = {0,0,0,0};
            if (am < M) {
                if (IM2COL) {
                    // stem im2col: row (b,l), 16 cols = one input channel's window
                    const float* x = (const float*)Ap;
                    int b = am / L, l = am - b * L;
                    int ic = (k0 + scol) >> 4;
                    const float* px = x + ((long)(b * 4 + ic)) * 20000 + l * 8;
                    float4 f0 = *(const float4*)(px);
                    float4 f1 = *(const float4*)(px + 4);
                    float4 f2 = *(const float4*)(px + 8);
                    float4 f3 = *(const float4*)(px + 12);
                    v0.x = pk2(f0.x,f0.y); v0.y = pk2(f0.z,f0.w);
                    v0.z = pk2(f1.x,f1.y); v0.w = pk2(f1.z,f1.w);
                    v1.x = pk2(f2.x,f2.y); v1.y = pk2(f2.z,f2.w);
                    v1.z = pk2(f3.x,f3.y); v1.w = pk2(f3.z,f3.w);
                } else {
                    const u16* pa = (const u16*)Ap + (long)am * lda + k0 + scol;
                    v0 = *(const uint4*)pa;
                    v1 = *(const uint4*)(pa + 8);
                }
            }
            *(uint4*)&Als[srow * 40 + scol]     = v0;
            *(uint4*)&Als[srow * 40 + scol + 8] = v1;
        }
        // stage B tile [128][32] from W rows (N tiles are exact)
        {
            const u16* pw = Wb + (long)(n0 + srow) * K + k0 + scol;
            *(uint4*)&Bls[srow * 40 + scol]     = *(const uint4*)pw;
            *(uint4*)&Bls[srow * 40 + scol + 8] = *(const uint4*)(pw + 8);
        }
        __syncthreads();

        bf16x8 af[4], bfr[4];
        #pragma unroll
        for (int i = 0; i < 4; ++i) {
            af[i]  = *(const bf16x8*)&Als[(wr * 64 + i * 16 + l15) * 40 + l4 * 8];
            bfr[i] = *(const bf16x8*)&Bls[(wc * 64 + i * 16 + l15) * 40 + l4 * 8];
        }
        #pragma unroll
        for (int i = 0; i < 4; ++i)
            #pragma unroll
            for (int j = 0; j < 4; ++j)
                acc[i][j] = __builtin_amdgcn_mfma_f32_16x16x32_bf16(
                    af[i], bfr[j], acc[i][j], 0, 0, 0);
        __syncthreads();
    }

    // store: D[row=(l>>4)*4+r][col=l&15] per 16x16 frag
    #pragma unroll
    for (int i = 0; i < 4; ++i) {
        #pragma unroll
        for (int j = 0; j < 4; ++j) {
            int n = n0 + wc * 64 + j * 16 + l15;
            #pragma unroll
            for (int r = 0; r < 4; ++r) {
                int m = m0 + wr * 64 + i * 16 + l4 * 4 + r;
                if (m < M) {
                    if (BF16OUT) ((u16*)Cp)[(long)m * ldc + n] = f2bf(acc[i][j][r]);
                    else         ((float*)Cp)[(long)m * ldc + n] = acc[i][j][r];
                }
            }
        }
    }
}

// ---------------- BN batch stats (from bf16 h) ----------------
__global__ __launch_bounds__(256) void k_bnstats(const u16* __restrict__ h,
                                                 float* __restrict__ sums,
                                                 float* __restrict__ sumsq) {
    int c = threadIdx.x;
    float s = 0.f, s2 = 0.f;
    for (long r = blockIdx.x; r < ROWS; r += gridDim.x) {
        float v = bf2f(h[r * 256 + c]);
        s += v; s2 += v * v;
    }
    atomicAdd(&sums[c], s);
    atomicAdd(&sumsq[c], s2);
}

__global__ __launch_bounds__(256) void k_bnfinal(const float* __restrict__ sums,
                                                 const float* __restrict__ sumsq,
                                                 const float* __restrict__ bn_w,
                                                 const float* __restrict__ bn_b,
                                                 float* __restrict__ scale,
                                                 float* __restrict__ shift) {
    int c = threadIdx.x;
    float mean = sums[c] / (float)ROWS;
    float var  = sumsq[c] / (float)ROWS - mean * mean;
    float inv  = rsqrtf(var + 1e-5f);
    float sc   = bn_w[c] * inv;
    scale[c] = sc;
    shift[c] = bn_b[c] - mean * sc;
}

// ---------------- in-place BN+ReLU: ht -> u = relu(scale*ht+shift) ----------------
__global__ __launch_bounds__(256) void k_bnapply(u16* __restrict__ ht,
                                                 const float* __restrict__ scale,
                                                 const float* __restrict__ shift) {
    long i = ((long)blockIdx.x * 256 + threadIdx.x) * 8;   // 4998 blocks exact
    int c = (int)(i & 255);
    float v[8];
    ld8bf(ht + i, v);
    float4 s0 = *(const float4*)(scale + c), s1 = *(const float4*)(scale + c + 4);
    float4 h0 = *(const float4*)(shift + c), h1 = *(const float4*)(shift + c + 4);
    v[0]=fmaxf(fmaf(v[0],s0.x,h0.x),0.f); v[1]=fmaxf(fmaf(v[1],s0.y,h0.y),0.f);
    v[2]=fmaxf(fmaf(v[2],s0.z,h0.z),0.f); v[3]=fmaxf(fmaf(v[3],s0.w,h0.w),0.f);
    v[4]=fmaxf(fmaf(v[4],s1.x,h1.x),0.f); v[5]=fmaxf(fmaf(v[5],s1.y,h1.y),0.f);
    v[6]=fmaxf(fmaf(v[6],s1.z,h1.z),0.f); v[7]=fmaxf(fmaf(v[7],s1.w,h1.w),0.f);
    st8bf(ht + i, v);
}

// ---------------- dt = softplus(u @ Wdt^T + dt_bias) ----------------
__global__ __launch_bounds__(256) void k_dtproj(const u16* __restrict__ u,
                                                const float* __restrict__ in_proj_w,
                                                const float* __restrict__ dt_bias,
                                                float* __restrict__ dtv) {
    long idx = (long)blockIdx.x * 256 + threadIdx.x;
    if (idx >= ROWS * 8) return;
    int h = (int)(idx & 7);
    long row = idx >> 3;
    const float* wr = in_proj_w + (long)(1280 + h) * 256;
    const u16* ar = u + row * 256;
    float acc = dt_bias[h];
    for (int k = 0; k < 256; ++k)
        acc = fmaf(bf2f(ar[k]), wr[k], acc);
    dtv[idx] = (acc > 20.f) ? acc : log1pf(expf(acc));
}

// ---------------- save 3-row halos at tile boundaries (pre-conv xBC) ----------------
__global__ __launch_bounds__(256) void k_halo(const u16* __restrict__ xbc,
                                              u16* __restrict__ halo) {
    long idx = (long)blockIdx.x * 256 + threadIdx.x;
    if (idx >= 16L * 19 * 3 * 768) return;
    int ch = (int)(idx % 768);
    long t1 = idx / 768;
    int j = (int)(t1 % 3);
    long t2 = t1 / 3;
    int t = (int)(t2 % 19) + 1;
    int b = (int)(t2 / 19);
    halo[(((long)b * 20 + t) * 3 + j) * 768 + ch] =
        xbc[((long)b * L + t * 128 - 3 + j) * 768 + ch];
}

// ---------------- in-place depthwise causal conv1d + SiLU (bf16) ----------------
__global__ __launch_bounds__(256) void k_dwip(u16* __restrict__ xbc,
                                              const u16* __restrict__ halo,
                                              const float* __restrict__ w,
                                              const float* __restrict__ bias) {
    int cg = blockIdx.x % 3;
    int t  = (blockIdx.x / 3) % 20;
    int b  = blockIdx.x / 60;
    int ch = cg * 256 + threadIdx.x;
    int l0 = t * 128, l1 = min(l0 + 128, L);
    float W0 = w[ch*4+0], W1 = w[ch*4+1], W2 = w[ch*4+2], W3 = w[ch*4+3];
    float bs = bias[ch];
    float p0 = 0.f, p1 = 0.f, p2 = 0.f;
    if (t > 0) {
        const u16* hp = halo + (((long)b * 20 + t) * 3) * 768 + ch;
        p0 = bf2f(hp[0]); p1 = bf2f(hp[768]); p2 = bf2f(hp[1536]);
    }
    u16* base = xbc + ((long)b * L + l0) * 768 + ch;
    for (int l = l0; l < l1; ++l) {
        float p3 = bf2f(*base);
        float acc = fmaf(p0, W0, fmaf(p1, W1, fmaf(p2, W2, fmaf(p3, W3, bs))));
        *base = f2bf(siluf(acc));
        p0 = p1; p1 = p2; p2 = p3;
        base += 768;
    }
}

// ---------------- per-chunk inclusive cumsum of dA ----------------
__global__ __launch_bounds__(128) void k_cs(const float* __restrict__ dtv,
                                            const float* __restrict__ A_log,
                                            float* __restrict__ cs) {
    int c = blockIdx.x % NC;
    int h = (blockIdx.x / NC) % NH;
    int b = blockIdx.x / (NC * NH);
    int q = threadIdx.x;
    int lg = c * 128 + q;
    float Av = -expf(A_log[h]);
    float dA = 0.f;
    if (lg < L) dA = dtv[((long)b * L + lg) * 8 + h] * Av;
    __shared__ float buf[128];
    buf[q] = dA;
    __syncthreads();
    for (int off = 1; off < 128; off <<= 1) {
        float add = (q >= off) ? buf[q - off] : 0.f;
        __syncthreads();
        buf[q] += add;
        __syncthreads();
    }
    cs[(long)blockIdx.x * 128 + q] = buf[q];
}

// ---------------- cb[bl,c,l,s] = C[l]·B[s]  (half-batch, local bl) ----------------
__global__ __launch_bounds__(256) void k_cb(const u16* __restrict__ xbc,
                                            u16* __restrict__ cb, int bo) {
    int c = blockIdx.x % NC, bl = blockIdx.x / NC;
    int b = bo + bl;
    long bcl = blockIdx.x;
    __shared__ float Ct[16][132];
    __shared__ float Bt[16][132];
    int tid = threadIdx.x;
    int lrow = tid >> 1, off8 = (tid & 1) * 8;
    int ti = tid >> 4, tj = tid & 15;
    float acc[8][8] = {};
    long baseRow = (long)b * L;

    for (int nk = 0; nk < 128; nk += 16) {
        int lg = c * 128 + lrow;
        float cv[8] = {0,0,0,0,0,0,0,0}, bv[8] = {0,0,0,0,0,0,0,0};
        if (lg < L) {
            const u16* p = xbc + (baseRow + lg) * XBCD;
            ld8bf(p + 640 + nk + off8, cv);
            ld8bf(p + 512 + nk + off8, bv);
        }
        #pragma unroll
        for (int i = 0; i < 8; ++i) { Ct[off8+i][lrow] = cv[i]; Bt[off8+i][lrow] = bv[i]; }
        __syncthreads();
        #pragma unroll
        for (int kk = 0; kk < 16; ++kk) {
            float ci[8], bj[8];
            *(float4*)ci     = *(const float4*)&Ct[kk][ti*8];
            *(float4*)(ci+4) = *(const float4*)&Ct[kk][ti*8+4];
            *(float4*)bj     = *(const float4*)&Bt[kk][tj*8];
            *(float4*)(bj+4) = *(const float4*)&Bt[kk][tj*8+4];
            #pragma unroll
            for (int i = 0; i < 8; ++i)
                #pragma unroll
                for (int j = 0; j < 8; ++j)
                    acc[i][j] = fmaf(ci[i], bj[j], acc[i][j]);
        }
        __syncthreads();
    }
    #pragma unroll
    for (int i = 0; i < 8; ++i)
        st8bf(cb + ((bcl * 128 + ti * 8 + i) * 128 + tj * 8), acc[i]);
}

// ---------------- states S[n,p] = sum_l B[l,n]*exp(csL-cs[l])*xw[l,p] ----------------
__global__ __launch_bounds__(256) void k_states(const u16* __restrict__ xbc,
                                                const float* __restrict__ dtv,
                                                const float* __restrict__ cs,
                                                u16* __restrict__ st, int bo) {
    int h = blockIdx.x & 7;
    int c = (blockIdx.x >> 3) % NC;
    int bl = blockIdx.x / (8 * NC);
    int b = bo + bl;
    __shared__ float Bs[16][132];
    __shared__ float Xs[16][68];
    long csbase = (((long)b * 8 + h) * NC + c) * 128;
    float csLast = cs[csbase + 127];
    int tid = threadIdx.x;
    int tn = tid >> 3, tp = tid & 7;
    int lk = tid >> 4, n8 = (tid & 15) * 8, p4 = (tid & 15) * 4;
    float acc[4][8] = {};

    for (int s0 = 0; s0 < 128; s0 += 16) {
        int lg = c * 128 + s0 + lk;
        float bv[8] = {0,0,0,0,0,0,0,0}, xv[4] = {0,0,0,0};
        if (lg < L) {
            long row = (long)b * L + lg;
            float wl = expf(csLast - cs[csbase + s0 + lk]);
            const u16* p = xbc + row * XBCD;
            ld8bf(p + 512 + n8, bv);
            #pragma unroll
            for (int i = 0; i < 8; ++i) bv[i] *= wl;
            float dt = dtv[row * 8 + h];
            ld4bf(p + h * 64 + p4, xv);
            #pragma unroll
            for (int i = 0; i < 4; ++i) xv[i] *= dt;
        }
        #pragma unroll
        for (int i = 0; i < 8; ++i) Bs[lk][n8+i] = bv[i];
        *(float4*)&Xs[lk][p4] = make_float4(xv[0], xv[1], xv[2], xv[3]);
        __syncthreads();
        #pragma unroll
        for (int kk = 0; kk < 16; ++kk) {
            float a[4], bb[8];
            *(float4*)a      = *(const float4*)&Bs[kk][tn*4];
            *(float4*)bb     = *(const float4*)&Xs[kk][tp*8];
            *(float4*)(bb+4) = *(const float4*)&Xs[kk][tp*8+4];
            #pragma unroll
            for (int i = 0; i < 4; ++i)
                #pragma unroll
                for (int j = 0; j < 8; ++j)
                    acc[i][j] = fmaf(a[i], bb[j], acc[i][j]);
        }
        __syncthreads();
    }
    long base = (long)blockIdx.x * 8192;
    #pragma unroll
    for (int i = 0; i < 4; ++i)
        st8bf(st + base + (tn * 4 + i) * 64 + tp * 8, acc[i]);
}

// ---------------- inter-chunk scan ----------------
__global__ __launch_bounds__(256) void k_scan(const float* __restrict__ cs,
                                              u16* __restrict__ st, int bo) {
    int h = blockIdx.x & 7, bl = blockIdx.x >> 3;
    int b = bo + bl;
    int tid = threadIdx.x;
    float carry[32];
    #pragma unroll
    for (int i = 0; i < 32; ++i) carry[i] = 0.f;
    long csbase = ((long)b * 8 + h) * NC * 128;
    for (int c = 0; c < NC; ++c) {
        float cd = expf(cs[csbase + c * 128 + 127]);
        u16* p = st + (((long)bl * NC + c) * 8 + h) * 8192;
        #pragma unroll
        for (int i = 0; i < 32; ++i) {
            int e = tid + i * 256;
            float v = bf2f(p[e]);
            p[e] = f2bf(carry[i]);
            carry[i] = carry[i] * cd + v;
        }
    }
}

// ---------------- Ydiag + Yoff + D-skip -> y overwrites x-part of xbc ----------------
__global__ __launch_bounds__(256) void k_yout(u16* __restrict__ xbc,
                                              const float* __restrict__ dtv,
                                              const float* __restrict__ cs,
                                              const u16* __restrict__ cb,
                                              const u16* __restrict__ st,
                                              const float* __restrict__ Dv, int bo) {
    int h = blockIdx.x & 7;
    int c = (blockIdx.x >> 3) % NC;
    int bl = blockIdx.x / (8 * NC);
    int b = bo + bl;
    long bcl = (long)bl * NC + c;
    __shared__ float As[16][132];
    __shared__ float Bs[16][68];
    __shared__ float csb[128], ecs[128];
    int tid = threadIdx.x;
    long csbase = (((long)b * 8 + h) * NC + c) * 128;
    if (tid < 128) {
        float v = cs[csbase + tid];
        csb[tid] = v;
        ecs[tid] = expf(v);
    }
    __syncthreads();
    int ti = tid >> 3, tp = tid & 7;
    int lrow = tid >> 1, s8 = (tid & 1) * 8;
    int lk = tid >> 4, p4 = (tid & 15) * 4;
    float acc[4][8] = {};

    for (int s0 = 0; s0 < 128; s0 += 16) {
        {
            float a[8];
            ld8bf(cb + ((bcl * 128 + lrow) * 128 + s0 + s8), a);
            #pragma unroll
            for (int i = 0; i < 8; ++i) {
                int s = s0 + s8 + i;
                float w = (s <= lrow) ? expf(csb[lrow] - csb[s]) : 0.f;
                As[s8 + i][lrow] = a[i] * w;
            }
        }
        {
            int lg = c * 128 + s0 + lk;
            float xv[4] = {0,0,0,0};
            if (lg < L) {
                long row = (long)b * L + lg;
                float dt = dtv[row * 8 + h];
                ld4bf(xbc + row * XBCD + h * 64 + p4, xv);
                #pragma unroll
                for (int i = 0; i < 4; ++i) xv[i] *= dt;
            }
            *(float4*)&Bs[lk][p4] = make_float4(xv[0], xv[1], xv[2], xv[3]);
        }
        __syncthreads();
        #pragma unroll
        for (int kk = 0; kk < 16; ++kk) {
            float a[4], bb[8];
            *(float4*)a      = *(const float4*)&As[kk][ti*4];
            *(float4*)bb     = *(const float4*)&Bs[kk][tp*8];
            *(float4*)(bb+4) = *(const float4*)&Bs[kk][tp*8+4];
            #pragma unroll
            for (int i = 0; i < 4; ++i)
                #pragma unroll
                for (int j = 0; j < 8; ++j)
                    acc[i][j] = fmaf(a[i], bb[j], acc[i][j]);
        }
        __syncthreads();
    }

    for (int n0 = 0; n0 < 128; n0 += 16) {
        {
            int lg = c * 128 + lrow;
            float a[8] = {0,0,0,0,0,0,0,0};
            if (lg < L) {
                ld8bf(xbc + ((long)b * L + lg) * XBCD + 640 + n0 + s8, a);
                float e = ecs[lrow];
                #pragma unroll
                for (int i = 0; i < 8; ++i) a[i] *= e;
            }
            #pragma unroll
            for (int i = 0; i < 8; ++i) As[s8 + i][lrow] = a[i];
        }
        {
            int n = n0 + lk;
            float sv[4];
            ld4bf(st + (bcl * 8 + h) * 8192 + (long)n * 64 + p4, sv);
            *(float4*)&Bs[lk][p4] = make_float4(sv[0], sv[1], sv[2], sv[3]);
        }
        __syncthreads();
        #pragma unroll
        for (int kk = 0; kk < 16; ++kk) {
            float a[4], bb[8];
            *(float4*)a      = *(const float4*)&As[kk][ti*4];
            *(float4*)bb     = *(const float4*)&Bs[kk][tp*8];
            *(float4*)(bb+4) = *(const float4*)&Bs[kk][tp*8+4];
            #pragma unroll
            for (int i = 0; i < 4; ++i)
                #pragma unroll
                for (int j = 0; j < 8; ++j)
                    acc[i][j] = fmaf(a[i], bb[j], acc[i][j]);
        }
        __syncthreads();
    }

    float Dh = Dv[h];
    #pragma unroll
    for (int i = 0; i < 4; ++i) {
        int l = ti * 4 + i;
        int lg = c * 128 + l;
        if (lg >= L) continue;
        long row = (long)b * L + lg;
        u16* xp = xbc + row * XBCD + h * 64 + tp * 8;
        float xo[8], yo[8];
        ld8bf(xp, xo);
        #pragma unroll
        for (int j = 0; j < 8; ++j) yo[j] = fmaf(Dh, xo[j], acc[i][j]);
        st8bf(xp, yo);
    }
}

// ---------------- gated RMSNorm (y strided 768 in xbc x-part, in place) ----------------
__global__ __launch_bounds__(256) void k_rmsnorm(u16* __restrict__ y,
                                                 const u16* __restrict__ z,
                                                 const float* __restrict__ nw) {
    long r = blockIdx.x;
    int tid = threadIdx.x;
    float v0 = bf2f(y[r * XBCD + tid]), v1 = bf2f(y[r * XBCD + 256 + tid]);
    float z0 = bf2f(z[r * DIN + tid]),  z1 = bf2f(z[r * DIN + 256 + tid]);
    v0 *= siluf(z0);
    v1 *= siluf(z1);
    __shared__ float red[256];
    red[tid] = v0 * v0 + v1 * v1;
    __syncthreads();
    for (int s = 128; s > 0; s >>= 1) {
        if (tid < s) red[tid] += red[tid + s];
        __syncthreads();
    }
    float sc = rsqrtf(red[0] / 512.f + 1e-5f);
    y[r * XBCD + tid]       = f2bf(v0 * sc * nw[tid]);
    y[r * XBCD + 256 + tid] = f2bf(v1 * sc * nw[256 + tid]);
}

// ---------------- repack conv1_w [8,256,16] -> bf16 [128,256] (row = s*16+k) ----------------
__global__ __launch_bounds__(256) void k_wpack(const float* __restrict__ w,
                                               u16* __restrict__ wp) {
    int idx = blockIdx.x * 256 + threadIdx.x;
    if (idx >= 8 * 256 * 16) return;
    int k = idx & 15;
    int cidx = (idx >> 4) & 255;
    int s = idx >> 12;
    wp[(s * 16 + k) * 256 + cidx] = f2bf(w[idx]);
}

// ---------------- conv1 combine ----------------
__global__ __launch_bounds__(256) void k_conv1(const float* __restrict__ G,
                                               const float* __restrict__ bias,
                                               float* __restrict__ f) {
    long idx = (long)blockIdx.x * 256 + threadIdx.x;
    if (idx >= (long)B * 8 * L) return;
    int l = (int)(idx % L);
    long t = idx / L;
    int s = (int)(t & 7);
    int b = (int)(t >> 3);
    float acc = bias[s];
    #pragma unroll
    for (int k = 0; k < 16; ++k) {
        int ls = l + k - 7;
        if (ls >= 0 && ls < L)
            acc += G[((long)b * L + ls) * 128 + s * 16 + k];
    }
    f[(long)b * FLAT + s * L + l] = acc;
}

// ---------------- MLP ----------------
__global__ __launch_bounds__(256) void k_mlp1(const float* __restrict__ f,
                                              const float* __restrict__ w1,
                                              const float* __restrict__ b1,
                                              float* __restrict__ out1) {
    int n = blockIdx.x;
    int tid = threadIdx.x;
    float acc[16];
    #pragma unroll
    for (int i = 0; i < 16; ++i) acc[i] = 0.f;
    const float* wr = w1 + (long)n * FLAT;
    for (int k = tid; k < FLAT; k += 256) {
        float wv = wr[k];
        #pragma unroll
        for (int b = 0; b < 16; ++b) acc[b] = fmaf(wv, f[(long)b * FLAT + k], acc[b]);
    }
    __shared__ float red[16][257];
    #pragma unroll
    for (int b = 0; b < 16; ++b) red[b][tid] = acc[b];
    __syncthreads();
    for (int s = 128; s > 0; s >>= 1) {
        if (tid < s)
            #pragma unroll
            for (int b = 0; b < 16; ++b) red[b][tid] += red[b][tid + s];
        __syncthreads();
    }
    if (tid < 16) out1[(long)tid * 512 + n] = fmaxf(red[tid][0] + b1[n], 0.f);
}

__global__ __launch_bounds__(256) void k_mlp2(const float* __restrict__ in,
                                              const float* __restrict__ w,
                                              const float* __restrict__ bias,
                                              float* __restrict__ out) {
    int b = blockIdx.x, n = threadIdx.x;
    const float* ir = in + b * 512;
    const float* wr = w + (long)n * 512;
    float acc = 0.f;
    for (int k = 0; k < 512; ++k) acc = fmaf(ir[k], wr[k], acc);
    out[b * 256 + n] = fmaxf(acc + bias[n], 0.f);
}

__global__ __launch_bounds__(64) void k_mlp3(const float* __restrict__ in,
                                             const float* __restrict__ w,
                                             const float* __restrict__ bias,
                                             float* __restrict__ out) {
    int b = blockIdx.x, n = threadIdx.x;
    const float* ir = in + b * 256;
    const float* wr = w + (long)n * 256;
    float acc = 0.f;
    for (int k = 0; k < 256; ++k) acc = fmaf(ir[k], wr[k], acc);
    out[b * 64 + n] = fmaxf(acc + bias[n], 0.f);
}

__global__ __launch_bounds__(64) void k_mlp4(const float* __restrict__ in,
                                             const float* __restrict__ w4,
                                             const float* __restrict__ b4,
                                             float* __restrict__ dout) {
    int b = blockIdx.x, k = threadIdx.x;
    float v = in[b * 64 + k] * w4[k];
    #pragma unroll
    for (int off = 32; off > 0; off >>= 1) v += __shfl_down(v, off);
    if (k == 0) dout[b] = v + b4[0];
}

// ---------------- host launcher ----------------
extern "C" void kernel_launch(void* const* d_in, const int* in_sizes, int n_in,
                              void* d_out, int out_size, void* d_ws, size_t ws_size,
                              hipStream_t stream) {
    (void)in_sizes; (void)n_in; (void)out_size;
    if (ws_size < WS_NEEDED) return;

    const float* x         = (const float*)d_in[0];
    const float* conv_w    = (const float*)d_in[1];
    // conv_b (d_in[2]) cancels under batch-stat BN — unused
    const float* bn_w      = (const float*)d_in[3];
    const float* bn_b      = (const float*)d_in[4];
    const float* in_proj_w = (const float*)d_in[5];
    const float* conv1d_w  = (const float*)d_in[6];
    const float* conv1d_b  = (const float*)d_in[7];
    const float* dt_bias   = (const float*)d_in[8];
    const float* A_log     = (const float*)d_in[9];
    const float* Dp        = (const float*)d_in[10];
    const float* norm_w    = (const float*)d_in[11];
    const float* out_proj_w= (const float*)d_in[12];
    const float* conv1_w   = (const float*)d_in[13];
    const float* conv1_b   = (const float*)d_in[14];
    const float* w1 = (const float*)d_in[15]; const float* b1 = (const float*)d_in[16];
    const float* w2 = (const float*)d_in[17]; const float* b2 = (const float*)d_in[18];
    const float* w3 = (const float*)d_in[19]; const float* b3 = (const float*)d_in[20];
    const float* w4 = (const float*)d_in[21]; const float* b4 = (const float*)d_in[22];

    char* base = (char*)d_ws;
    float* dtv  = (float*)(base + S_DTV);
    float* cs   = (float*)(base + S_CS);
    float* sums = (float*)(base + S_STAT);
    float* sumsq= sums + 256;
    float* scale= sums + 512;
    float* shift= sums + 768;
    u16*   cwbf = (u16*)(base + S_WPK);      // conv_w bf16
    u16*   wbf  = (u16*)(base + S_HALO);     // rotating weight-bf16 / halo region
    u16*   halo = (u16*)(base + S_HALO);
    u16*   ht   = (u16*)(base + OFF_HT);     // ht -> u -> yproj
    u16*   xbc  = (u16*)(base + OFF_XBC);    // xBC -> y(x-part); later G fp32
    u16*   cb   = (u16*)(base + OFF_CBST + CB_OFF);
    u16*   st   = (u16*)(base + OFF_CBST + ST_OFF);
    u16*   zb   = (u16*)(base + OFF_CBST + Z_OFF);
    float* G    = (float*)(base + OFF_XBC);
    float* fbuf = (float*)(base + OFF_CBST + F_OFF);
    float* o1   = (float*)(base + OFF_CBST + O1_OFF);
    float* o2   = (float*)(base + OFF_CBST + O2_OFF);
    float* o3   = (float*)(base + OFF_CBST + O3_OFF);
    u16*   yproj= ht;

    // 1-2. stem conv as fused-im2col MFMA GEMM (conv bias cancels in BN)
    k_wcvt<<<64, 256, 0, stream>>>(conv_w, cwbf, 256 * 64);
    gemm_mfma<true, true><<<dim3(313, 2), 256, 0, stream>>>(
        x, cwbf, ht, (int)ROWS, 256, 64, 0, 256);

    // 3. BN batch stats + in-place BN+ReLU (ht becomes u)
    k_zero<<<2, 256, 0, stream>>>(sums, 512);
    k_bnstats<<<256, 256, 0, stream>>>(ht, sums, sumsq);
    k_bnfinal<<<1, 256, 0, stream>>>(sums, sumsq, bn_w, bn_b, scale, shift);
    k_bnapply<<<4998, 256, 0, stream>>>(ht, scale, shift);

    // 4. xBC projection (MFMA, bf16 weights staged in halo region); dt projection
    k_wcvt<<<768, 256, 0, stream>>>(in_proj_w + 512L * 256, wbf, 768 * 256);
    gemm_mfma<false, true><<<dim3(313, 6), 256, 0, stream>>>(
        ht, wbf, xbc, (int)ROWS, 768, 256, 256, 768);
    k_dtproj<<<1250, 256, 0, stream>>>(ht, in_proj_w, dt_bias, dtv);

    // 5. in-place depthwise conv + SiLU (halo overwrites weight scratch); cumsum
    k_halo<<<2736, 256, 0, stream>>>(xbc, halo);
    k_dwip<<<960, 256, 0, stream>>>(xbc, halo, conv1d_w, conv1d_b);
    k_cs<<<2560, 128, 0, stream>>>(dtv, A_log, cs);

    // 6. SSD in two half-batches
    for (int bh = 0; bh < 2; ++bh) {
        int bo = bh * 8;
        k_cb<<<160, 256, 0, stream>>>(xbc, cb, bo);
        k_states<<<1280, 256, 0, stream>>>(xbc, dtv, cs, st, bo);
        k_scan<<<64, 256, 0, stream>>>(cs, st, bo);
        k_yout<<<1280, 256, 0, stream>>>(xbc, dtv, cs, cb, st, Dp, bo);
    }

    // 6.9. z projection (MFMA; halo region now dead -> z weights)
    k_wcvt<<<512, 256, 0, stream>>>(in_proj_w, wbf, 512 * 256);
    gemm_mfma<false, true><<<dim3(313, 4), 256, 0, stream>>>(
        ht, wbf, zb, (int)ROWS, 512, 256, 256, 512);

    // 7-8. gated RMSNorm + out_proj (MFMA)
    k_rmsnorm<<<39984, 256, 0, stream>>>(xbc, zb, norm_w);
    k_wcvt<<<512, 256, 0, stream>>>(out_proj_w, wbf, 256 * 512);
    gemm_mfma<false, true><<<dim3(313, 2), 256, 0, stream>>>(
        xbc, wbf, yproj, (int)ROWS, 256, 512, 768, 256);

    // 9. conv1 as MFMA GEMM (G fp32 overwrites xbc segment) + shifted gather
    k_wpack<<<128, 256, 0, stream>>>(conv1_w, wbf);
    gemm_mfma<false, false><<<dim3(313, 1), 256, 0, stream>>>(
        yproj, wbf, G, (int)ROWS, 128, 256, 256, 128);
    k_conv1<<<1250, 256, 0, stream>>>(G, conv1_b, fbuf);

    // 10. MLP head
    k_mlp1<<<512, 256, 0, stream>>>(fbuf, w1, b1, o1);
    k_mlp2<<<16, 256, 0, stream>>>(o1, w2, b2, o2);
    k_mlp3<<<16, 64, 0, stream>>>(o2, w3, b3, o3);
    k_mlp4<<<16, 64, 0, stream>>>(o3, w4, b4, (float*)d_out);
}

// Round 6
// 769.015 us; speedup vs baseline: 1.7794x; 1.1905x over previous
//
#include <hip/hip_runtime.h>
#include <math.h>

// ---------------- problem constants ----------------
constexpr int B    = 16;
constexpr int L    = 2499;        // conv-stem output length
constexpr int DIN  = 512;         // d_inner
constexpr int NH   = 8;
constexpr int DS   = 128;         // d_state
constexpr int NC   = 20;          // ceil(2499/128) chunks
constexpr int XBCD = 768;         // DIN + 2*DS
constexpr int FLAT = 19992;
constexpr long ROWS = (long)B * L;   // 39984

// ---------------- workspace layout (BYTE offsets) — identical to passing round ----------------
constexpr size_t S_DTV  = 0;          // fp32 ROWS*8
constexpr size_t S_CS   = 1279488;    // fp32 16*8*20*128
constexpr size_t S_STAT = 2590208;    // fp32 1024
constexpr size_t S_WPK  = 2594304;    // conv_w bf16
constexpr size_t S_HALO = 2725376;    // rotating: xbcw-bf16 -> halo -> zw/outw/wpk bf16
constexpr size_t OFF_HT  = 4199936;   // bf16 ROWS*256 (ht -> u -> yproj)
constexpr size_t OFF_XBC = 24671744;  // bf16 ROWS*768 (xbc/y); later G fp32 ROWS*128
constexpr size_t OFF_CBST= 86087168;  // cb+st -> z bf16 -> fbuf+MLP
constexpr size_t CB_OFF  = 0;         // bf16 8*20*128*128
constexpr size_t ST_OFF  = 5242880;   // bf16 8*20*8*8192
constexpr size_t Z_OFF   = 0;         // bf16 ROWS*512
constexpr size_t F_OFF   = 0;         // fp32 16*19992
constexpr size_t O1_OFF  = 1279488;
constexpr size_t O2_OFF  = 1312256;
constexpr size_t O3_OFF  = 1328640;
constexpr size_t WS_NEEDED = 127030784;

// ---------------- bf16 helpers ----------------
typedef unsigned short u16;
typedef __attribute__((ext_vector_type(8))) short bf16x8;
typedef __attribute__((ext_vector_type(4))) float f32x4;

__device__ __forceinline__ float bf2f(unsigned int u) {
    return __uint_as_float(u << 16);
}
__device__ __forceinline__ u16 f2bf(float f) {
    unsigned int x = __float_as_uint(f);
    unsigned int r = x + 0x7fffu + ((x >> 16) & 1u);
    return (u16)(r >> 16);
}
__device__ __forceinline__ unsigned int pk2(float a, float b) {
    return (unsigned int)f2bf(a) | ((unsigned int)f2bf(b) << 16);
}
__device__ __forceinline__ void ld8bf(const u16* p, float* o) {
    uint4 v = *(const uint4*)p;
    o[0]=bf2f(v.x&0xffffu); o[1]=bf2f(v.x>>16);
    o[2]=bf2f(v.y&0xffffu); o[3]=bf2f(v.y>>16);
    o[4]=bf2f(v.z&0xffffu); o[5]=bf2f(v.z>>16);
    o[6]=bf2f(v.w&0xffffu); o[7]=bf2f(v.w>>16);
}
__device__ __forceinline__ void ld4bf(const u16* p, float* o) {
    uint2 v = *(const uint2*)p;
    o[0]=bf2f(v.x&0xffffu); o[1]=bf2f(v.x>>16);
    o[2]=bf2f(v.y&0xffffu); o[3]=bf2f(v.y>>16);
}
__device__ __forceinline__ void st8bf(u16* p, const float* s) {
    uint4 v;
    v.x = pk2(s[0],s[1]); v.y = pk2(s[2],s[3]);
    v.z = pk2(s[4],s[5]); v.w = pk2(s[6],s[7]);
    *(uint4*)p = v;
}
__device__ __forceinline__ float siluf(float x) { return x / (1.f + expf(-x)); }

// ---------------- zero-init ----------------
__global__ __launch_bounds__(256) void k_zero(float* __restrict__ p, int n) {
    int i = blockIdx.x * 256 + threadIdx.x;
    if (i < n) p[i] = 0.f;
}

// ---------------- fp32 -> bf16 weight convert ----------------
__global__ __launch_bounds__(256) void k_wcvt(const float* __restrict__ src,
                                              u16* __restrict__ dst, int n) {
    int i = blockIdx.x * 256 + threadIdx.x;
    if (i < n) dst[i] = f2bf(src[i]);
}

// ---------------- MFMA GEMM: C[M,N] = A[M,K](bf16) @ Wb[N,K](bf16)^T ----------------
template <bool IM2COL, bool BF16OUT>
__global__ __launch_bounds__(256) void gemm_mfma(const void* __restrict__ Ap,
                                                 const u16* __restrict__ Wb,
                                                 void* __restrict__ Cp,
                                                 int M, int N, int K, int lda, int ldc) {
    __shared__ u16 Als[128 * 40];
    __shared__ u16 Bls[128 * 40];
    int tid = threadIdx.x;
    int wave = tid >> 6, lane = tid & 63;
    int wr = wave >> 1, wc = wave & 1;
    int m0 = blockIdx.x * 128, n0 = blockIdx.y * 128;
    int l15 = lane & 15, l4 = lane >> 4;
    int srow = tid >> 1, scol = (tid & 1) * 16;

    f32x4 acc[4][4];
    #pragma unroll
    for (int i = 0; i < 4; ++i)
        #pragma unroll
        for (int j = 0; j < 4; ++j)
            acc[i][j] = (f32x4){0.f, 0.f, 0.f, 0.f};

    for (int k0 = 0; k0 < K; k0 += 32) {
        {
            int am = m0 + srow;
            uint4 v0 = {0,0,0,0}, v1 = {0,0,0,0};
            if (am < M) {
                if (IM2COL) {
                    const float* x = (const float*)Ap;
                    int b = am / L, l = am - b * L;
                    int ic = (k0 + scol) >> 4;
                    const float* px = x + ((long)(b * 4 + ic)) * 20000 + l * 8;
                    float4 f0 = *(const float4*)(px);
                    float4 f1 = *(const float4*)(px + 4);
                    float4 f2 = *(const float4*)(px + 8);
                    float4 f3 = *(const float4*)(px + 12);
                    v0.x = pk2(f0.x,f0.y); v0.y = pk2(f0.z,f0.w);
                    v0.z = pk2(f1.x,f1.y); v0.w = pk2(f1.z,f1.w);
                    v1.x = pk2(f2.x,f2.y); v1.y = pk2(f2.z,f2.w);
                    v1.z = pk2(f3.x,f3.y); v1.w = pk2(f3.z,f3.w);
                } else {
                    const u16* pa = (const u16*)Ap + (long)am * lda + k0 + scol;
                    v0 = *(const uint4*)pa;
                    v1 = *(const uint4*)(pa + 8);
                }
            }
            *(uint4*)&Als[srow * 40 + scol]     = v0;
            *(uint4*)&Als[srow * 40 + scol + 8] = v1;
        }
        {
            const u16* pw = Wb + (long)(n0 + srow) * K + k0 + scol;
            *(uint4*)&Bls[srow * 40 + scol]     = *(const uint4*)pw;
            *(uint4*)&Bls[srow * 40 + scol + 8] = *(const uint4*)(pw + 8);
        }
        __syncthreads();

        bf16x8 af[4], bfr[4];
        #pragma unroll
        for (int i = 0; i < 4; ++i) {
            af[i]  = *(const bf16x8*)&Als[(wr * 64 + i * 16 + l15) * 40 + l4 * 8];
            bfr[i] = *(const bf16x8*)&Bls[(wc * 64 + i * 16 + l15) * 40 + l4 * 8];
        }
        #pragma unroll
        for (int i = 0; i < 4; ++i)
            #pragma unroll
            for (int j = 0; j < 4; ++j)
                acc[i][j] = __builtin_amdgcn_mfma_f32_16x16x32_bf16(
                    af[i], bfr[j], acc[i][j], 0, 0, 0);
        __syncthreads();
    }

    #pragma unroll
    for (int i = 0; i < 4; ++i) {
        #pragma unroll
        for (int j = 0; j < 4; ++j) {
            int n = n0 + wc * 64 + j * 16 + l15;
            #pragma unroll
            for (int r = 0; r < 4; ++r) {
                int m = m0 + wr * 64 + i * 16 + l4 * 4 + r;
                if (m < M) {
                    if (BF16OUT) ((u16*)Cp)[(long)m * ldc + n] = f2bf(acc[i][j][r]);
                    else         ((float*)Cp)[(long)m * ldc + n] = acc[i][j][r];
                }
            }
        }
    }
}

// ---------------- BN batch stats ----------------
__global__ __launch_bounds__(256) void k_bnstats(const u16* __restrict__ h,
                                                 float* __restrict__ sums,
                                                 float* __restrict__ sumsq) {
    int c = threadIdx.x;
    float s = 0.f, s2 = 0.f;
    for (long r = blockIdx.x; r < ROWS; r += gridDim.x) {
        float v = bf2f(h[r * 256 + c]);
        s += v; s2 += v * v;
    }
    atomicAdd(&sums[c], s);
    atomicAdd(&sumsq[c], s2);
}

__global__ __launch_bounds__(256) void k_bnfinal(const float* __restrict__ sums,
                                                 const float* __restrict__ sumsq,
                                                 const float* __restrict__ bn_w,
                                                 const float* __restrict__ bn_b,
                                                 float* __restrict__ scale,
                                                 float* __restrict__ shift) {
    int c = threadIdx.x;
    float mean = sums[c] / (float)ROWS;
    float var  = sumsq[c] / (float)ROWS - mean * mean;
    float inv  = rsqrtf(var + 1e-5f);
    float sc   = bn_w[c] * inv;
    scale[c] = sc;
    shift[c] = bn_b[c] - mean * sc;
}

// ---------------- in-place BN+ReLU ----------------
__global__ __launch_bounds__(256) void k_bnapply(u16* __restrict__ ht,
                                                 const float* __restrict__ scale,
                                                 const float* __restrict__ shift) {
    long i = ((long)blockIdx.x * 256 + threadIdx.x) * 8;
    int c = (int)(i & 255);
    float v[8];
    ld8bf(ht + i, v);
    float4 s0 = *(const float4*)(scale + c), s1 = *(const float4*)(scale + c + 4);
    float4 h0 = *(const float4*)(shift + c), h1 = *(const float4*)(shift + c + 4);
    v[0]=fmaxf(fmaf(v[0],s0.x,h0.x),0.f); v[1]=fmaxf(fmaf(v[1],s0.y,h0.y),0.f);
    v[2]=fmaxf(fmaf(v[2],s0.z,h0.z),0.f); v[3]=fmaxf(fmaf(v[3],s0.w,h0.w),0.f);
    v[4]=fmaxf(fmaf(v[4],s1.x,h1.x),0.f); v[5]=fmaxf(fmaf(v[5],s1.y,h1.y),0.f);
    v[6]=fmaxf(fmaf(v[6],s1.z,h1.z),0.f); v[7]=fmaxf(fmaf(v[7],s1.w,h1.w),0.f);
    st8bf(ht + i, v);
}

// ---------------- dt = softplus(u @ Wdt^T + dt_bias) ----------------
__global__ __launch_bounds__(256) void k_dtproj(const u16* __restrict__ u,
                                                const float* __restrict__ in_proj_w,
                                                const float* __restrict__ dt_bias,
                                                float* __restrict__ dtv) {
    long idx = (long)blockIdx.x * 256 + threadIdx.x;
    if (idx >= ROWS * 8) return;
    int h = (int)(idx & 7);
    long row = idx >> 3;
    const float* wr = in_proj_w + (long)(1280 + h) * 256;
    const u16* ar = u + row * 256;
    float acc = dt_bias[h];
    for (int k = 0; k < 256; ++k)
        acc = fmaf(bf2f(ar[k]), wr[k], acc);
    dtv[idx] = (acc > 20.f) ? acc : log1pf(expf(acc));
}

// ---------------- save 3-row halos ----------------
__global__ __launch_bounds__(256) void k_halo(const u16* __restrict__ xbc,
                                              u16* __restrict__ halo) {
    long idx = (long)blockIdx.x * 256 + threadIdx.x;
    if (idx >= 16L * 19 * 3 * 768) return;
    int ch = (int)(idx % 768);
    long t1 = idx / 768;
    int j = (int)(t1 % 3);
    long t2 = t1 / 3;
    int t = (int)(t2 % 19) + 1;
    int b = (int)(t2 / 19);
    halo[(((long)b * 20 + t) * 3 + j) * 768 + ch] =
        xbc[((long)b * L + t * 128 - 3 + j) * 768 + ch];
}

// ---------------- in-place depthwise causal conv1d + SiLU ----------------
__global__ __launch_bounds__(256) void k_dwip(u16* __restrict__ xbc,
                                              const u16* __restrict__ halo,
                                              const float* __restrict__ w,
                                              const float* __restrict__ bias) {
    int cg = blockIdx.x % 3;
    int t  = (blockIdx.x / 3) % 20;
    int b  = blockIdx.x / 60;
    int ch = cg * 256 + threadIdx.x;
    int l0 = t * 128, l1 = min(l0 + 128, L);
    float W0 = w[ch*4+0], W1 = w[ch*4+1], W2 = w[ch*4+2], W3 = w[ch*4+3];
    float bs = bias[ch];
    float p0 = 0.f, p1 = 0.f, p2 = 0.f;
    if (t > 0) {
        const u16* hp = halo + (((long)b * 20 + t) * 3) * 768 + ch;
        p0 = bf2f(hp[0]); p1 = bf2f(hp[768]); p2 = bf2f(hp[1536]);
    }
    u16* base = xbc + ((long)b * L + l0) * 768 + ch;
    for (int l = l0; l < l1; ++l) {
        float p3 = bf2f(*base);
        float acc = fmaf(p0, W0, fmaf(p1, W1, fmaf(p2, W2, fmaf(p3, W3, bs))));
        *base = f2bf(siluf(acc));
        p0 = p1; p1 = p2; p2 = p3;
        base += 768;
    }
}

// ---------------- per-chunk inclusive cumsum of dA ----------------
__global__ __launch_bounds__(128) void k_cs(const float* __restrict__ dtv,
                                            const float* __restrict__ A_log,
                                            float* __restrict__ cs) {
    int c = blockIdx.x % NC;
    int h = (blockIdx.x / NC) % NH;
    int b = blockIdx.x / (NC * NH);
    int q = threadIdx.x;
    int lg = c * 128 + q;
    float Av = -expf(A_log[h]);
    float dA = 0.f;
    if (lg < L) dA = dtv[((long)b * L + lg) * 8 + h] * Av;
    __shared__ float buf[128];
    buf[q] = dA;
    __syncthreads();
    for (int off = 1; off < 128; off <<= 1) {
        float add = (q >= off) ? buf[q - off] : 0.f;
        __syncthreads();
        buf[q] += add;
        __syncthreads();
    }
    cs[(long)blockIdx.x * 128 + q] = buf[q];
}

// ---------------- cb[bl,c,l,s] = C[l]·B[s]  (MFMA NT GEMM, both K-contiguous) ----------------
__global__ __launch_bounds__(256) void k_cb(const u16* __restrict__ xbc,
                                            u16* __restrict__ cb, int bo) {
    int c = blockIdx.x % NC, bl = blockIdx.x / NC;
    int b = bo + bl;
    long bcl = blockIdx.x;
    __shared__ u16 Als[128 * 40];
    __shared__ u16 Bls[128 * 40];
    int tid = threadIdx.x;
    int wave = tid >> 6, lane = tid & 63;
    int wr = wave >> 1, wc = wave & 1;
    int l15 = lane & 15, l4 = lane >> 4;
    int srow = tid >> 1, scol = (tid & 1) * 16;

    f32x4 acc[4][4];
    #pragma unroll
    for (int i = 0; i < 4; ++i)
        #pragma unroll
        for (int j = 0; j < 4; ++j)
            acc[i][j] = (f32x4){0.f, 0.f, 0.f, 0.f};

    int lg = c * 128 + srow;
    const u16* prow = xbc + ((long)b * L + lg) * XBCD;

    for (int k0 = 0; k0 < 128; k0 += 32) {
        uint4 cv0 = {0,0,0,0}, cv1 = cv0, bv0 = cv0, bv1 = cv0;
        if (lg < L) {
            cv0 = *(const uint4*)(prow + 640 + k0 + scol);
            cv1 = *(const uint4*)(prow + 640 + k0 + scol + 8);
            bv0 = *(const uint4*)(prow + 512 + k0 + scol);
            bv1 = *(const uint4*)(prow + 512 + k0 + scol + 8);
        }
        *(uint4*)&Als[srow * 40 + scol]     = cv0;
        *(uint4*)&Als[srow * 40 + scol + 8] = cv1;
        *(uint4*)&Bls[srow * 40 + scol]     = bv0;
        *(uint4*)&Bls[srow * 40 + scol + 8] = bv1;
        __syncthreads();

        bf16x8 af[4], bfr[4];
        #pragma unroll
        for (int i = 0; i < 4; ++i) {
            af[i]  = *(const bf16x8*)&Als[(wr * 64 + i * 16 + l15) * 40 + l4 * 8];
            bfr[i] = *(const bf16x8*)&Bls[(wc * 64 + i * 16 + l15) * 40 + l4 * 8];
        }
        #pragma unroll
        for (int i = 0; i < 4; ++i)
            #pragma unroll
            for (int j = 0; j < 4; ++j)
                acc[i][j] = __builtin_amdgcn_mfma_f32_16x16x32_bf16(
                    af[i], bfr[j], acc[i][j], 0, 0, 0);
        __syncthreads();
    }

    #pragma unroll
    for (int i = 0; i < 4; ++i)
        #pragma unroll
        for (int j = 0; j < 4; ++j) {
            int n = wc * 64 + j * 16 + l15;
            #pragma unroll
            for (int r = 0; r < 4; ++r) {
                int m = wr * 64 + i * 16 + l4 * 4 + r;
                cb[(bcl * 128 + m) * 128 + n] = f2bf(acc[i][j][r]);
            }
        }
}

// ---------------- states S[n,p] = sum_l Bw[l,n]*xw[l,p]  (MFMA, transposed staging) ----------------
__global__ __launch_bounds__(256) void k_states(const u16* __restrict__ xbc,
                                                const float* __restrict__ dtv,
                                                const float* __restrict__ cs,
                                                u16* __restrict__ st, int bo) {
    int h = blockIdx.x & 7;
    int c = (blockIdx.x >> 3) % NC;
    int bl = blockIdx.x / (8 * NC);
    int b = bo + bl;
    __shared__ u16 At[128][136];   // Bw^T [n][l]
    __shared__ u16 Bt[64][136];    // xw^T [p][l]
    long csbase = (((long)b * 8 + h) * NC + c) * 128;
    float csLast = cs[csbase + 127];
    int tid = threadIdx.x;
    int lane = tid & 63, wave = tid >> 6;
    int wr = wave >> 1, wc = wave & 1;
    int l15 = lane & 15, l4 = lane >> 4;

    // transposed staging: thread handles l-pair (l0,l1) and a quarter of n/p range
    int l0 = 2 * (tid & 63), l1 = l0 + 1;
    int q = tid >> 6;
    int lg0 = c * 128 + l0, lg1 = c * 128 + l1;
    long row0 = (long)b * L + lg0, row1 = row0 + 1;
    float wl0 = 0.f, wl1 = 0.f, dt0 = 0.f, dt1 = 0.f;
    if (lg0 < L) { wl0 = expf(csLast - cs[csbase + l0]); dt0 = dtv[row0 * 8 + h]; }
    if (lg1 < L) { wl1 = expf(csLast - cs[csbase + l1]); dt1 = dtv[row1 * 8 + h]; }

    #pragma unroll
    for (int nb = 0; nb < 4; ++nb) {
        int n0 = q * 32 + nb * 8;
        float a0[8] = {0,0,0,0,0,0,0,0}, a1[8] = {0,0,0,0,0,0,0,0};
        if (lg0 < L) ld8bf(xbc + row0 * XBCD + 512 + n0, a0);
        if (lg1 < L) ld8bf(xbc + row1 * XBCD + 512 + n0, a1);
        #pragma unroll
        for (int i = 0; i < 8; ++i)
            *(unsigned int*)&At[n0 + i][l0] = pk2(a0[i] * wl0, a1[i] * wl1);
    }
    #pragma unroll
    for (int pb = 0; pb < 2; ++pb) {
        int p0 = q * 16 + pb * 8;
        float a0[8] = {0,0,0,0,0,0,0,0}, a1[8] = {0,0,0,0,0,0,0,0};
        if (lg0 < L) ld8bf(xbc + row0 * XBCD + h * 64 + p0, a0);
        if (lg1 < L) ld8bf(xbc + row1 * XBCD + h * 64 + p0, a1);
        #pragma unroll
        for (int i = 0; i < 8; ++i)
            *(unsigned int*)&Bt[p0 + i][l0] = pk2(a0[i] * dt0, a1[i] * dt1);
    }
    __syncthreads();

    f32x4 acc[4][2];
    #pragma unroll
    for (int i = 0; i < 4; ++i)
        #pragma unroll
        for (int j = 0; j < 2; ++j)
            acc[i][j] = (f32x4){0.f, 0.f, 0.f, 0.f};

    #pragma unroll
    for (int k0 = 0; k0 < 128; k0 += 32) {
        bf16x8 af[4], bfr[2];
        #pragma unroll
        for (int i = 0; i < 4; ++i)
            af[i] = *(const bf16x8*)&At[wr * 64 + i * 16 + l15][k0 + l4 * 8];
        #pragma unroll
        for (int j = 0; j < 2; ++j)
            bfr[j] = *(const bf16x8*)&Bt[wc * 32 + j * 16 + l15][k0 + l4 * 8];
        #pragma unroll
        for (int i = 0; i < 4; ++i)
            #pragma unroll
            for (int j = 0; j < 2; ++j)
                acc[i][j] = __builtin_amdgcn_mfma_f32_16x16x32_bf16(
                    af[i], bfr[j], acc[i][j], 0, 0, 0);
    }

    long basep = (long)blockIdx.x * 8192;
    #pragma unroll
    for (int i = 0; i < 4; ++i)
        #pragma unroll
        for (int j = 0; j < 2; ++j) {
            int p = wc * 32 + j * 16 + l15;
            #pragma unroll
            for (int r = 0; r < 4; ++r) {
                int n = wr * 64 + i * 16 + l4 * 4 + r;
                st[basep + n * 64 + p] = f2bf(acc[i][j][r]);
            }
        }
}

// ---------------- inter-chunk scan ----------------
__global__ __launch_bounds__(256) void k_scan(const float* __restrict__ cs,
                                              u16* __restrict__ st, int bo) {
    int h = blockIdx.x & 7, bl = blockIdx.x >> 3;
    int b = bo + bl;
    int tid = threadIdx.x;
    float carry[32];
    #pragma unroll
    for (int i = 0; i < 32; ++i) carry[i] = 0.f;
    long csbase = ((long)b * 8 + h) * NC * 128;
    for (int c = 0; c < NC; ++c) {
        float cd = expf(cs[csbase + c * 128 + 127]);
        u16* p = st + (((long)bl * NC + c) * 8 + h) * 8192;
        #pragma unroll
        for (int i = 0; i < 32; ++i) {
            int e = tid + i * 256;
            float v = bf2f(p[e]);
            p[e] = f2bf(carry[i]);
            carry[i] = carry[i] * cd + v;
        }
    }
}

// ---------------- Ydiag + Yoff + D-skip (MFMA, 2-phase accumulate) ----------------
__global__ __launch_bounds__(256) void k_yout(u16* __restrict__ xbc,
                                              const float* __restrict__ dtv,
                                              const float* __restrict__ cs,
                                              const u16* __restrict__ cb,
                                              const u16* __restrict__ st,
                                              const float* __restrict__ Dv, int bo) {
    int h = blockIdx.x & 7;
    int c = (blockIdx.x >> 3) % NC;
    int bl = blockIdx.x / (8 * NC);
    int b = bo + bl;
    long bcl = (long)bl * NC + c;
    __shared__ u16 Am[128][136];   // phase1: masked decay CB [l][s]; phase2: C*ecs [l][n]
    __shared__ u16 Bt[64][136];    // phase1: xw^T [p][s]; phase2: prev^T [p][n]
    __shared__ float csb[128], ecs[128];
    int tid = threadIdx.x;
    long csbase = (((long)b * 8 + h) * NC + c) * 128;
    if (tid < 128) {
        float v = cs[csbase + tid];
        csb[tid] = v;
        ecs[tid] = expf(v);
    }
    __syncthreads();

    int lane = tid & 63, wave = tid >> 6;
    int wr = wave >> 1, wc = wave & 1;
    int l15 = lane & 15, l4 = lane >> 4;
    int lrow = tid >> 1, sh = (tid & 1) * 64;
    int l0 = 2 * (tid & 63), l1 = l0 + 1;
    int q = tid >> 6;
    int lg0 = c * 128 + l0, lg1 = c * 128 + l1;
    long row0 = (long)b * L + lg0, row1 = row0 + 1;

    // ---- phase 1 staging ----
    {
        float cl = csb[lrow];
        const u16* cbrow = cb + (bcl * 128 + lrow) * 128;
        #pragma unroll
        for (int sb = 0; sb < 8; ++sb) {
            int s0 = sh + sb * 8;
            float a[8];
            ld8bf(cbrow + s0, a);
            #pragma unroll
            for (int i = 0; i < 8; ++i) {
                int s = s0 + i;
                float w = (s <= lrow) ? expf(cl - csb[s]) : 0.f;
                a[i] *= w;
            }
            st8bf(&Am[lrow][s0], a);
        }
        float dt0 = 0.f, dt1 = 0.f;
        if (lg0 < L) dt0 = dtv[row0 * 8 + h];
        if (lg1 < L) dt1 = dtv[row1 * 8 + h];
        #pragma unroll
        for (int pb = 0; pb < 2; ++pb) {
            int p0 = q * 16 + pb * 8;
            float a0[8] = {0,0,0,0,0,0,0,0}, a1[8] = {0,0,0,0,0,0,0,0};
            if (lg0 < L) ld8bf(xbc + row0 * XBCD + h * 64 + p0, a0);
            if (lg1 < L) ld8bf(xbc + row1 * XBCD + h * 64 + p0, a1);
            #pragma unroll
            for (int i = 0; i < 8; ++i)
                *(unsigned int*)&Bt[p0 + i][l0] = pk2(a0[i] * dt0, a1[i] * dt1);
        }
    }
    __syncthreads();

    f32x4 acc[4][2];
    #pragma unroll
    for (int i = 0; i < 4; ++i)
        #pragma unroll
        for (int j = 0; j < 2; ++j)
            acc[i][j] = (f32x4){0.f, 0.f, 0.f, 0.f};

    #pragma unroll
    for (int k0 = 0; k0 < 128; k0 += 32) {
        bf16x8 af[4], bfr[2];
        #pragma unroll
        for (int i = 0; i < 4; ++i)
            af[i] = *(const bf16x8*)&Am[wr * 64 + i * 16 + l15][k0 + l4 * 8];
        #pragma unroll
        for (int j = 0; j < 2; ++j)
            bfr[j] = *(const bf16x8*)&Bt[wc * 32 + j * 16 + l15][k0 + l4 * 8];
        #pragma unroll
        for (int i = 0; i < 4; ++i)
            #pragma unroll
            for (int j = 0; j < 2; ++j)
                acc[i][j] = __builtin_amdgcn_mfma_f32_16x16x32_bf16(
                    af[i], bfr[j], acc[i][j], 0, 0, 0);
    }
    __syncthreads();

    // ---- phase 2 staging ----
    {
        float el = ecs[lrow];
        int lgr = c * 128 + lrow;
        const u16* xr = xbc + ((long)b * L + lgr) * XBCD + 640;
        #pragma unroll
        for (int nb = 0; nb < 8; ++nb) {
            int n0 = sh + nb * 8;
            float a[8] = {0,0,0,0,0,0,0,0};
            if (lgr < L) {
                ld8bf(xr + n0, a);
                #pragma unroll
                for (int i = 0; i < 8; ++i) a[i] *= el;
            }
            st8bf(&Am[lrow][n0], a);
        }
        const u16* pv = st + (bcl * 8 + h) * 8192;
        #pragma unroll
        for (int pb = 0; pb < 2; ++pb) {
            int p0 = q * 16 + pb * 8;
            float a0[8], a1[8];
            ld8bf(pv + (long)l0 * 64 + p0, a0);
            ld8bf(pv + (long)l1 * 64 + p0, a1);
            #pragma unroll
            for (int i = 0; i < 8; ++i)
                *(unsigned int*)&Bt[p0 + i][l0] = pk2(a0[i], a1[i]);
        }
    }
    __syncthreads();

    #pragma unroll
    for (int k0 = 0; k0 < 128; k0 += 32) {
        bf16x8 af[4], bfr[2];
        #pragma unroll
        for (int i = 0; i < 4; ++i)
            af[i] = *(const bf16x8*)&Am[wr * 64 + i * 16 + l15][k0 + l4 * 8];
        #pragma unroll
        for (int j = 0; j < 2; ++j)
            bfr[j] = *(const bf16x8*)&Bt[wc * 32 + j * 16 + l15][k0 + l4 * 8];
        #pragma unroll
        for (int i = 0; i < 4; ++i)
            #pragma unroll
            for (int j = 0; j < 2; ++j)
                acc[i][j] = __builtin_amdgcn_mfma_f32_16x16x32_bf16(
                    af[i], bfr[j], acc[i][j], 0, 0, 0);
    }

    // ---- epilogue: + D*xh, overwrite x-part in place ----
    float Dh = Dv[h];
    #pragma unroll
    for (int i = 0; i < 4; ++i)
        #pragma unroll
        for (int r = 0; r < 4; ++r) {
            int l = wr * 64 + i * 16 + l4 * 4 + r;
            int lg = c * 128 + l;
            if (lg >= L) continue;
            long row = (long)b * L + lg;
            #pragma unroll
            for (int j = 0; j < 2; ++j) {
                int p = wc * 32 + j * 16 + l15;
                u16* xp = xbc + row * XBCD + h * 64 + p;
                float xv = bf2f(*xp);
                *xp = f2bf(fmaf(Dh, xv, acc[i][j][r]));
            }
        }
}

// ---------------- gated RMSNorm ----------------
__global__ __launch_bounds__(256) void k_rmsnorm(u16* __restrict__ y,
                                                 const u16* __restrict__ z,
                                                 const float* __restrict__ nw) {
    long r = blockIdx.x;
    int tid = threadIdx.x;
    float v0 = bf2f(y[r * XBCD + tid]), v1 = bf2f(y[r * XBCD + 256 + tid]);
    float z0 = bf2f(z[r * DIN + tid]),  z1 = bf2f(z[r * DIN + 256 + tid]);
    v0 *= siluf(z0);
    v1 *= siluf(z1);
    __shared__ float red[256];
    red[tid] = v0 * v0 + v1 * v1;
    __syncthreads();
    for (int s = 128; s > 0; s >>= 1) {
        if (tid < s) red[tid] += red[tid + s];
        __syncthreads();
    }
    float sc = rsqrtf(red[0] / 512.f + 1e-5f);
    y[r * XBCD + tid]       = f2bf(v0 * sc * nw[tid]);
    y[r * XBCD + 256 + tid] = f2bf(v1 * sc * nw[256 + tid]);
}

// ---------------- repack conv1_w ----------------
__global__ __launch_bounds__(256) void k_wpack(const float* __restrict__ w,
                                               u16* __restrict__ wp) {
    int idx = blockIdx.x * 256 + threadIdx.x;
    if (idx >= 8 * 256 * 16) return;
    int k = idx & 15;
    int cidx = (idx >> 4) & 255;
    int s = idx >> 12;
    wp[(s * 16 + k) * 256 + cidx] = f2bf(w[idx]);
}

// ---------------- conv1 combine ----------------
__global__ __launch_bounds__(256) void k_conv1(const float* __restrict__ G,
                                               const float* __restrict__ bias,
                                               float* __restrict__ f) {
    long idx = (long)blockIdx.x * 256 + threadIdx.x;
    if (idx >= (long)B * 8 * L) return;
    int l = (int)(idx % L);
    long t = idx / L;
    int s = (int)(t & 7);
    int b = (int)(t >> 3);
    float acc = bias[s];
    #pragma unroll
    for (int k = 0; k < 16; ++k) {
        int ls = l + k - 7;
        if (ls >= 0 && ls < L)
            acc += G[((long)b * L + ls) * 128 + s * 16 + k];
    }
    f[(long)b * FLAT + s * L + l] = acc;
}

// ---------------- MLP ----------------
__global__ __launch_bounds__(256) void k_mlp1(const float* __restrict__ f,
                                              const float* __restrict__ w1,
                                              const float* __restrict__ b1,
                                              float* __restrict__ out1) {
    int n = blockIdx.x;
    int tid = threadIdx.x;
    float acc[16];
    #pragma unroll
    for (int i = 0; i < 16; ++i) acc[i] = 0.f;
    const float* wr = w1 + (long)n * FLAT;
    for (int k = tid; k < FLAT; k += 256) {
        float wv = wr[k];
        #pragma unroll
        for (int b = 0; b < 16; ++b) acc[b] = fmaf(wv, f[(long)b * FLAT + k], acc[b]);
    }
    __shared__ float red[16][257];
    #pragma unroll
    for (int b = 0; b < 16; ++b) red[b][tid] = acc[b];
    __syncthreads();
    for (int s = 128; s > 0; s >>= 1) {
        if (tid < s)
            #pragma unroll
            for (int b = 0; b < 16; ++b) red[b][tid] += red[b][tid + s];
        __syncthreads();
    }
    if (tid < 16) out1[(long)tid * 512 + n] = fmaxf(red[tid][0] + b1[n], 0.f);
}

__global__ __launch_bounds__(256) void k_mlp2(const float* __restrict__ in,
                                              const float* __restrict__ w,
                                              const float* __restrict__ bias,
                                              float* __restrict__ out) {
    int b = blockIdx.x, n = threadIdx.x;
    const float* ir = in + b * 512;
    const float* wr = w + (long)n * 512;
    float acc = 0.f;
    for (int k = 0; k < 512; ++k) acc = fmaf(ir[k], wr[k], acc);
    out[b * 256 + n] = fmaxf(acc + bias[n], 0.f);
}

__global__ __launch_bounds__(64) void k_mlp3(const float* __restrict__ in,
                                             const float* __restrict__ w,
                                             const float* __restrict__ bias,
                                             float* __restrict__ out) {
    int b = blockIdx.x, n = threadIdx.x;
    const float* ir = in + b * 256;
    const float* wr = w + (long)n * 256;
    float acc = 0.f;
    for (int k = 0; k < 256; ++k) acc = fmaf(ir[k], wr[k], acc);
    out[b * 64 + n] = fmaxf(acc + bias[n], 0.f);
}

__global__ __launch_bounds__(64) void k_mlp4(const float* __restrict__ in,
                                             const float* __restrict__ w4,
                                             const float* __restrict__ b4,
                                             float* __restrict__ dout) {
    int b = blockIdx.x, k = threadIdx.x;
    float v = in[b * 64 + k] * w4[k];
    #pragma unroll
    for (int off = 32; off > 0; off >>= 1) v += __shfl_down(v, off);
    if (k == 0) dout[b] = v + b4[0];
}

// ---------------- host launcher ----------------
extern "C" void kernel_launch(void* const* d_in, const int* in_sizes, int n_in,
                              void* d_out, int out_size, void* d_ws, size_t ws_size,
                              hipStream_t stream) {
    (void)in_sizes; (void)n_in; (void)out_size;
    if (ws_size < WS_NEEDED) return;

    const float* x         = (const float*)d_in[0];
    const float* conv_w    = (const float*)d_in[1];
    // conv_b (d_in[2]) cancels under batch-stat BN — unused
    const float* bn_w      = (const float*)d_in[3];
    const float* bn_b      = (const float*)d_in[4];
    const float* in_proj_w = (const float*)d_in[5];
    const float* conv1d_w  = (const float*)d_in[6];
    const float* conv1d_b  = (const float*)d_in[7];
    const float* dt_bias   = (const float*)d_in[8];
    const float* A_log     = (const float*)d_in[9];
    const float* Dp        = (const float*)d_in[10];
    const float* norm_w    = (const float*)d_in[11];
    const float* out_proj_w= (const float*)d_in[12];
    const float* conv1_w   = (const float*)d_in[13];
    const float* conv1_b   = (const float*)d_in[14];
    const float* w1 = (const float*)d_in[15]; const float* b1 = (const float*)d_in[16];
    const float* w2 = (const float*)d_in[17]; const float* b2 = (const float*)d_in[18];
    const float* w3 = (const float*)d_in[19]; const float* b3 = (const float*)d_in[20];
    const float* w4 = (const float*)d_in[21]; const float* b4 = (const float*)d_in[22];

    char* base = (char*)d_ws;
    float* dtv  = (float*)(base + S_DTV);
    float* cs   = (float*)(base + S_CS);
    float* sums = (float*)(base + S_STAT);
    float* sumsq= sums + 256;
    float* scale= sums + 512;
    float* shift= sums + 768;
    u16*   cwbf = (u16*)(base + S_WPK);
    u16*   wbf  = (u16*)(base + S_HALO);
    u16*   halo = (u16*)(base + S_HALO);
    u16*   ht   = (u16*)(base + OFF_HT);
    u16*   xbc  = (u16*)(base + OFF_XBC);
    u16*   cb   = (u16*)(base + OFF_CBST + CB_OFF);
    u16*   st   = (u16*)(base + OFF_CBST + ST_OFF);
    u16*   zb   = (u16*)(base + OFF_CBST + Z_OFF);
    float* G    = (float*)(base + OFF_XBC);
    float* fbuf = (float*)(base + OFF_CBST + F_OFF);
    float* o1   = (float*)(base + OFF_CBST + O1_OFF);
    float* o2   = (float*)(base + OFF_CBST + O2_OFF);
    float* o3   = (float*)(base + OFF_CBST + O3_OFF);
    u16*   yproj= ht;

    // 1-2. stem conv as fused-im2col MFMA GEMM
    k_wcvt<<<64, 256, 0, stream>>>(conv_w, cwbf, 256 * 64);
    gemm_mfma<true, true><<<dim3(313, 2), 256, 0, stream>>>(
        x, cwbf, ht, (int)ROWS, 256, 64, 0, 256);

    // 3. BN batch stats + in-place BN+ReLU
    k_zero<<<2, 256, 0, stream>>>(sums, 512);
    k_bnstats<<<256, 256, 0, stream>>>(ht, sums, sumsq);
    k_bnfinal<<<1, 256, 0, stream>>>(sums, sumsq, bn_w, bn_b, scale, shift);
    k_bnapply<<<4998, 256, 0, stream>>>(ht, scale, shift);

    // 4. xBC projection (MFMA); dt projection
    k_wcvt<<<768, 256, 0, stream>>>(in_proj_w + 512L * 256, wbf, 768 * 256);
    gemm_mfma<false, true><<<dim3(313, 6), 256, 0, stream>>>(
        ht, wbf, xbc, (int)ROWS, 768, 256, 256, 768);
    k_dtproj<<<1250, 256, 0, stream>>>(ht, in_proj_w, dt_bias, dtv);

    // 5. in-place depthwise conv + SiLU; cumsum
    k_halo<<<2736, 256, 0, stream>>>(xbc, halo);
    k_dwip<<<960, 256, 0, stream>>>(xbc, halo, conv1d_w, conv1d_b);
    k_cs<<<2560, 128, 0, stream>>>(dtv, A_log, cs);

    // 6. SSD in two half-batches (all MFMA now)
    for (int bh = 0; bh < 2; ++bh) {
        int bo = bh * 8;
        k_cb<<<160, 256, 0, stream>>>(xbc, cb, bo);
        k_states<<<1280, 256, 0, stream>>>(xbc, dtv, cs, st, bo);
        k_scan<<<64, 256, 0, stream>>>(cs, st, bo);
        k_yout<<<1280, 256, 0, stream>>>(xbc, dtv, cs, cb, st, Dp, bo);
    }

    // 6.9. z projection (MFMA)
    k_wcvt<<<512, 256, 0, stream>>>(in_proj_w, wbf, 512 * 256);
    gemm_mfma<false, true><<<dim3(313, 4), 256, 0, stream>>>(
        ht, wbf, zb, (int)ROWS, 512, 256, 256, 512);

    // 7-8. gated RMSNorm + out_proj (MFMA)
    k_rmsnorm<<<39984, 256, 0, stream>>>(xbc, zb, norm_w);
    k_wcvt<<<512, 256, 0, stream>>>(out_proj_w, wbf, 256 * 512);
    gemm_mfma<false, true><<<dim3(313, 2), 256, 0, stream>>>(
        xbc, wbf, yproj, (int)ROWS, 256, 512, 768, 256);

    // 9. conv1 as MFMA GEMM + shifted gather
    k_wpack<<<128, 256, 0, stream>>>(conv1_w, wbf);
    gemm_mfma<false, false><<<dim3(313, 1), 256, 0, stream>>>(
        yproj, wbf, G, (int)ROWS, 128, 256, 256, 128);
    k_conv1<<<1250, 256, 0, stream>>>(G, conv1_b, fbuf);

    // 10. MLP head
    k_mlp1<<<512, 256, 0, stream>>>(fbuf, w1, b1, o1);
    k_mlp2<<<16, 256, 0, stream>>>(o1, w2, b2, o2);
    k_mlp3<<<16, 64, 0, stream>>>(o2, w3, b3, o3);
    k_mlp4<<<16, 64, 0, stream>>>(o3, w4, b4, (float*)d_out);
}

// Round 8
// 709.887 us; speedup vs baseline: 1.9277x; 1.0833x over previous
//
#include <hip/hip_runtime.h>
#include <math.h>

// ---------------- problem constants ----------------
constexpr int B    = 16;
constexpr int L    = 2499;        // conv-stem output length
constexpr int DIN  = 512;         // d_inner
constexpr int NH   = 8;
constexpr int DS   = 128;         // d_state
constexpr int NC   = 20;          // ceil(2499/128) chunks
constexpr int XBCD = 768;         // DIN + 2*DS
constexpr int FLAT = 19992;
constexpr int FLATP= 20000;       // padded to multiple of 32 for MFMA K-loop
constexpr long ROWS = (long)B * L;   // 39984

// ---------------- workspace layout (BYTE offsets) ----------------
constexpr size_t S_DTV  = 0;          // fp32 ROWS*8
constexpr size_t S_CS   = 1279488;    // fp32 16*8*20*128
constexpr size_t S_STAT = 2590208;    // fp32 1024
constexpr size_t S_WPK  = 2594304;    // conv_w bf16
constexpr size_t S_HALO = 2725376;    // rotating: xbcw-bf16 -> halo -> zw/outw/wpk bf16
constexpr size_t OFF_HT  = 4199936;   // bf16 ROWS*256 (ht -> u -> yproj)
constexpr size_t OFF_XBC = 24671744;  // bf16 ROWS*768 (xbc/y); later G bf16 ROWS*128
constexpr size_t OFF_CBST= 86087168;  // cb+st -> z bf16 -> MLP stage
constexpr size_t CB_OFF  = 0;         // bf16 8*20*128*128
constexpr size_t ST_OFF  = 5242880;   // bf16 8*20*8*8192
constexpr size_t Z_OFF   = 0;         // bf16 ROWS*512
// MLP-stage overlay of CBST (z dead after rmsnorm):
constexpr size_t F_OFF   = 0;         // bf16 16*20000 = 640,000
constexpr size_t O1A_OFF = 640000;    // fp32 16*512 accumulator
constexpr size_t O1_OFF  = 672768;    // fp32 16*512
constexpr size_t O2_OFF  = 705536;    // fp32 16*256
constexpr size_t O3_OFF  = 721920;    // fp32 16*64
constexpr size_t W1B_OFF = 726016;    // bf16 512*20000 = 20,480,000 (ends 21,206,016)
constexpr size_t WS_NEEDED = 127030784;

// ---------------- bf16 helpers ----------------
typedef unsigned short u16;
typedef __attribute__((ext_vector_type(8))) short bf16x8;
typedef __attribute__((ext_vector_type(4))) float f32x4;

__device__ __forceinline__ float bf2f(unsigned int u) {
    return __uint_as_float(u << 16);
}
__device__ __forceinline__ u16 f2bf(float f) {
    unsigned int x = __float_as_uint(f);
    unsigned int r = x + 0x7fffu + ((x >> 16) & 1u);
    return (u16)(r >> 16);
}
__device__ __forceinline__ unsigned int pk2(float a, float b) {
    return (unsigned int)f2bf(a) | ((unsigned int)f2bf(b) << 16);
}
__device__ __forceinline__ void ld8bf(const u16* p, float* o) {
    uint4 v = *(const uint4*)p;
    o[0]=bf2f(v.x&0xffffu); o[1]=bf2f(v.x>>16);
    o[2]=bf2f(v.y&0xffffu); o[3]=bf2f(v.y>>16);
    o[4]=bf2f(v.z&0xffffu); o[5]=bf2f(v.z>>16);
    o[6]=bf2f(v.w&0xffffu); o[7]=bf2f(v.w>>16);
}
__device__ __forceinline__ void ld4bf(const u16* p, float* o) {
    uint2 v = *(const uint2*)p;
    o[0]=bf2f(v.x&0xffffu); o[1]=bf2f(v.x>>16);
    o[2]=bf2f(v.y&0xffffu); o[3]=bf2f(v.y>>16);
}
__device__ __forceinline__ void st8bf(u16* p, const float* s) {
    uint4 v;
    v.x = pk2(s[0],s[1]); v.y = pk2(s[2],s[3]);
    v.z = pk2(s[4],s[5]); v.w = pk2(s[6],s[7]);
    *(uint4*)p = v;
}
__device__ __forceinline__ float siluf(float x) { return x / (1.f + expf(-x)); }

// ---------------- zero-init ----------------
__global__ __launch_bounds__(256) void k_zero(float* __restrict__ p, int n) {
    int i = blockIdx.x * 256 + threadIdx.x;
    if (i < n) p[i] = 0.f;
}

// ---------------- fp32 -> bf16 weight convert ----------------
__global__ __launch_bounds__(256) void k_wcvt(const float* __restrict__ src,
                                              u16* __restrict__ dst, int n) {
    int i = blockIdx.x * 256 + threadIdx.x;
    if (i < n) dst[i] = f2bf(src[i]);
}

// ---------------- w1 [512][19992] fp32 -> [512][20000] bf16, zero pad ----------------
__global__ __launch_bounds__(256) void k_w1cvt(const float* __restrict__ w1,
                                               u16* __restrict__ w1b) {
    long e0 = ((long)blockIdx.x * 256 + threadIdx.x) * 8;   // 5000 blocks exact
    int n = (int)(e0 / FLATP);
    int k = (int)(e0 - (long)n * FLATP);
    const float* src = w1 + (long)n * FLAT + k;
    u16* dst = w1b + e0;
    if (k + 8 <= FLAT) {
        float4 a = *(const float4*)src;
        float4 b = *(const float4*)(src + 4);
        *(uint4*)dst = (uint4){pk2(a.x,a.y), pk2(a.z,a.w), pk2(b.x,b.y), pk2(b.z,b.w)};
    } else {
        #pragma unroll
        for (int i = 0; i < 8; ++i)
            dst[i] = (k + i < FLAT) ? f2bf(src[i]) : (u16)0;
    }
}

// ---------------- MFMA GEMM: C[M,N] = A[M,K](bf16) @ Wb[N,K](bf16)^T ----------------
template <bool IM2COL, bool BF16OUT>
__global__ __launch_bounds__(256) void gemm_mfma(const void* __restrict__ Ap,
                                                 const u16* __restrict__ Wb,
                                                 void* __restrict__ Cp,
                                                 int M, int N, int K, int lda, int ldc) {
    __shared__ u16 Als[128 * 40];
    __shared__ u16 Bls[128 * 40];
    int tid = threadIdx.x;
    int wave = tid >> 6, lane = tid & 63;
    int wr = wave >> 1, wc = wave & 1;
    int m0 = blockIdx.x * 128, n0 = blockIdx.y * 128;
    int l15 = lane & 15, l4 = lane >> 4;
    int srow = tid >> 1, scol = (tid & 1) * 16;

    f32x4 acc[4][4];
    #pragma unroll
    for (int i = 0; i < 4; ++i)
        #pragma unroll
        for (int j = 0; j < 4; ++j)
            acc[i][j] = (f32x4){0.f, 0.f, 0.f, 0.f};

    for (int k0 = 0; k0 < K; k0 += 32) {
        {
            int am = m0 + srow;
            uint4 v0 = {0,0,0,0}, v1 = {0,0,0,0};
            if (am < M) {
                if (IM2COL) {
                    const float* x = (const float*)Ap;
                    int b = am / L, l = am - b * L;
                    int ic = (k0 + scol) >> 4;
                    const float* px = x + ((long)(b * 4 + ic)) * 20000 + l * 8;
                    float4 f0 = *(const float4*)(px);
                    float4 f1 = *(const float4*)(px + 4);
                    float4 f2 = *(const float4*)(px + 8);
                    float4 f3 = *(const float4*)(px + 12);
                    v0.x = pk2(f0.x,f0.y); v0.y = pk2(f0.z,f0.w);
                    v0.z = pk2(f1.x,f1.y); v0.w = pk2(f1.z,f1.w);
                    v1.x = pk2(f2.x,f2.y); v1.y = pk2(f2.z,f2.w);
                    v1.z = pk2(f3.x,f3.y); v1.w = pk2(f3.z,f3.w);
                } else {
                    const u16* pa = (const u16*)Ap + (long)am * lda + k0 + scol;
                    v0 = *(const uint4*)pa;
                    v1 = *(const uint4*)(pa + 8);
                }
            }
            *(uint4*)&Als[srow * 40 + scol]     = v0;
            *(uint4*)&Als[srow * 40 + scol + 8] = v1;
        }
        {
            const u16* pw = Wb + (long)(n0 + srow) * K + k0 + scol;
            *(uint4*)&Bls[srow * 40 + scol]     = *(const uint4*)pw;
            *(uint4*)&Bls[srow * 40 + scol + 8] = *(const uint4*)(pw + 8);
        }
        __syncthreads();

        bf16x8 af[4], bfr[4];
        #pragma unroll
        for (int i = 0; i < 4; ++i) {
            af[i]  = *(const bf16x8*)&Als[(wr * 64 + i * 16 + l15) * 40 + l4 * 8];
            bfr[i] = *(const bf16x8*)&Bls[(wc * 64 + i * 16 + l15) * 40 + l4 * 8];
        }
        #pragma unroll
        for (int i = 0; i < 4; ++i)
            #pragma unroll
            for (int j = 0; j < 4; ++j)
                acc[i][j] = __builtin_amdgcn_mfma_f32_16x16x32_bf16(
                    af[i], bfr[j], acc[i][j], 0, 0, 0);
        __syncthreads();
    }

    #pragma unroll
    for (int i = 0; i < 4; ++i) {
        #pragma unroll
        for (int j = 0; j < 4; ++j) {
            int n = n0 + wc * 64 + j * 16 + l15;
            #pragma unroll
            for (int r = 0; r < 4; ++r) {
                int m = m0 + wr * 64 + i * 16 + l4 * 4 + r;
                if (m < M) {
                    if (BF16OUT) ((u16*)Cp)[(long)m * ldc + n] = f2bf(acc[i][j][r]);
                    else         ((float*)Cp)[(long)m * ldc + n] = acc[i][j][r];
                }
            }
        }
    }
}

// ---------------- BN batch stats ----------------
__global__ __launch_bounds__(256) void k_bnstats(const u16* __restrict__ h,
                                                 float* __restrict__ sums,
                                                 float* __restrict__ sumsq) {
    int c = threadIdx.x;
    float s = 0.f, s2 = 0.f;
    for (long r = blockIdx.x; r < ROWS; r += gridDim.x) {
        float v = bf2f(h[r * 256 + c]);
        s += v; s2 += v * v;
    }
    atomicAdd(&sums[c], s);
    atomicAdd(&sumsq[c], s2);
}

__global__ __launch_bounds__(256) void k_bnfinal(const float* __restrict__ sums,
                                                 const float* __restrict__ sumsq,
                                                 const float* __restrict__ bn_w,
                                                 const float* __restrict__ bn_b,
                                                 float* __restrict__ scale,
                                                 float* __restrict__ shift) {
    int c = threadIdx.x;
    float mean = sums[c] / (float)ROWS;
    float var  = sumsq[c] / (float)ROWS - mean * mean;
    float inv  = rsqrtf(var + 1e-5f);
    float sc   = bn_w[c] * inv;
    scale[c] = sc;
    shift[c] = bn_b[c] - mean * sc;
}

// ---------------- in-place BN+ReLU ----------------
__global__ __launch_bounds__(256) void k_bnapply(u16* __restrict__ ht,
                                                 const float* __restrict__ scale,
                                                 const float* __restrict__ shift) {
    long i = ((long)blockIdx.x * 256 + threadIdx.x) * 8;
    int c = (int)(i & 255);
    float v[8];
    ld8bf(ht + i, v);
    float4 s0 = *(const float4*)(scale + c), s1 = *(const float4*)(scale + c + 4);
    float4 h0 = *(const float4*)(shift + c), h1 = *(const float4*)(shift + c + 4);
    v[0]=fmaxf(fmaf(v[0],s0.x,h0.x),0.f); v[1]=fmaxf(fmaf(v[1],s0.y,h0.y),0.f);
    v[2]=fmaxf(fmaf(v[2],s0.z,h0.z),0.f); v[3]=fmaxf(fmaf(v[3],s0.w,h0.w),0.f);
    v[4]=fmaxf(fmaf(v[4],s1.x,h1.x),0.f); v[5]=fmaxf(fmaf(v[5],s1.y,h1.y),0.f);
    v[6]=fmaxf(fmaf(v[6],s1.z,h1.z),0.f); v[7]=fmaxf(fmaf(v[7],s1.w,h1.w),0.f);
    st8bf(ht + i, v);
}

// ---------------- dt = softplus(u @ Wdt^T + dt_bias) ----------------
__global__ __launch_bounds__(256) void k_dtproj(const u16* __restrict__ u,
                                                const float* __restrict__ in_proj_w,
                                                const float* __restrict__ dt_bias,
                                                float* __restrict__ dtv) {
    long idx = (long)blockIdx.x * 256 + threadIdx.x;
    if (idx >= ROWS * 8) return;
    int h = (int)(idx & 7);
    long row = idx >> 3;
    const float* wr = in_proj_w + (long)(1280 + h) * 256;
    const u16* ar = u + row * 256;
    float acc = dt_bias[h];
    for (int k = 0; k < 256; ++k)
        acc = fmaf(bf2f(ar[k]), wr[k], acc);
    dtv[idx] = (acc > 20.f) ? acc : log1pf(expf(acc));
}

// ---------------- save 3-row halos ----------------
__global__ __launch_bounds__(256) void k_halo(const u16* __restrict__ xbc,
                                              u16* __restrict__ halo) {
    long idx = (long)blockIdx.x * 256 + threadIdx.x;
    if (idx >= 16L * 19 * 3 * 768) return;
    int ch = (int)(idx % 768);
    long t1 = idx / 768;
    int j = (int)(t1 % 3);
    long t2 = t1 / 3;
    int t = (int)(t2 % 19) + 1;
    int b = (int)(t2 / 19);
    halo[(((long)b * 20 + t) * 3 + j) * 768 + ch] =
        xbc[((long)b * L + t * 128 - 3 + j) * 768 + ch];
}

// ---------------- in-place depthwise causal conv1d + SiLU ----------------
__global__ __launch_bounds__(256) void k_dwip(u16* __restrict__ xbc,
                                              const u16* __restrict__ halo,
                                              const float* __restrict__ w,
                                              const float* __restrict__ bias) {
    int cg = blockIdx.x % 3;
    int t  = (blockIdx.x / 3) % 20;
    int b  = blockIdx.x / 60;
    int ch = cg * 256 + threadIdx.x;
    int l0 = t * 128, l1 = min(l0 + 128, L);
    float W0 = w[ch*4+0], W1 = w[ch*4+1], W2 = w[ch*4+2], W3 = w[ch*4+3];
    float bs = bias[ch];
    float p0 = 0.f, p1 = 0.f, p2 = 0.f;
    if (t > 0) {
        const u16* hp = halo + (((long)b * 20 + t) * 3) * 768 + ch;
        p0 = bf2f(hp[0]); p1 = bf2f(hp[768]); p2 = bf2f(hp[1536]);
    }
    u16* base = xbc + ((long)b * L + l0) * 768 + ch;
    for (int l = l0; l < l1; ++l) {
        float p3 = bf2f(*base);
        float acc = fmaf(p0, W0, fmaf(p1, W1, fmaf(p2, W2, fmaf(p3, W3, bs))));
        *base = f2bf(siluf(acc));
        p0 = p1; p1 = p2; p2 = p3;
        base += 768;
    }
}

// ---------------- per-chunk inclusive cumsum of dA ----------------
__global__ __launch_bounds__(128) void k_cs(const float* __restrict__ dtv,
                                            const float* __restrict__ A_log,
                                            float* __restrict__ cs) {
    int c = blockIdx.x % NC;
    int h = (blockIdx.x / NC) % NH;
    int b = blockIdx.x / (NC * NH);
    int q = threadIdx.x;
    int lg = c * 128 + q;
    float Av = -expf(A_log[h]);
    float dA = 0.f;
    if (lg < L) dA = dtv[((long)b * L + lg) * 8 + h] * Av;
    __shared__ float buf[128];
    buf[q] = dA;
    __syncthreads();
    for (int off = 1; off < 128; off <<= 1) {
        float add = (q >= off) ? buf[q - off] : 0.f;
        __syncthreads();
        buf[q] += add;
        __syncthreads();
    }
    cs[(long)blockIdx.x * 128 + q] = buf[q];
}

// ---------------- cb[bl,c,l,s] = C[l]·B[s]  (MFMA) ----------------
__global__ __launch_bounds__(256) void k_cb(const u16* __restrict__ xbc,
                                            u16* __restrict__ cb, int bo) {
    int c = blockIdx.x % NC, bl = blockIdx.x / NC;
    int b = bo + bl;
    long bcl = blockIdx.x;
    __shared__ u16 Als[128 * 40];
    __shared__ u16 Bls[128 * 40];
    int tid = threadIdx.x;
    int wave = tid >> 6, lane = tid & 63;
    int wr = wave >> 1, wc = wave & 1;
    int l15 = lane & 15, l4 = lane >> 4;
    int srow = tid >> 1, scol = (tid & 1) * 16;

    f32x4 acc[4][4];
    #pragma unroll
    for (int i = 0; i < 4; ++i)
        #pragma unroll
        for (int j = 0; j < 4; ++j)
            acc[i][j] = (f32x4){0.f, 0.f, 0.f, 0.f};

    int lg = c * 128 + srow;
    const u16* prow = xbc + ((long)b * L + lg) * XBCD;

    for (int k0 = 0; k0 < 128; k0 += 32) {
        uint4 cv0 = {0,0,0,0}, cv1 = cv0, bv0 = cv0, bv1 = cv0;
        if (lg < L) {
            cv0 = *(const uint4*)(prow + 640 + k0 + scol);
            cv1 = *(const uint4*)(prow + 640 + k0 + scol + 8);
            bv0 = *(const uint4*)(prow + 512 + k0 + scol);
            bv1 = *(const uint4*)(prow + 512 + k0 + scol + 8);
        }
        *(uint4*)&Als[srow * 40 + scol]     = cv0;
        *(uint4*)&Als[srow * 40 + scol + 8] = cv1;
        *(uint4*)&Bls[srow * 40 + scol]     = bv0;
        *(uint4*)&Bls[srow * 40 + scol + 8] = bv1;
        __syncthreads();

        bf16x8 af[4], bfr[4];
        #pragma unroll
        for (int i = 0; i < 4; ++i) {
            af[i]  = *(const bf16x8*)&Als[(wr * 64 + i * 16 + l15) * 40 + l4 * 8];
            bfr[i] = *(const bf16x8*)&Bls[(wc * 64 + i * 16 + l15) * 40 + l4 * 8];
        }
        #pragma unroll
        for (int i = 0; i < 4; ++i)
            #pragma unroll
            for (int j = 0; j < 4; ++j)
                acc[i][j] = __builtin_amdgcn_mfma_f32_16x16x32_bf16(
                    af[i], bfr[j], acc[i][j], 0, 0, 0);
        __syncthreads();
    }

    #pragma unroll
    for (int i = 0; i < 4; ++i)
        #pragma unroll
        for (int j = 0; j < 4; ++j) {
            int n = wc * 64 + j * 16 + l15;
            #pragma unroll
            for (int r = 0; r < 4; ++r) {
                int m = wr * 64 + i * 16 + l4 * 4 + r;
                cb[(bcl * 128 + m) * 128 + n] = f2bf(acc[i][j][r]);
            }
        }
}

// ---------------- states S[n,p] (MFMA, transposed staging) ----------------
__global__ __launch_bounds__(256) void k_states(const u16* __restrict__ xbc,
                                                const float* __restrict__ dtv,
                                                const float* __restrict__ cs,
                                                u16* __restrict__ st, int bo) {
    int h = blockIdx.x & 7;
    int c = (blockIdx.x >> 3) % NC;
    int bl = blockIdx.x / (8 * NC);
    int b = bo + bl;
    __shared__ u16 At[128][136];
    __shared__ u16 Bt[64][136];
    long csbase = (((long)b * 8 + h) * NC + c) * 128;
    float csLast = cs[csbase + 127];
    int tid = threadIdx.x;
    int lane = tid & 63, wave = tid >> 6;
    int wr = wave >> 1, wc = wave & 1;
    int l15 = lane & 15, l4 = lane >> 4;

    int l0 = 2 * (tid & 63), l1 = l0 + 1;
    int q = tid >> 6;
    int lg0 = c * 128 + l0, lg1 = c * 128 + l1;
    long row0 = (long)b * L + lg0, row1 = row0 + 1;
    float wl0 = 0.f, wl1 = 0.f, dt0 = 0.f, dt1 = 0.f;
    if (lg0 < L) { wl0 = expf(csLast - cs[csbase + l0]); dt0 = dtv[row0 * 8 + h]; }
    if (lg1 < L) { wl1 = expf(csLast - cs[csbase + l1]); dt1 = dtv[row1 * 8 + h]; }

    #pragma unroll
    for (int nb = 0; nb < 4; ++nb) {
        int n0 = q * 32 + nb * 8;
        float a0[8] = {0,0,0,0,0,0,0,0}, a1[8] = {0,0,0,0,0,0,0,0};
        if (lg0 < L) ld8bf(xbc + row0 * XBCD + 512 + n0, a0);
        if (lg1 < L) ld8bf(xbc + row1 * XBCD + 512 + n0, a1);
        #pragma unroll
        for (int i = 0; i < 8; ++i)
            *(unsigned int*)&At[n0 + i][l0] = pk2(a0[i] * wl0, a1[i] * wl1);
    }
    #pragma unroll
    for (int pb = 0; pb < 2; ++pb) {
        int p0 = q * 16 + pb * 8;
        float a0[8] = {0,0,0,0,0,0,0,0}, a1[8] = {0,0,0,0,0,0,0,0};
        if (lg0 < L) ld8bf(xbc + row0 * XBCD + h * 64 + p0, a0);
        if (lg1 < L) ld8bf(xbc + row1 * XBCD + h * 64 + p0, a1);
        #pragma unroll
        for (int i = 0; i < 8; ++i)
            *(unsigned int*)&Bt[p0 + i][l0] = pk2(a0[i] * dt0, a1[i] * dt1);
    }
    __syncthreads();

    f32x4 acc[4][2];
    #pragma unroll
    for (int i = 0; i < 4; ++i)
        #pragma unroll
        for (int j = 0; j < 2; ++j)
            acc[i][j] = (f32x4){0.f, 0.f, 0.f, 0.f};

    #pragma unroll
    for (int k0 = 0; k0 < 128; k0 += 32) {
        bf16x8 af[4], bfr[2];
        #pragma unroll
        for (int i = 0; i < 4; ++i)
            af[i] = *(const bf16x8*)&At[wr * 64 + i * 16 + l15][k0 + l4 * 8];
        #pragma unroll
        for (int j = 0; j < 2; ++j)
            bfr[j] = *(const bf16x8*)&Bt[wc * 32 + j * 16 + l15][k0 + l4 * 8];
        #pragma unroll
        for (int i = 0; i < 4; ++i)
            #pragma unroll
            for (int j = 0; j < 2; ++j)
                acc[i][j] = __builtin_amdgcn_mfma_f32_16x16x32_bf16(
                    af[i], bfr[j], acc[i][j], 0, 0, 0);
    }

    long basep = (long)blockIdx.x * 8192;
    #pragma unroll
    for (int i = 0; i < 4; ++i)
        #pragma unroll
        for (int j = 0; j < 2; ++j) {
            int p = wc * 32 + j * 16 + l15;
            #pragma unroll
            for (int r = 0; r < 4; ++r) {
                int n = wr * 64 + i * 16 + l4 * 4 + r;
                st[basep + n * 64 + p] = f2bf(acc[i][j][r]);
            }
        }
}

// ---------------- inter-chunk scan (4x parallel: 256 blocks/half) ----------------
__global__ __launch_bounds__(256) void k_scan(const float* __restrict__ cs,
                                              u16* __restrict__ st, int bo) {
    int h = blockIdx.x & 7, bl = (blockIdx.x >> 3) & 7, q = blockIdx.x >> 6;
    int b = bo + bl;
    int tid = threadIdx.x;
    float carry[8];
    #pragma unroll
    for (int i = 0; i < 8; ++i) carry[i] = 0.f;
    long csbase = ((long)b * 8 + h) * NC * 128;
    for (int c = 0; c < NC; ++c) {
        float cd = expf(cs[csbase + c * 128 + 127]);
        u16* p = st + (((long)bl * NC + c) * 8 + h) * 8192 + q * 2048;
        #pragma unroll
        for (int i = 0; i < 8; ++i) {
            int e = tid + i * 256;
            float v = bf2f(p[e]);
            p[e] = f2bf(carry[i]);
            carry[i] = carry[i] * cd + v;
        }
    }
}

// ---------------- Ydiag + Yoff + D-skip (MFMA, 2-phase accumulate) ----------------
__global__ __launch_bounds__(256) void k_yout(u16* __restrict__ xbc,
                                              const float* __restrict__ dtv,
                                              const float* __restrict__ cs,
                                              const u16* __restrict__ cb,
                                              const u16* __restrict__ st,
                                              const float* __restrict__ Dv, int bo) {
    int h = blockIdx.x & 7;
    int c = (blockIdx.x >> 3) % NC;
    int bl = blockIdx.x / (8 * NC);
    int b = bo + bl;
    long bcl = (long)bl * NC + c;
    __shared__ u16 Am[128][136];
    __shared__ u16 Bt[64][136];
    __shared__ float csb[128], ecs[128];
    int tid = threadIdx.x;
    long csbase = (((long)b * 8 + h) * NC + c) * 128;
    if (tid < 128) {
        float v = cs[csbase + tid];
        csb[tid] = v;
        ecs[tid] = expf(v);
    }
    __syncthreads();

    int lane = tid & 63, wave = tid >> 6;
    int wr = wave >> 1, wc = wave & 1;
    int l15 = lane & 15, l4 = lane >> 4;
    int lrow = tid >> 1, sh = (tid & 1) * 64;
    int l0 = 2 * (tid & 63), l1 = l0 + 1;
    int q = tid >> 6;
    int lg0 = c * 128 + l0, lg1 = c * 128 + l1;
    long row0 = (long)b * L + lg0, row1 = row0 + 1;

    // phase 1 staging
    {
        float cl = csb[lrow];
        const u16* cbrow = cb + (bcl * 128 + lrow) * 128;
        #pragma unroll
        for (int sb = 0; sb < 8; ++sb) {
            int s0 = sh + sb * 8;
            float a[8];
            ld8bf(cbrow + s0, a);
            #pragma unroll
            for (int i = 0; i < 8; ++i) {
                int s = s0 + i;
                float w = (s <= lrow) ? expf(cl - csb[s]) : 0.f;
                a[i] *= w;
            }
            st8bf(&Am[lrow][s0], a);
        }
        float dt0 = 0.f, dt1 = 0.f;
        if (lg0 < L) dt0 = dtv[row0 * 8 + h];
        if (lg1 < L) dt1 = dtv[row1 * 8 + h];
        #pragma unroll
        for (int pb = 0; pb < 2; ++pb) {
            int p0 = q * 16 + pb * 8;
            float a0[8] = {0,0,0,0,0,0,0,0}, a1[8] = {0,0,0,0,0,0,0,0};
            if (lg0 < L) ld8bf(xbc + row0 * XBCD + h * 64 + p0, a0);
            if (lg1 < L) ld8bf(xbc + row1 * XBCD + h * 64 + p0, a1);
            #pragma unroll
            for (int i = 0; i < 8; ++i)
                *(unsigned int*)&Bt[p0 + i][l0] = pk2(a0[i] * dt0, a1[i] * dt1);
        }
    }
    __syncthreads();

    f32x4 acc[4][2];
    #pragma unroll
    for (int i = 0; i < 4; ++i)
        #pragma unroll
        for (int j = 0; j < 2; ++j)
            acc[i][j] = (f32x4){0.f, 0.f, 0.f, 0.f};

    #pragma unroll
    for (int k0 = 0; k0 < 128; k0 += 32) {
        bf16x8 af[4], bfr[2];
        #pragma unroll
        for (int i = 0; i < 4; ++i)
            af[i] = *(const bf16x8*)&Am[wr * 64 + i * 16 + l15][k0 + l4 * 8];
        #pragma unroll
        for (int j = 0; j < 2; ++j)
            bfr[j] = *(const bf16x8*)&Bt[wc * 32 + j * 16 + l15][k0 + l4 * 8];
        #pragma unroll
        for (int i = 0; i < 4; ++i)
            #pragma unroll
            for (int j = 0; j < 2; ++j)
                acc[i][j] = __builtin_amdgcn_mfma_f32_16x16x32_bf16(
                    af[i], bfr[j], acc[i][j], 0, 0, 0);
    }
    __syncthreads();

    // phase 2 staging
    {
        float el = ecs[lrow];
        int lgr = c * 128 + lrow;
        const u16* xr = xbc + ((long)b * L + lgr) * XBCD + 640;
        #pragma unroll
        for (int nb = 0; nb < 8; ++nb) {
            int n0 = sh + nb * 8;
            float a[8] = {0,0,0,0,0,0,0,0};
            if (lgr < L) {
                ld8bf(xr + n0, a);
                #pragma unroll
                for (int i = 0; i < 8; ++i) a[i] *= el;
            }
            st8bf(&Am[lrow][n0], a);
        }
        const u16* pv = st + (bcl * 8 + h) * 8192;
        #pragma unroll
        for (int pb = 0; pb < 2; ++pb) {
            int p0 = q * 16 + pb * 8;
            float a0[8], a1[8];
            ld8bf(pv + (long)l0 * 64 + p0, a0);
            ld8bf(pv + (long)l1 * 64 + p0, a1);
            #pragma unroll
            for (int i = 0; i < 8; ++i)
                *(unsigned int*)&Bt[p0 + i][l0] = pk2(a0[i], a1[i]);
        }
    }
    __syncthreads();

    #pragma unroll
    for (int k0 = 0; k0 < 128; k0 += 32) {
        bf16x8 af[4], bfr[2];
        #pragma unroll
        for (int i = 0; i < 4; ++i)
            af[i] = *(const bf16x8*)&Am[wr * 64 + i * 16 + l15][k0 + l4 * 8];
        #pragma unroll
        for (int j = 0; j < 2; ++j)
            bfr[j] = *(const bf16x8*)&Bt[wc * 32 + j * 16 + l15][k0 + l4 * 8];
        #pragma unroll
        for (int i = 0; i < 4; ++i)
            #pragma unroll
            for (int j = 0; j < 2; ++j)
                acc[i][j] = __builtin_amdgcn_mfma_f32_16x16x32_bf16(
                    af[i], bfr[j], acc[i][j], 0, 0, 0);
    }

    // epilogue: + D*xh, overwrite x-part in place
    float Dh = Dv[h];
    #pragma unroll
    for (int i = 0; i < 4; ++i)
        #pragma unroll
        for (int r = 0; r < 4; ++r) {
            int l = wr * 64 + i * 16 + l4 * 4 + r;
            int lg = c * 128 + l;
            if (lg >= L) continue;
            long row = (long)b * L + lg;
            #pragma unroll
            for (int j = 0; j < 2; ++j) {
                int p = wc * 32 + j * 16 + l15;
                u16* xp = xbc + row * XBCD + h * 64 + p;
                float xv = bf2f(*xp);
                *xp = f2bf(fmaf(Dh, xv, acc[i][j][r]));
            }
        }
}

// ---------------- gated RMSNorm ----------------
__global__ __launch_bounds__(256) void k_rmsnorm(u16* __restrict__ y,
                                                 const u16* __restrict__ z,
                                                 const float* __restrict__ nw) {
    long r = blockIdx.x;
    int tid = threadIdx.x;
    float v0 = bf2f(y[r * XBCD + tid]), v1 = bf2f(y[r * XBCD + 256 + tid]);
    float z0 = bf2f(z[r * DIN + tid]),  z1 = bf2f(z[r * DIN + 256 + tid]);
    v0 *= siluf(z0);
    v1 *= siluf(z1);
    __shared__ float red[256];
    red[tid] = v0 * v0 + v1 * v1;
    __syncthreads();
    for (int s = 128; s > 0; s >>= 1) {
        if (tid < s) red[tid] += red[tid + s];
        __syncthreads();
    }
    float sc = rsqrtf(red[0] / 512.f + 1e-5f);
    y[r * XBCD + tid]       = f2bf(v0 * sc * nw[tid]);
    y[r * XBCD + 256 + tid] = f2bf(v1 * sc * nw[256 + tid]);
}

// ---------------- repack conv1_w ----------------
__global__ __launch_bounds__(256) void k_wpack(const float* __restrict__ w,
                                               u16* __restrict__ wp) {
    int idx = blockIdx.x * 256 + threadIdx.x;
    if (idx >= 8 * 256 * 16) return;
    int k = idx & 15;
    int cidx = (idx >> 4) & 255;
    int s = idx >> 12;
    wp[(s * 16 + k) * 256 + cidx] = f2bf(w[idx]);
}

// ---------------- conv1 combine: G bf16 in, f bf16 [16][20000] out + pad ----------------
__global__ __launch_bounds__(256) void k_conv1(const u16* __restrict__ G,
                                               const float* __restrict__ bias,
                                               u16* __restrict__ f) {
    long idx = (long)blockIdx.x * 256 + threadIdx.x;
    if (idx >= (long)B * 8 * L) {
        long j = idx - (long)B * 8 * L;      // 128 spare threads zero the pad
        if (j < 16 * 8)
            f[(j >> 3) * FLATP + FLAT + (j & 7)] = 0;
        return;
    }
    int l = (int)(idx % L);
    long t = idx / L;
    int s = (int)(t & 7);
    int b = (int)(t >> 3);
    float acc = bias[s];
    #pragma unroll
    for (int k = 0; k < 16; ++k) {
        int ls = l + k - 7;
        if (ls >= 0 && ls < L)
            acc += bf2f(G[((long)b * L + ls) * 128 + s * 16 + k]);
    }
    f[(long)b * FLATP + s * L + l] = f2bf(acc);
}

// ---------------- MLP1: o1acc[16][512] += f[16][20000] @ w1b[512][20000]^T (MFMA) ----------------
__global__ __launch_bounds__(256) void k_mlp1(const u16* __restrict__ fb,
                                              const u16* __restrict__ w1b,
                                              float* __restrict__ o1acc) {
    int wave = threadIdx.x >> 6, lane = threadIdx.x & 63;
    int l15 = lane & 15, l4 = lane >> 4;
    int n0 = blockIdx.x * 64 + wave * 16;     // 8 x-blocks
    int k0 = blockIdx.y * 800;                // 25 y-blocks
    const u16* fp = fb + (long)l15 * FLATP + k0 + l4 * 8;
    const u16* wp = w1b + (long)(n0 + l15) * FLATP + k0 + l4 * 8;
    f32x4 acc = (f32x4){0.f, 0.f, 0.f, 0.f};
    #pragma unroll
    for (int kk = 0; kk < 25; ++kk) {
        bf16x8 af = *(const bf16x8*)fp;
        bf16x8 bf = *(const bf16x8*)wp;
        acc = __builtin_amdgcn_mfma_f32_16x16x32_bf16(af, bf, acc, 0, 0, 0);
        fp += 32; wp += 32;
    }
    #pragma unroll
    for (int r = 0; r < 4; ++r) {
        int b = l4 * 4 + r;
        atomicAdd(&o1acc[b * 512 + n0 + l15], acc[r]);
    }
}

__global__ __launch_bounds__(256) void k_mlp1fin(const float* __restrict__ o1acc,
                                                 const float* __restrict__ b1,
                                                 float* __restrict__ o1) {
    int i = blockIdx.x * 256 + threadIdx.x;   // 32 blocks, 8192 elems
    o1[i] = fmaxf(o1acc[i] + b1[i & 511], 0.f);
}

__global__ __launch_bounds__(256) void k_mlp2(const float* __restrict__ in,
                                              const float* __restrict__ w,
                                              const float* __restrict__ bias,
                                              float* __restrict__ out) {
    int b = blockIdx.x, n = threadIdx.x;
    const float* ir = in + b * 512;
    const float* wr = w + (long)n * 512;
    float acc = 0.f;
    for (int k = 0; k < 512; ++k) acc = fmaf(ir[k], wr[k], acc);
    out[b * 256 + n] = fmaxf(acc + bias[n], 0.f);
}

__global__ __launch_bounds__(64) void k_mlp3(const float* __restrict__ in,
                                             const float* __restrict__ w,
                                             const float* __restrict__ bias,
                                             float* __restrict__ out) {
    int b = blockIdx.x, n = threadIdx.x;
    const float* ir = in + b * 256;
    const float* wr = w + (long)n * 256;
    float acc = 0.f;
    for (int k = 0; k < 256; ++k) acc = fmaf(ir[k], wr[k], acc);
    out[b * 64 + n] = fmaxf(acc + bias[n], 0.f);
}

__global__ __launch_bounds__(64) void k_mlp4(const float* __restrict__ in,
                                             const float* __restrict__ w4,
                                             const float* __restrict__ b4,
                                             float* __restrict__ dout) {
    int b = blockIdx.x, k = threadIdx.x;
    float v = in[b * 64 + k] * w4[k];
    #pragma unroll
    for (int off = 32; off > 0; off >>= 1) v += __shfl_down(v, off);
    if (k == 0) dout[b] = v + b4[0];
}

// ---------------- host launcher ----------------
extern "C" void kernel_launch(void* const* d_in, const int* in_sizes, int n_in,
                              void* d_out, int out_size, void* d_ws, size_t ws_size,
                              hipStream_t stream) {
    (void)in_sizes; (void)n_in; (void)out_size;
    if (ws_size < WS_NEEDED) return;

    const float* x         = (const float*)d_in[0];
    const float* conv_w    = (const float*)d_in[1];
    // conv_b (d_in[2]) cancels under batch-stat BN — unused
    const float* bn_w      = (const float*)d_in[3];
    const float* bn_b      = (const float*)d_in[4];
    const float* in_proj_w = (const float*)d_in[5];
    const float* conv1d_w  = (const float*)d_in[6];
    const float* conv1d_b  = (const float*)d_in[7];
    const float* dt_bias   = (const float*)d_in[8];
    const float* A_log     = (const float*)d_in[9];
    const float* Dp        = (const float*)d_in[10];
    const float* norm_w    = (const float*)d_in[11];
    const float* out_proj_w= (const float*)d_in[12];
    const float* conv1_w   = (const float*)d_in[13];
    const float* conv1_b   = (const float*)d_in[14];
    const float* w1 = (const float*)d_in[15]; const float* b1 = (const float*)d_in[16];
    const float* w2 = (const float*)d_in[17]; const float* b2 = (const float*)d_in[18];
    const float* w3 = (const float*)d_in[19]; const float* b3 = (const float*)d_in[20];
    const float* w4 = (const float*)d_in[21]; const float* b4 = (const float*)d_in[22];

    char* base = (char*)d_ws;
    float* dtv  = (float*)(base + S_DTV);
    float* cs   = (float*)(base + S_CS);
    float* sums = (float*)(base + S_STAT);
    float* sumsq= sums + 256;
    float* scale= sums + 512;
    float* shift= sums + 768;
    u16*   cwbf = (u16*)(base + S_WPK);
    u16*   wbf  = (u16*)(base + S_HALO);
    u16*   halo = (u16*)(base + S_HALO);
    u16*   ht   = (u16*)(base + OFF_HT);
    u16*   xbc  = (u16*)(base + OFF_XBC);
    u16*   cb   = (u16*)(base + OFF_CBST + CB_OFF);
    u16*   st   = (u16*)(base + OFF_CBST + ST_OFF);
    u16*   zb   = (u16*)(base + OFF_CBST + Z_OFF);
    u16*   G    = (u16*)(base + OFF_XBC);
    u16*   fbuf = (u16*)(base + OFF_CBST + F_OFF);
    float* o1a  = (float*)(base + OFF_CBST + O1A_OFF);
    float* o1   = (float*)(base + OFF_CBST + O1_OFF);
    float* o2   = (float*)(base + OFF_CBST + O2_OFF);
    float* o3   = (float*)(base + OFF_CBST + O3_OFF);
    u16*   w1b  = (u16*)(base + OFF_CBST + W1B_OFF);
    u16*   yproj= ht;

    // 1-2. stem conv as fused-im2col MFMA GEMM
    k_wcvt<<<64, 256, 0, stream>>>(conv_w, cwbf, 256 * 64);
    gemm_mfma<true, true><<<dim3(313, 2), 256, 0, stream>>>(
        x, cwbf, ht, (int)ROWS, 256, 64, 0, 256);

    // 3. BN batch stats + in-place BN+ReLU
    k_zero<<<2, 256, 0, stream>>>(sums, 512);
    k_bnstats<<<256, 256, 0, stream>>>(ht, sums, sumsq);
    k_bnfinal<<<1, 256, 0, stream>>>(sums, sumsq, bn_w, bn_b, scale, shift);
    k_bnapply<<<4998, 256, 0, stream>>>(ht, scale, shift);

    // 4. xBC projection (MFMA); dt projection
    k_wcvt<<<768, 256, 0, stream>>>(in_proj_w + 512L * 256, wbf, 768 * 256);
    gemm_mfma<false, true><<<dim3(313, 6), 256, 0, stream>>>(
        ht, wbf, xbc, (int)ROWS, 768, 256, 256, 768);
    k_dtproj<<<1250, 256, 0, stream>>>(ht, in_proj_w, dt_bias, dtv);

    // 5. in-place depthwise conv + SiLU; cumsum
    k_halo<<<2736, 256, 0, stream>>>(xbc, halo);
    k_dwip<<<960, 256, 0, stream>>>(xbc, halo, conv1d_w, conv1d_b);
    k_cs<<<2560, 128, 0, stream>>>(dtv, A_log, cs);

    // 6. SSD in two half-batches (all MFMA)
    for (int bh = 0; bh < 2; ++bh) {
        int bo = bh * 8;
        k_cb<<<160, 256, 0, stream>>>(xbc, cb, bo);
        k_states<<<1280, 256, 0, stream>>>(xbc, dtv, cs, st, bo);
        k_scan<<<256, 256, 0, stream>>>(cs, st, bo);
        k_yout<<<1280, 256, 0, stream>>>(xbc, dtv, cs, cb, st, Dp, bo);
    }

    // 6.9. z projection (MFMA)
    k_wcvt<<<512, 256, 0, stream>>>(in_proj_w, wbf, 512 * 256);
    gemm_mfma<false, true><<<dim3(313, 4), 256, 0, stream>>>(
        ht, wbf, zb, (int)ROWS, 512, 256, 256, 512);

    // 7-8. gated RMSNorm + out_proj (MFMA)
    k_rmsnorm<<<39984, 256, 0, stream>>>(xbc, zb, norm_w);
    k_wcvt<<<512, 256, 0, stream>>>(out_proj_w, wbf, 256 * 512);
    gemm_mfma<false, true><<<dim3(313, 2), 256, 0, stream>>>(
        xbc, wbf, yproj, (int)ROWS, 256, 512, 768, 256);

    // 9. conv1 as MFMA GEMM (G bf16) + shifted gather (fbuf bf16 padded)
    k_wpack<<<128, 256, 0, stream>>>(conv1_w, wbf);
    gemm_mfma<false, true><<<dim3(313, 1), 256, 0, stream>>>(
        yproj, wbf, G, (int)ROWS, 128, 256, 256, 128);
    k_conv1<<<1250, 256, 0, stream>>>(G, conv1_b, fbuf);

    // 10. MLP head (mlp1 as bf16 MFMA split-K)
    k_w1cvt<<<5000, 256, 0, stream>>>(w1, w1b);
    k_zero<<<32, 256, 0, stream>>>(o1a, 8192);
    k_mlp1<<<dim3(8, 25), 256, 0, stream>>>(fbuf, w1b, o1a);
    k_mlp1fin<<<32, 256, 0, stream>>>(o1a, b1, o1);
    k_mlp2<<<16, 256, 0, stream>>>(o1, w2, b2, o2);
    k_mlp3<<<16, 64, 0, stream>>>(o2, w3, b3, o3);
    k_mlp4<<<16, 64, 0, stream>>>(o3, w4, b4, (float*)d_out);
}

// Round 10
// 669.911 us; speedup vs baseline: 2.0427x; 1.0597x over previous
//
#include <hip/hip_runtime.h>
#include <math.h>

// ---------------- problem constants ----------------
constexpr int B    = 16;
constexpr int L    = 2499;        // conv-stem output length
constexpr int DIN  = 512;         // d_inner
constexpr int NH   = 8;
constexpr int DS   = 128;         // d_state
constexpr int NC   = 20;          // ceil(2499/128) chunks
constexpr int XBCD = 768;         // DIN + 2*DS
constexpr int FLAT = 19992;
constexpr int FLATP= 20000;       // padded to multiple of 32 for MFMA K-loop
constexpr long ROWS = (long)B * L;   // 39984
constexpr float LOG2E = 1.4426950408889634f;

// ---------------- workspace layout (BYTE offsets) ----------------
constexpr size_t S_DTV  = 0;          // fp32 ROWS*8
constexpr size_t S_CS   = 1279488;    // fp32 16*8*20*128 (stored pre-scaled by log2e)
constexpr size_t S_STAT = 2590208;    // fp32 1024
constexpr size_t S_WPK  = 2594304;    // conv_w bf16
constexpr size_t S_HALO = 2725376;    // rotating: xbcw-bf16 -> halo -> zw/outw/wpk bf16
constexpr size_t OFF_HT  = 4199936;   // bf16 ROWS*256 (ht -> u -> yproj)
constexpr size_t OFF_XBC = 24671744;  // bf16 ROWS*768 (xbc/y); later G bf16 ROWS*128
constexpr size_t OFF_CBST= 86087168;  // cb+st -> z bf16 -> MLP stage
constexpr size_t CB_OFF  = 0;         // bf16 8*20*128*128
constexpr size_t ST_OFF  = 5242880;   // bf16 8*20*8*8192
constexpr size_t Z_OFF   = 0;         // bf16 ROWS*512
// MLP-stage overlay of CBST (z dead after rmsnorm):
constexpr size_t F_OFF   = 0;         // bf16 16*20000 = 640,000
constexpr size_t O1A_OFF = 640000;    // fp32 16*512 accumulator
constexpr size_t O1_OFF  = 672768;    // fp32 16*512
constexpr size_t O2_OFF  = 705536;    // fp32 16*256
constexpr size_t O3_OFF  = 721920;    // fp32 16*64
constexpr size_t W1B_OFF = 726016;    // bf16 512*20000 = 20,480,000
constexpr size_t WS_NEEDED = 127030784;

// ---------------- bf16 helpers ----------------
typedef unsigned short u16;
typedef __attribute__((ext_vector_type(8))) short bf16x8;
typedef __attribute__((ext_vector_type(4))) float f32x4;

__device__ __forceinline__ float bf2f(unsigned int u) {
    return __uint_as_float(u << 16);
}
__device__ __forceinline__ u16 f2bf(float f) {
    unsigned int x = __float_as_uint(f);
    unsigned int r = x + 0x7fffu + ((x >> 16) & 1u);
    return (u16)(r >> 16);
}
__device__ __forceinline__ unsigned int pk2(float a, float b) {
    return (unsigned int)f2bf(a) | ((unsigned int)f2bf(b) << 16);
}
__device__ __forceinline__ void ld8bf(const u16* p, float* o) {
    uint4 v = *(const uint4*)p;
    o[0]=bf2f(v.x&0xffffu); o[1]=bf2f(v.x>>16);
    o[2]=bf2f(v.y&0xffffu); o[3]=bf2f(v.y>>16);
    o[4]=bf2f(v.z&0xffffu); o[5]=bf2f(v.z>>16);
    o[6]=bf2f(v.w&0xffffu); o[7]=bf2f(v.w>>16);
}
__device__ __forceinline__ void ld4bf(const u16* p, float* o) {
    uint2 v = *(const uint2*)p;
    o[0]=bf2f(v.x&0xffffu); o[1]=bf2f(v.x>>16);
    o[2]=bf2f(v.y&0xffffu); o[3]=bf2f(v.y>>16);
}
__device__ __forceinline__ void st8bf(u16* p, const float* s) {
    uint4 v;
    v.x = pk2(s[0],s[1]); v.y = pk2(s[2],s[3]);
    v.z = pk2(s[4],s[5]); v.w = pk2(s[6],s[7]);
    *(uint4*)p = v;
}
__device__ __forceinline__ float siluf(float x) { return x / (1.f + expf(-x)); }

// ---------------- zero-init ----------------
__global__ __launch_bounds__(256) void k_zero(float* __restrict__ p, int n) {
    int i = blockIdx.x * 256 + threadIdx.x;
    if (i < n) p[i] = 0.f;
}

// ---------------- fp32 -> bf16 weight convert ----------------
__global__ __launch_bounds__(256) void k_wcvt(const float* __restrict__ src,
                                              u16* __restrict__ dst, int n) {
    int i = blockIdx.x * 256 + threadIdx.x;
    if (i < n) dst[i] = f2bf(src[i]);
}

// ---------------- w1 [512][19992] fp32 -> [512][20000] bf16, zero pad ----------------
__global__ __launch_bounds__(256) void k_w1cvt(const float* __restrict__ w1,
                                               u16* __restrict__ w1b) {
    long e0 = ((long)blockIdx.x * 256 + threadIdx.x) * 8;   // 5000 blocks exact
    int n = (int)(e0 / FLATP);
    int k = (int)(e0 - (long)n * FLATP);
    const float* src = w1 + (long)n * FLAT + k;
    u16* dst = w1b + e0;
    if (k + 8 <= FLAT) {
        float4 a = *(const float4*)src;
        float4 b = *(const float4*)(src + 4);
        *(uint4*)dst = (uint4){pk2(a.x,a.y), pk2(a.z,a.w), pk2(b.x,b.y), pk2(b.z,b.w)};
    } else {
        #pragma unroll
        for (int i = 0; i < 8; ++i)
            dst[i] = (k + i < FLAT) ? f2bf(src[i]) : (u16)0;
    }
}

// ---------------- MFMA GEMM: C[M,N] = A[M,K](bf16) @ Wb[N,K](bf16)^T ----------------
template <bool IM2COL, bool BF16OUT>
__global__ __launch_bounds__(256) void gemm_mfma(const void* __restrict__ Ap,
                                                 const u16* __restrict__ Wb,
                                                 void* __restrict__ Cp,
                                                 int M, int N, int K, int lda, int ldc) {
    __shared__ u16 Als[128 * 40];
    __shared__ u16 Bls[128 * 40];
    int tid = threadIdx.x;
    int wave = tid >> 6, lane = tid & 63;
    int wr = wave >> 1, wc = wave & 1;
    int m0 = blockIdx.x * 128, n0 = blockIdx.y * 128;
    int l15 = lane & 15, l4 = lane >> 4;
    int srow = tid >> 1, scol = (tid & 1) * 16;

    f32x4 acc[4][4];
    #pragma unroll
    for (int i = 0; i < 4; ++i)
        #pragma unroll
        for (int j = 0; j < 4; ++j)
            acc[i][j] = (f32x4){0.f, 0.f, 0.f, 0.f};

    for (int k0 = 0; k0 < K; k0 += 32) {
        {
            int am = m0 + srow;
            uint4 v0 = {0,0,0,0}, v1 = {0,0,0,0};
            if (am < M) {
                if (IM2COL) {
                    const float* x = (const float*)Ap;
                    int b = am / L, l = am - b * L;
                    int ic = (k0 + scol) >> 4;
                    const float* px = x + ((long)(b * 4 + ic)) * 20000 + l * 8;
                    float4 f0 = *(const float4*)(px);
                    float4 f1 = *(const float4*)(px + 4);
                    float4 f2 = *(const float4*)(px + 8);
                    float4 f3 = *(const float4*)(px + 12);
                    v0.x = pk2(f0.x,f0.y); v0.y = pk2(f0.z,f0.w);
                    v0.z = pk2(f1.x,f1.y); v0.w = pk2(f1.z,f1.w);
                    v1.x = pk2(f2.x,f2.y); v1.y = pk2(f2.z,f2.w);
                    v1.z = pk2(f3.x,f3.y); v1.w = pk2(f3.z,f3.w);
                } else {
                    const u16* pa = (const u16*)Ap + (long)am * lda + k0 + scol;
                    v0 = *(const uint4*)pa;
                    v1 = *(const uint4*)(pa + 8);
                }
            }
            *(uint4*)&Als[srow * 40 + scol]     = v0;
            *(uint4*)&Als[srow * 40 + scol + 8] = v1;
        }
        {
            const u16* pw = Wb + (long)(n0 + srow) * K + k0 + scol;
            *(uint4*)&Bls[srow * 40 + scol]     = *(const uint4*)pw;
            *(uint4*)&Bls[srow * 40 + scol + 8] = *(const uint4*)(pw + 8);
        }
        __syncthreads();

        bf16x8 af[4], bfr[4];
        #pragma unroll
        for (int i = 0; i < 4; ++i) {
            af[i]  = *(const bf16x8*)&Als[(wr * 64 + i * 16 + l15) * 40 + l4 * 8];
            bfr[i] = *(const bf16x8*)&Bls[(wc * 64 + i * 16 + l15) * 40 + l4 * 8];
        }
        #pragma unroll
        for (int i = 0; i < 4; ++i)
            #pragma unroll
            for (int j = 0; j < 4; ++j)
                acc[i][j] = __builtin_amdgcn_mfma_f32_16x16x32_bf16(
                    af[i], bfr[j], acc[i][j], 0, 0, 0);
        __syncthreads();
    }

    #pragma unroll
    for (int i = 0; i < 4; ++i) {
        #pragma unroll
        for (int j = 0; j < 4; ++j) {
            int n = n0 + wc * 64 + j * 16 + l15;
            #pragma unroll
            for (int r = 0; r < 4; ++r) {
                int m = m0 + wr * 64 + i * 16 + l4 * 4 + r;
                if (m < M) {
                    if (BF16OUT) ((u16*)Cp)[(long)m * ldc + n] = f2bf(acc[i][j][r]);
                    else         ((float*)Cp)[(long)m * ldc + n] = acc[i][j][r];
                }
            }
        }
    }
}

// ---------------- BN batch stats ----------------
__global__ __launch_bounds__(256) void k_bnstats(const u16* __restrict__ h,
                                                 float* __restrict__ sums,
                                                 float* __restrict__ sumsq) {
    int c = threadIdx.x;
    float s = 0.f, s2 = 0.f;
    for (long r = blockIdx.x; r < ROWS; r += gridDim.x) {
        float v = bf2f(h[r * 256 + c]);
        s += v; s2 += v * v;
    }
    atomicAdd(&sums[c], s);
    atomicAdd(&sumsq[c], s2);
}

__global__ __launch_bounds__(256) void k_bnfinal(const float* __restrict__ sums,
                                                 const float* __restrict__ sumsq,
                                                 const float* __restrict__ bn_w,
                                                 const float* __restrict__ bn_b,
                                                 float* __restrict__ scale,
                                                 float* __restrict__ shift) {
    int c = threadIdx.x;
    float mean = sums[c] / (float)ROWS;
    float var  = sumsq[c] / (float)ROWS - mean * mean;
    float inv  = rsqrtf(var + 1e-5f);
    float sc   = bn_w[c] * inv;
    scale[c] = sc;
    shift[c] = bn_b[c] - mean * sc;
}

// ---------------- in-place BN+ReLU ----------------
__global__ __launch_bounds__(256) void k_bnapply(u16* __restrict__ ht,
                                                 const float* __restrict__ scale,
                                                 const float* __restrict__ shift) {
    long i = ((long)blockIdx.x * 256 + threadIdx.x) * 8;
    int c = (int)(i & 255);
    float v[8];
    ld8bf(ht + i, v);
    float4 s0 = *(const float4*)(scale + c), s1 = *(const float4*)(scale + c + 4);
    float4 h0 = *(const float4*)(shift + c), h1 = *(const float4*)(shift + c + 4);
    v[0]=fmaxf(fmaf(v[0],s0.x,h0.x),0.f); v[1]=fmaxf(fmaf(v[1],s0.y,h0.y),0.f);
    v[2]=fmaxf(fmaf(v[2],s0.z,h0.z),0.f); v[3]=fmaxf(fmaf(v[3],s0.w,h0.w),0.f);
    v[4]=fmaxf(fmaf(v[4],s1.x,h1.x),0.f); v[5]=fmaxf(fmaf(v[5],s1.y,h1.y),0.f);
    v[6]=fmaxf(fmaf(v[6],s1.z,h1.z),0.f); v[7]=fmaxf(fmaf(v[7],s1.w,h1.w),0.f);
    st8bf(ht + i, v);
}

// ---------------- dt = softplus(u @ Wdt^T + dt_bias) ----------------
__global__ __launch_bounds__(256) void k_dtproj(const u16* __restrict__ u,
                                                const float* __restrict__ in_proj_w,
                                                const float* __restrict__ dt_bias,
                                                float* __restrict__ dtv) {
    long idx = (long)blockIdx.x * 256 + threadIdx.x;
    if (idx >= ROWS * 8) return;
    int h = (int)(idx & 7);
    long row = idx >> 3;
    const float* wr = in_proj_w + (long)(1280 + h) * 256;
    const u16* ar = u + row * 256;
    float acc = dt_bias[h];
    for (int k = 0; k < 256; ++k)
        acc = fmaf(bf2f(ar[k]), wr[k], acc);
    dtv[idx] = (acc > 20.f) ? acc : log1pf(expf(acc));
}

// ---------------- save 3-row halos ----------------
__global__ __launch_bounds__(256) void k_halo(const u16* __restrict__ xbc,
                                              u16* __restrict__ halo) {
    long idx = (long)blockIdx.x * 256 + threadIdx.x;
    if (idx >= 16L * 19 * 3 * 768) return;
    int ch = (int)(idx % 768);
    long t1 = idx / 768;
    int j = (int)(t1 % 3);
    long t2 = t1 / 3;
    int t = (int)(t2 % 19) + 1;
    int b = (int)(t2 / 19);
    halo[(((long)b * 20 + t) * 3 + j) * 768 + ch] =
        xbc[((long)b * L + t * 128 - 3 + j) * 768 + ch];
}

// ---------------- in-place depthwise causal conv1d + SiLU ----------------
__global__ __launch_bounds__(256) void k_dwip(u16* __restrict__ xbc,
                                              const u16* __restrict__ halo,
                                              const float* __restrict__ w,
                                              const float* __restrict__ bias) {
    int cg = blockIdx.x % 3;
    int t  = (blockIdx.x / 3) % 20;
    int b  = blockIdx.x / 60;
    int ch = cg * 256 + threadIdx.x;
    int l0 = t * 128, l1 = min(l0 + 128, L);
    float W0 = w[ch*4+0], W1 = w[ch*4+1], W2 = w[ch*4+2], W3 = w[ch*4+3];
    float bs = bias[ch];
    float p0 = 0.f, p1 = 0.f, p2 = 0.f;
    if (t > 0) {
        const u16* hp = halo + (((long)b * 20 + t) * 3) * 768 + ch;
        p0 = bf2f(hp[0]); p1 = bf2f(hp[768]); p2 = bf2f(hp[1536]);
    }
    u16* base = xbc + ((long)b * L + l0) * 768 + ch;
    for (int l = l0; l < l1; ++l) {
        float p3 = bf2f(*base);
        float acc = fmaf(p0, W0, fmaf(p1, W1, fmaf(p2, W2, fmaf(p3, W3, bs))));
        *base = f2bf(siluf(acc));
        p0 = p1; p1 = p2; p2 = p3;
        base += 768;
    }
}

// ---------------- per-chunk inclusive cumsum of dA (stored * log2e) ----------------
__global__ __launch_bounds__(128) void k_cs(const float* __restrict__ dtv,
                                            const float* __restrict__ A_log,
                                            float* __restrict__ cs) {
    int c = blockIdx.x % NC;
    int h = (blockIdx.x / NC) % NH;
    int b = blockIdx.x / (NC * NH);
    int q = threadIdx.x;
    int lg = c * 128 + q;
    float Av = -expf(A_log[h]);
    float dA = 0.f;
    if (lg < L) dA = dtv[((long)b * L + lg) * 8 + h] * Av;
    __shared__ float buf[128];
    buf[q] = dA;
    __syncthreads();
    for (int off = 1; off < 128; off <<= 1) {
        float add = (q >= off) ? buf[q - off] : 0.f;
        __syncthreads();
        buf[q] += add;
        __syncthreads();
    }
    cs[(long)blockIdx.x * 128 + q] = buf[q] * LOG2E;
}

// ---------------- cb[bl,c,l,s] = C[l]·B[s]  (MFMA) ----------------
__global__ __launch_bounds__(256) void k_cb(const u16* __restrict__ xbc,
                                            u16* __restrict__ cb, int bo) {
    int c = blockIdx.x % NC, bl = blockIdx.x / NC;
    int b = bo + bl;
    long bcl = blockIdx.x;
    __shared__ u16 Als[128 * 40];
    __shared__ u16 Bls[128 * 40];
    int tid = threadIdx.x;
    int wave = tid >> 6, lane = tid & 63;
    int wr = wave >> 1, wc = wave & 1;
    int l15 = lane & 15, l4 = lane >> 4;
    int srow = tid >> 1, scol = (tid & 1) * 16;

    f32x4 acc[4][4];
    #pragma unroll
    for (int i = 0; i < 4; ++i)
        #pragma unroll
        for (int j = 0; j < 4; ++j)
            acc[i][j] = (f32x4){0.f, 0.f, 0.f, 0.f};

    int lg = c * 128 + srow;
    const u16* prow = xbc + ((long)b * L + lg) * XBCD;

    for (int k0 = 0; k0 < 128; k0 += 32) {
        uint4 cv0 = {0,0,0,0}, cv1 = cv0, bv0 = cv0, bv1 = cv0;
        if (lg < L) {
            cv0 = *(const uint4*)(prow + 640 + k0 + scol);
            cv1 = *(const uint4*)(prow + 640 + k0 + scol + 8);
            bv0 = *(const uint4*)(prow + 512 + k0 + scol);
            bv1 = *(const uint4*)(prow + 512 + k0 + scol + 8);
        }
        *(uint4*)&Als[srow * 40 + scol]     = cv0;
        *(uint4*)&Als[srow * 40 + scol + 8] = cv1;
        *(uint4*)&Bls[srow * 40 + scol]     = bv0;
        *(uint4*)&Bls[srow * 40 + scol + 8] = bv1;
        __syncthreads();

        bf16x8 af[4], bfr[4];
        #pragma unroll
        for (int i = 0; i < 4; ++i) {
            af[i]  = *(const bf16x8*)&Als[(wr * 64 + i * 16 + l15) * 40 + l4 * 8];
            bfr[i] = *(const bf16x8*)&Bls[(wc * 64 + i * 16 + l15) * 40 + l4 * 8];
        }
        #pragma unroll
        for (int i = 0; i < 4; ++i)
            #pragma unroll
            for (int j = 0; j < 4; ++j)
                acc[i][j] = __builtin_amdgcn_mfma_f32_16x16x32_bf16(
                    af[i], bfr[j], acc[i][j], 0, 0, 0);
        __syncthreads();
    }

    #pragma unroll
    for (int i = 0; i < 4; ++i)
        #pragma unroll
        for (int j = 0; j < 4; ++j) {
            int n = wc * 64 + j * 16 + l15;
            #pragma unroll
            for (int r = 0; r < 4; ++r) {
                int m = wr * 64 + i * 16 + l4 * 4 + r;
                cb[(bcl * 128 + m) * 128 + n] = f2bf(acc[i][j][r]);
            }
        }
}

// ---------------- states S[n,p] (MFMA, split-K staging: 2 l-halves) ----------------
__global__ __launch_bounds__(256) void k_states(const u16* __restrict__ xbc,
                                                const float* __restrict__ dtv,
                                                const float* __restrict__ cs,
                                                u16* __restrict__ st, int bo) {
    int h = blockIdx.x & 7;
    int c = (blockIdx.x >> 3) % NC;
    int bl = blockIdx.x / (8 * NC);
    int b = bo + bl;
    __shared__ u16 At[128][72];   // Bw^T [n][l-half]
    __shared__ u16 Bt[64][72];    // xw^T [p][l-half]
    long csbase = (((long)b * 8 + h) * NC + c) * 128;
    float cs2Last = cs[csbase + 127];
    int tid = threadIdx.x;
    int lane = tid & 63, wave = tid >> 6;
    int wr = wave >> 1, wc = wave & 1;
    int l15 = lane & 15, l4 = lane >> 4;
    int pr = tid & 31, grp = tid >> 5;

    f32x4 acc[4][2];
    #pragma unroll
    for (int i = 0; i < 4; ++i)
        #pragma unroll
        for (int j = 0; j < 2; ++j)
            acc[i][j] = (f32x4){0.f, 0.f, 0.f, 0.f};

    #pragma unroll
    for (int lh = 0; lh < 2; ++lh) {
        int l0 = lh * 64 + 2 * pr, l1 = l0 + 1;
        int lg0 = c * 128 + l0, lg1 = lg0 + 1;
        long row0 = (long)b * L + lg0, row1 = row0 + 1;
        float wl0 = 0.f, wl1 = 0.f, dt0 = 0.f, dt1 = 0.f;
        if (lg0 < L) { wl0 = exp2f(cs2Last - cs[csbase + l0]); dt0 = dtv[row0 * 8 + h]; }
        if (lg1 < L) { wl1 = exp2f(cs2Last - cs[csbase + l1]); dt1 = dtv[row1 * 8 + h]; }

        #pragma unroll
        for (int nb = 0; nb < 2; ++nb) {
            int n0 = grp * 16 + nb * 8;
            float a0[8] = {0,0,0,0,0,0,0,0}, a1[8] = {0,0,0,0,0,0,0,0};
            if (lg0 < L) ld8bf(xbc + row0 * XBCD + 512 + n0, a0);
            if (lg1 < L) ld8bf(xbc + row1 * XBCD + 512 + n0, a1);
            #pragma unroll
            for (int i = 0; i < 8; ++i)
                *(unsigned int*)&At[n0 + i][2 * pr] = pk2(a0[i] * wl0, a1[i] * wl1);
        }
        {
            int p0 = grp * 8;
            float a0[8] = {0,0,0,0,0,0,0,0}, a1[8] = {0,0,0,0,0,0,0,0};
            if (lg0 < L) ld8bf(xbc + row0 * XBCD + h * 64 + p0, a0);
            if (lg1 < L) ld8bf(xbc + row1 * XBCD + h * 64 + p0, a1);
            #pragma unroll
            for (int i = 0; i < 8; ++i)
                *(unsigned int*)&Bt[p0 + i][2 * pr] = pk2(a0[i] * dt0, a1[i] * dt1);
        }
        __syncthreads();

        #pragma unroll
        for (int k0 = 0; k0 < 64; k0 += 32) {
            bf16x8 af[4], bfr[2];
            #pragma unroll
            for (int i = 0; i < 4; ++i)
                af[i] = *(const bf16x8*)&At[wr * 64 + i * 16 + l15][k0 + l4 * 8];
            #pragma unroll
            for (int j = 0; j < 2; ++j)
                bfr[j] = *(const bf16x8*)&Bt[wc * 32 + j * 16 + l15][k0 + l4 * 8];
            #pragma unroll
            for (int i = 0; i < 4; ++i)
                #pragma unroll
                for (int j = 0; j < 2; ++j)
                    acc[i][j] = __builtin_amdgcn_mfma_f32_16x16x32_bf16(
                        af[i], bfr[j], acc[i][j], 0, 0, 0);
        }
        __syncthreads();
    }

    long basep = (long)blockIdx.x * 8192;
    #pragma unroll
    for (int i = 0; i < 4; ++i)
        #pragma unroll
        for (int j = 0; j < 2; ++j) {
            int p = wc * 32 + j * 16 + l15;
            #pragma unroll
            for (int r = 0; r < 4; ++r) {
                int n = wr * 64 + i * 16 + l4 * 4 + r;
                st[basep + n * 64 + p] = f2bf(acc[i][j][r]);
            }
        }
}

// ---------------- inter-chunk scan (4x parallel: 256 blocks/half) ----------------
__global__ __launch_bounds__(256) void k_scan(const float* __restrict__ cs,
                                              u16* __restrict__ st, int bo) {
    int h = blockIdx.x & 7, bl = (blockIdx.x >> 3) & 7, q = blockIdx.x >> 6;
    int b = bo + bl;
    int tid = threadIdx.x;
    float carry[8];
    #pragma unroll
    for (int i = 0; i < 8; ++i) carry[i] = 0.f;
    long csbase = ((long)b * 8 + h) * NC * 128;
    for (int c = 0; c < NC; ++c) {
        float cd = exp2f(cs[csbase + c * 128 + 127]);
        u16* p = st + (((long)bl * NC + c) * 8 + h) * 8192 + q * 2048;
        #pragma unroll
        for (int i = 0; i < 8; ++i) {
            int e = tid + i * 256;
            float v = bf2f(p[e]);
            p[e] = f2bf(carry[i]);
            carry[i] = carry[i] * cd + v;
        }
    }
}

// ---------------- Ydiag + Yoff + D-skip (MFMA, 4 split-K sub-phases) ----------------
__global__ __launch_bounds__(256) void k_yout(u16* __restrict__ xbc,
                                              const float* __restrict__ dtv,
                                              const float* __restrict__ cs,
                                              const u16* __restrict__ cb,
                                              const u16* __restrict__ st,
                                              const float* __restrict__ Dv, int bo) {
    int h = blockIdx.x & 7;
    int c = (blockIdx.x >> 3) % NC;
    int bl = blockIdx.x / (8 * NC);
    int b = bo + bl;
    long bcl = (long)bl * NC + c;
    __shared__ u16 Am[128][72];   // phase1: masked decay CB [l][s-half]; phase2: C*ecs [l][n-half]
    __shared__ u16 Bt[64][72];    // phase1: xw^T [p][s-half]; phase2: prev^T [p][n-half]
    __shared__ float csb[128], ecs[128];
    int tid = threadIdx.x;
    long csbase = (((long)b * 8 + h) * NC + c) * 128;
    if (tid < 128) {
        float v = cs[csbase + tid];
        csb[tid] = v;
        ecs[tid] = exp2f(v);
    }
    __syncthreads();

    int lane = tid & 63, wave = tid >> 6;
    int wr = wave >> 1, wc = wave & 1;
    int l15 = lane & 15, l4 = lane >> 4;
    int lrow = tid >> 1, sh32 = (tid & 1) * 32;
    int pr = tid & 31, grp = tid >> 5;

    f32x4 acc[4][2];
    #pragma unroll
    for (int i = 0; i < 4; ++i)
        #pragma unroll
        for (int j = 0; j < 2; ++j)
            acc[i][j] = (f32x4){0.f, 0.f, 0.f, 0.f};

    // ---- phase 1: Ydiag over two s-halves ----
    #pragma unroll
    for (int sh2 = 0; sh2 < 2; ++sh2) {
        int sbase = sh2 * 64;
        {
            float cl = csb[lrow];
            const u16* cbrow = cb + (bcl * 128 + lrow) * 128 + sbase + sh32;
            #pragma unroll
            for (int sb = 0; sb < 4; ++sb) {
                float a[8];
                ld8bf(cbrow + sb * 8, a);
                #pragma unroll
                for (int i = 0; i < 8; ++i) {
                    int s = sbase + sh32 + sb * 8 + i;
                    float w = (s <= lrow) ? exp2f(cl - csb[s]) : 0.f;
                    a[i] *= w;
                }
                st8bf(&Am[lrow][sh32 + sb * 8], a);
            }
        }
        {
            int l0 = sbase + 2 * pr, l1 = l0 + 1;
            int lg0 = c * 128 + l0, lg1 = lg0 + 1;
            long row0 = (long)b * L + lg0, row1 = row0 + 1;
            float dt0 = 0.f, dt1 = 0.f;
            if (lg0 < L) dt0 = dtv[row0 * 8 + h];
            if (lg1 < L) dt1 = dtv[row1 * 8 + h];
            int p0 = grp * 8;
            float a0[8] = {0,0,0,0,0,0,0,0}, a1[8] = {0,0,0,0,0,0,0,0};
            if (lg0 < L) ld8bf(xbc + row0 * XBCD + h * 64 + p0, a0);
            if (lg1 < L) ld8bf(xbc + row1 * XBCD + h * 64 + p0, a1);
            #pragma unroll
            for (int i = 0; i < 8; ++i)
                *(unsigned int*)&Bt[p0 + i][2 * pr] = pk2(a0[i] * dt0, a1[i] * dt1);
        }
        __syncthreads();
        #pragma unroll
        for (int k0 = 0; k0 < 64; k0 += 32) {
            bf16x8 af[4], bfr[2];
            #pragma unroll
            for (int i = 0; i < 4; ++i)
                af[i] = *(const bf16x8*)&Am[wr * 64 + i * 16 + l15][k0 + l4 * 8];
            #pragma unroll
            for (int j = 0; j < 2; ++j)
                bfr[j] = *(const bf16x8*)&Bt[wc * 32 + j * 16 + l15][k0 + l4 * 8];
            #pragma unroll
            for (int i = 0; i < 4; ++i)
                #pragma unroll
                for (int j = 0; j < 2; ++j)
                    acc[i][j] = __builtin_amdgcn_mfma_f32_16x16x32_bf16(
                        af[i], bfr[j], acc[i][j], 0, 0, 0);
        }
        __syncthreads();
    }

    // ---- phase 2: Yoff over two n-halves ----
    #pragma unroll
    for (int nh2 = 0; nh2 < 2; ++nh2) {
        int nbase = nh2 * 64;
        {
            float el = ecs[lrow];
            int lgr = c * 128 + lrow;
            const u16* xr = xbc + ((long)b * L + lgr) * XBCD + 640 + nbase + sh32;
            #pragma unroll
            for (int sb = 0; sb < 4; ++sb) {
                float a[8] = {0,0,0,0,0,0,0,0};
                if (lgr < L) {
                    ld8bf(xr + sb * 8, a);
                    #pragma unroll
                    for (int i = 0; i < 8; ++i) a[i] *= el;
                }
                st8bf(&Am[lrow][sh32 + sb * 8], a);
            }
        }
        {
            int n0 = nbase + 2 * pr;
            const u16* pv = st + (bcl * 8 + h) * 8192;
            int p0 = grp * 8;
            float a0[8], a1[8];
            ld8bf(pv + (long)n0 * 64 + p0, a0);
            ld8bf(pv + (long)(n0 + 1) * 64 + p0, a1);
            #pragma unroll
            for (int i = 0; i < 8; ++i)
                *(unsigned int*)&Bt[p0 + i][2 * pr] = pk2(a0[i], a1[i]);
        }
        __syncthreads();
        #pragma unroll
        for (int k0 = 0; k0 < 64; k0 += 32) {
            bf16x8 af[4], bfr[2];
            #pragma unroll
            for (int i = 0; i < 4; ++i)
                af[i] = *(const bf16x8*)&Am[wr * 64 + i * 16 + l15][k0 + l4 * 8];
            #pragma unroll
            for (int j = 0; j < 2; ++j)
                bfr[j] = *(const bf16x8*)&Bt[wc * 32 + j * 16 + l15][k0 + l4 * 8];
            #pragma unroll
            for (int i = 0; i < 4; ++i)
                #pragma unroll
                for (int j = 0; j < 2; ++j)
                    acc[i][j] = __builtin_amdgcn_mfma_f32_16x16x32_bf16(
                        af[i], bfr[j], acc[i][j], 0, 0, 0);
        }
        __syncthreads();
    }

    // epilogue: + D*xh, overwrite x-part in place
    float Dh = Dv[h];
    #pragma unroll
    for (int i = 0; i < 4; ++i)
        #pragma unroll
        for (int r = 0; r < 4; ++r) {
            int l = wr * 64 + i * 16 + l4 * 4 + r;
            int lg = c * 128 + l;
            if (lg >= L) continue;
            long row = (long)b * L + lg;
            #pragma unroll
            for (int j = 0; j < 2; ++j) {
                int p = wc * 32 + j * 16 + l15;
                u16* xp = xbc + row * XBCD + h * 64 + p;
                float xv = bf2f(*xp);
                *xp = f2bf(fmaf(Dh, xv, acc[i][j][r]));
            }
        }
}

// ---------------- gated RMSNorm (wave per row) ----------------
__global__ __launch_bounds__(256) void k_rmsnorm(u16* __restrict__ y,
                                                 const u16* __restrict__ z,
                                                 const float* __restrict__ nw) {
    int wave = threadIdx.x >> 6, lane = threadIdx.x & 63;
    long r = (long)blockIdx.x * 4 + wave;     // 9996 blocks exact
    int c0 = lane * 8;
    float v[8], zv[8];
    ld8bf(y + r * XBCD + c0, v);
    ld8bf(z + r * DIN + c0, zv);
    float ss = 0.f;
    #pragma unroll
    for (int j = 0; j < 8; ++j) {
        v[j] *= siluf(zv[j]);
        ss += v[j] * v[j];
    }
    #pragma unroll
    for (int off = 32; off > 0; off >>= 1) ss += __shfl_xor(ss, off, 64);
    float sc = rsqrtf(ss / 512.f + 1e-5f);
    float4 w0 = *(const float4*)(nw + c0);
    float4 w1 = *(const float4*)(nw + c0 + 4);
    v[0] *= sc * w0.x; v[1] *= sc * w0.y; v[2] *= sc * w0.z; v[3] *= sc * w0.w;
    v[4] *= sc * w1.x; v[5] *= sc * w1.y; v[6] *= sc * w1.z; v[7] *= sc * w1.w;
    st8bf(y + r * XBCD + c0, v);
}

// ---------------- repack conv1_w ----------------
__global__ __launch_bounds__(256) void k_wpack(const float* __restrict__ w,
                                               u16* __restrict__ wp) {
    int idx = blockIdx.x * 256 + threadIdx.x;
    if (idx >= 8 * 256 * 16) return;
    int k = idx & 15;
    int cidx = (idx >> 4) & 255;
    int s = idx >> 12;
    wp[(s * 16 + k) * 256 + cidx] = f2bf(w[idx]);
}

// ---------------- conv1 combine: G bf16 in, f bf16 [16][20000] out + pad ----------------
__global__ __launch_bounds__(256) void k_conv1(const u16* __restrict__ G,
                                               const float* __restrict__ bias,
                                               u16* __restrict__ f) {
    long idx = (long)blockIdx.x * 256 + threadIdx.x;
    if (idx >= (long)B * 8 * L) {
        long j = idx - (long)B * 8 * L;      // 128 spare threads zero the pad
        if (j < 16 * 8)
            f[(j >> 3) * FLATP + FLAT + (j & 7)] = 0;
        return;
    }
    int l = (int)(idx % L);
    long t = idx / L;
    int s = (int)(t & 7);
    int b = (int)(t >> 3);
    float acc = bias[s];
    #pragma unroll
    for (int k = 0; k < 16; ++k) {
        int ls = l + k - 7;
        if (ls >= 0 && ls < L)
            acc += bf2f(G[((long)b * L + ls) * 128 + s * 16 + k]);
    }
    f[(long)b * FLATP + s * L + l] = f2bf(acc);
}

// ---------------- MLP1: o1acc[16][512] += f[16][20000] @ w1b[512][20000]^T (MFMA) ----------------
__global__ __launch_bounds__(256) void k_mlp1(const u16* __restrict__ fb,
                                              const u16* __restrict__ w1b,
                                              float* __restrict__ o1acc) {
    int wave = threadIdx.x >> 6, lane = threadIdx.x & 63;
    int l15 = lane & 15, l4 = lane >> 4;
    int n0 = blockIdx.x * 64 + wave * 16;     // 8 x-blocks
    int k0 = blockIdx.y * 800;                // 25 y-blocks
    const u16* fp = fb + (long)l15 * FLATP + k0 + l4 * 8;
    const u16* wp = w1b + (long)(n0 + l15) * FLATP + k0 + l4 * 8;
    f32x4 acc = (f32x4){0.f, 0.f, 0.f, 0.f};
    #pragma unroll
    for (int kk = 0; kk < 25; ++kk) {
        bf16x8 af = *(const bf16x8*)fp;
        bf16x8 bf = *(const bf16x8*)wp;
        acc = __builtin_amdgcn_mfma_f32_16x16x32_bf16(af, bf, acc, 0, 0, 0);
        fp += 32; wp += 32;
    }
    #pragma unroll
    for (int r = 0; r < 4; ++r) {
        int b = l4 * 4 + r;
        atomicAdd(&o1acc[b * 512 + n0 + l15], acc[r]);
    }
}

__global__ __launch_bounds__(256) void k_mlp1fin(const float* __restrict__ o1acc,
                                                 const float* __restrict__ b1,
                                                 float* __restrict__ o1) {
    int i = blockIdx.x * 256 + threadIdx.x;   // 32 blocks, 8192 elems
    o1[i] = fmaxf(o1acc[i] + b1[i & 511], 0.f);
}

__global__ __launch_bounds__(256) void k_mlp2(const float* __restrict__ in,
                                              const float* __restrict__ w,
                                              const float* __restrict__ bias,
                                              float* __restrict__ out) {
    int b = blockIdx.x, n = threadIdx.x;
    const float* ir = in + b * 512;
    const float* wr = w + (long)n * 512;
    float acc = 0.f;
    for (int k = 0; k < 512; ++k) acc = fmaf(ir[k], wr[k], acc);
    out[b * 256 + n] = fmaxf(acc + bias[n], 0.f);
}

__global__ __launch_bounds__(64) void k_mlp3(const float* __restrict__ in,
                                             const float* __restrict__ w,
                                             const float* __restrict__ bias,
                                             float* __restrict__ out) {
    int b = blockIdx.x, n = threadIdx.x;
    const float* ir = in + b * 256;
    const float* wr = w + (long)n * 256;
    float acc = 0.f;
    for (int k = 0; k < 256; ++k) acc = fmaf(ir[k], wr[k], acc);
    out[b * 64 + n] = fmaxf(acc + bias[n], 0.f);
}

__global__ __launch_bounds__(64) void k_mlp4(const float* __restrict__ in,
                                             const float* __restrict__ w4,
                                             const float* __restrict__ b4,
                                             float* __restrict__ dout) {
    int b = blockIdx.x, k = threadIdx.x;
    float v = in[b * 64 + k] * w4[k];
    #pragma unroll
    for (int off = 32; off > 0; off >>= 1) v += __shfl_down(v, off);
    if (k == 0) dout[b] = v + b4[0];
}

// ---------------- host launcher ----------------
extern "C" void kernel_launch(void* const* d_in, const int* in_sizes, int n_in,
                              void* d_out, int out_size, void* d_ws, size_t ws_size,
                              hipStream_t stream) {
    (void)in_sizes; (void)n_in; (void)out_size;
    if (ws_size < WS_NEEDED) return;

    const float* x         = (const float*)d_in[0];
    const float* conv_w    = (const float*)d_in[1];
    // conv_b (d_in[2]) cancels under batch-stat BN — unused
    const float* bn_w      = (const float*)d_in[3];
    const float* bn_b      = (const float*)d_in[4];
    const float* in_proj_w = (const float*)d_in[5];
    const float* conv1d_w  = (const float*)d_in[6];
    const float* conv1d_b  = (const float*)d_in[7];
    const float* dt_bias   = (const float*)d_in[8];
    const float* A_log     = (const float*)d_in[9];
    const float* Dp        = (const float*)d_in[10];
    const float* norm_w    = (const float*)d_in[11];
    const float* out_proj_w= (const float*)d_in[12];
    const float* conv1_w   = (const float*)d_in[13];
    const float* conv1_b   = (const float*)d_in[14];
    const float* w1 = (const float*)d_in[15]; const float* b1 = (const float*)d_in[16];
    const float* w2 = (const float*)d_in[17]; const float* b2 = (const float*)d_in[18];
    const float* w3 = (const float*)d_in[19]; const float* b3 = (const float*)d_in[20];
    const float* w4 = (const float*)d_in[21]; const float* b4 = (const float*)d_in[22];

    char* base = (char*)d_ws;
    float* dtv  = (float*)(base + S_DTV);
    float* cs   = (float*)(base + S_CS);
    float* sums = (float*)(base + S_STAT);
    float* sumsq= sums + 256;
    float* scale= sums + 512;
    float* shift= sums + 768;
    u16*   cwbf = (u16*)(base + S_WPK);
    u16*   wbf  = (u16*)(base + S_HALO);
    u16*   halo = (u16*)(base + S_HALO);
    u16*   ht   = (u16*)(base + OFF_HT);
    u16*   xbc  = (u16*)(base + OFF_XBC);
    u16*   cb   = (u16*)(base + OFF_CBST + CB_OFF);
    u16*   st   = (u16*)(base + OFF_CBST + ST_OFF);
    u16*   zb   = (u16*)(base + OFF_CBST + Z_OFF);
    u16*   G    = (u16*)(base + OFF_XBC);
    u16*   fbuf = (u16*)(base + OFF_CBST + F_OFF);
    float* o1a  = (float*)(base + OFF_CBST + O1A_OFF);
    float* o1   = (float*)(base + OFF_CBST + O1_OFF);
    float* o2   = (float*)(base + OFF_CBST + O2_OFF);
    float* o3   = (float*)(base + OFF_CBST + O3_OFF);
    u16*   w1b  = (u16*)(base + OFF_CBST + W1B_OFF);
    u16*   yproj= ht;

    // 1-2. stem conv as fused-im2col MFMA GEMM
    k_wcvt<<<64, 256, 0, stream>>>(conv_w, cwbf, 256 * 64);
    gemm_mfma<true, true><<<dim3(313, 2), 256, 0, stream>>>(
        x, cwbf, ht, (int)ROWS, 256, 64, 0, 256);

    // 3. BN batch stats + in-place BN+ReLU
    k_zero<<<2, 256, 0, stream>>>(sums, 512);
    k_bnstats<<<256, 256, 0, stream>>>(ht, sums, sumsq);
    k_bnfinal<<<1, 256, 0, stream>>>(sums, sumsq, bn_w, bn_b, scale, shift);
    k_bnapply<<<4998, 256, 0, stream>>>(ht, scale, shift);

    // 4. xBC projection (MFMA); dt projection
    k_wcvt<<<768, 256, 0, stream>>>(in_proj_w + 512L * 256, wbf, 768 * 256);
    gemm_mfma<false, true><<<dim3(313, 6), 256, 0, stream>>>(
        ht, wbf, xbc, (int)ROWS, 768, 256, 256, 768);
    k_dtproj<<<1250, 256, 0, stream>>>(ht, in_proj_w, dt_bias, dtv);

    // 5. in-place depthwise conv + SiLU; cumsum (scaled by log2e)
    k_halo<<<2736, 256, 0, stream>>>(xbc, halo);
    k_dwip<<<960, 256, 0, stream>>>(xbc, halo, conv1d_w, conv1d_b);
    k_cs<<<2560, 128, 0, stream>>>(dtv, A_log, cs);

    // 6. SSD in two half-batches (all MFMA)
    for (int bh = 0; bh < 2; ++bh) {
        int bo = bh * 8;
        k_cb<<<160, 256, 0, stream>>>(xbc, cb, bo);
        k_states<<<1280, 256, 0, stream>>>(xbc, dtv, cs, st, bo);
        k_scan<<<256, 256, 0, stream>>>(cs, st, bo);
        k_yout<<<1280, 256, 0, stream>>>(xbc, dtv, cs, cb, st, Dp, bo);
    }

    // 6.9. z projection (MFMA)
    k_wcvt<<<512, 256, 0, stream>>>(in_proj_w, wbf, 512 * 256);
    gemm_mfma<false, true><<<dim3(313, 4), 256, 0, stream>>>(
        ht, wbf, zb, (int)ROWS, 512, 256, 256, 512);

    // 7-8. gated RMSNorm + out_proj (MFMA)
    k_rmsnorm<<<9996, 256, 0, stream>>>(xbc, zb, norm_w);
    k_wcvt<<<512, 256, 0, stream>>>(out_proj_w, wbf, 256 * 512);
    gemm_mfma<false, true><<<dim3(313, 2), 256, 0, stream>>>(
        xbc, wbf, yproj, (int)ROWS, 256, 512, 768, 256);

    // 9. conv1 as MFMA GEMM (G bf16) + shifted gather (fbuf bf16 padded)
    k_wpack<<<128, 256, 0, stream>>>(conv1_w, wbf);
    gemm_mfma<false, true><<<dim3(313, 1), 256, 0, stream>>>(
        yproj, wbf, G, (int)ROWS, 128, 256, 256, 128);
    k_conv1<<<1250, 256, 0, stream>>>(G, conv1_b, fbuf);

    // 10. MLP head (mlp1 as bf16 MFMA split-K)
    k_w1cvt<<<5000, 256, 0, stream>>>(w1, w1b);
    k_zero<<<32, 256, 0, stream>>>(o1a, 8192);
    k_mlp1<<<dim3(8, 25), 256, 0, stream>>>(fbuf, w1b, o1a);
    k_mlp1fin<<<32, 256, 0, stream>>>(o1a, b1, o1);
    k_mlp2<<<16, 256, 0, stream>>>(o1, w2, b2, o2);
    k_mlp3<<<16, 64, 0, stream>>>(o2, w3, b3, o3);
    k_mlp4<<<16, 64, 0, stream>>>(o3, w4, b4, (float*)d_out);
}

// Round 12
// 624.571 us; speedup vs baseline: 2.1910x; 1.0726x over previous
//
#include <hip/hip_runtime.h>
#include <math.h>

// ---------------- problem constants ----------------
constexpr int B    = 16;
constexpr int L    = 2499;        // conv-stem output length
constexpr int DIN  = 512;         // d_inner
constexpr int NH   = 8;
constexpr int DS   = 128;         // d_state
constexpr int NC   = 20;          // ceil(2499/128) chunks
constexpr int XBCD = 768;         // DIN + 2*DS
constexpr int FLAT = 19992;
constexpr int FLATP= 20000;       // padded to multiple of 32 for MFMA K-loop
constexpr long ROWS = (long)B * L;   // 39984
constexpr float LOG2E = 1.4426950408889634f;

// ---------------- workspace layout (BYTE offsets) ----------------
constexpr size_t S_DTV  = 0;          // fp32 ROWS*8
constexpr size_t S_CS   = 1279488;    // fp32 16*8*20*128 (stored pre-scaled by log2e)
constexpr size_t S_STAT = 2590208;    // fp32 1024
constexpr size_t S_WPK  = 2594304;    // conv_w bf16
constexpr size_t S_HALO = 2725376;    // rotating: xbcw-bf16 -> halo -> zw/outw/wpk bf16
constexpr size_t OFF_HT  = 4199936;   // bf16 ROWS*256 (ht -> u -> yproj)
constexpr size_t OFF_XBC = 24671744;  // bf16 ROWS*768 (xbc/y); later G bf16 ROWS*128
constexpr size_t OFF_CBST= 86087168;  // cb+st -> z bf16 -> MLP stage
constexpr size_t CB_OFF  = 0;         // bf16 8*20*128*128
constexpr size_t ST_OFF  = 5242880;   // bf16 8*20*8*8192
constexpr size_t Z_OFF   = 0;         // bf16 ROWS*512
// MLP-stage overlay of CBST (z dead after rmsnorm):
constexpr size_t F_OFF   = 0;         // bf16 16*20000 = 640,000
constexpr size_t O1A_OFF = 640000;    // fp32 16*512 accumulator
constexpr size_t O1_OFF  = 672768;    // fp32 16*512
constexpr size_t O2_OFF  = 705536;    // fp32 16*256
constexpr size_t O3_OFF  = 721920;    // fp32 16*64
constexpr size_t W1B_OFF = 726016;    // bf16 512*20000 = 20,480,000
constexpr size_t WS_NEEDED = 127030784;

// ---------------- bf16 helpers ----------------
typedef unsigned short u16;
typedef __attribute__((ext_vector_type(8))) short bf16x8;
typedef __attribute__((ext_vector_type(4))) float f32x4;

__device__ __forceinline__ float bf2f(unsigned int u) {
    return __uint_as_float(u << 16);
}
__device__ __forceinline__ u16 f2bf(float f) {
    unsigned int x = __float_as_uint(f);
    unsigned int r = x + 0x7fffu + ((x >> 16) & 1u);
    return (u16)(r >> 16);
}
__device__ __forceinline__ unsigned int pk2(float a, float b) {
    return (unsigned int)f2bf(a) | ((unsigned int)f2bf(b) << 16);
}
__device__ __forceinline__ void ld8bf(const u16* p, float* o) {
    uint4 v = *(const uint4*)p;
    o[0]=bf2f(v.x&0xffffu); o[1]=bf2f(v.x>>16);
    o[2]=bf2f(v.y&0xffffu); o[3]=bf2f(v.y>>16);
    o[4]=bf2f(v.z&0xffffu); o[5]=bf2f(v.z>>16);
    o[6]=bf2f(v.w&0xffffu); o[7]=bf2f(v.w>>16);
}
__device__ __forceinline__ void ld4bf(const u16* p, float* o) {
    uint2 v = *(const uint2*)p;
    o[0]=bf2f(v.x&0xffffu); o[1]=bf2f(v.x>>16);
    o[2]=bf2f(v.y&0xffffu); o[3]=bf2f(v.y>>16);
}
__device__ __forceinline__ void st8bf(u16* p, const float* s) {
    uint4 v;
    v.x = pk2(s[0],s[1]); v.y = pk2(s[2],s[3]);
    v.z = pk2(s[4],s[5]); v.w = pk2(s[6],s[7]);
    *(uint4*)p = v;
}
__device__ __forceinline__ float siluf(float x) { return x / (1.f + expf(-x)); }

// ---------------- zero-init ----------------
__global__ __launch_bounds__(256) void k_zero(float* __restrict__ p, int n) {
    int i = blockIdx.x * 256 + threadIdx.x;
    if (i < n) p[i] = 0.f;
}

// ---------------- fp32 -> bf16 weight convert ----------------
__global__ __launch_bounds__(256) void k_wcvt(const float* __restrict__ src,
                                              u16* __restrict__ dst, int n) {
    int i = blockIdx.x * 256 + threadIdx.x;
    if (i < n) dst[i] = f2bf(src[i]);
}

// ---------------- w1 [512][19992] fp32 -> [512][20000] bf16, zero pad ----------------
__global__ __launch_bounds__(256) void k_w1cvt(const float* __restrict__ w1,
                                               u16* __restrict__ w1b) {
    long e0 = ((long)blockIdx.x * 256 + threadIdx.x) * 8;   // 5000 blocks exact
    int n = (int)(e0 / FLATP);
    int k = (int)(e0 - (long)n * FLATP);
    const float* src = w1 + (long)n * FLAT + k;
    u16* dst = w1b + e0;
    if (k + 8 <= FLAT) {
        float4 a = *(const float4*)src;
        float4 b = *(const float4*)(src + 4);
        *(uint4*)dst = (uint4){pk2(a.x,a.y), pk2(a.z,a.w), pk2(b.x,b.y), pk2(b.z,b.w)};
    } else {
        #pragma unroll
        for (int i = 0; i < 8; ++i)
            dst[i] = (k + i < FLAT) ? f2bf(src[i]) : (u16)0;
    }
}

// ---------------- MFMA GEMM: C[M,N] = A[M,K](bf16) @ Wb[N,K](bf16)^T ----------------
template <bool IM2COL, bool BF16OUT>
__global__ __launch_bounds__(256) void gemm_mfma(const void* __restrict__ Ap,
                                                 const u16* __restrict__ Wb,
                                                 void* __restrict__ Cp,
                                                 int M, int N, int K, int lda, int ldc) {
    __shared__ u16 Als[128 * 40];
    __shared__ u16 Bls[128 * 40];
    int tid = threadIdx.x;
    int wave = tid >> 6, lane = tid & 63;
    int wr = wave >> 1, wc = wave & 1;
    int m0 = blockIdx.x * 128, n0 = blockIdx.y * 128;
    int l15 = lane & 15, l4 = lane >> 4;
    int srow = tid >> 1, scol = (tid & 1) * 16;

    f32x4 acc[4][4];
    #pragma unroll
    for (int i = 0; i < 4; ++i)
        #pragma unroll
        for (int j = 0; j < 4; ++j)
            acc[i][j] = (f32x4){0.f, 0.f, 0.f, 0.f};

    for (int k0 = 0; k0 < K; k0 += 32) {
        {
            int am = m0 + srow;
            uint4 v0 = {0,0,0,0}, v1 = {0,0,0,0};
            if (am < M) {
                if (IM2COL) {
                    const float* x = (const float*)Ap;
                    int b = am / L, l = am - b * L;
                    int ic = (k0 + scol) >> 4;
                    const float* px = x + ((long)(b * 4 + ic)) * 20000 + l * 8;
                    float4 f0 = *(const float4*)(px);
                    float4 f1 = *(const float4*)(px + 4);
                    float4 f2 = *(const float4*)(px + 8);
                    float4 f3 = *(const float4*)(px + 12);
                    v0.x = pk2(f0.x,f0.y); v0.y = pk2(f0.z,f0.w);
                    v0.z = pk2(f1.x,f1.y); v0.w = pk2(f1.z,f1.w);
                    v1.x = pk2(f2.x,f2.y); v1.y = pk2(f2.z,f2.w);
                    v1.z = pk2(f3.x,f3.y); v1.w = pk2(f3.z,f3.w);
                } else {
                    const u16* pa = (const u16*)Ap + (long)am * lda + k0 + scol;
                    v0 = *(const uint4*)pa;
                    v1 = *(const uint4*)(pa + 8);
                }
            }
            *(uint4*)&Als[srow * 40 + scol]     = v0;
            *(uint4*)&Als[srow * 40 + scol + 8] = v1;
        }
        {
            const u16* pw = Wb + (long)(n0 + srow) * K + k0 + scol;
            *(uint4*)&Bls[srow * 40 + scol]     = *(const uint4*)pw;
            *(uint4*)&Bls[srow * 40 + scol + 8] = *(const uint4*)(pw + 8);
        }
        __syncthreads();

        bf16x8 af[4], bfr[4];
        #pragma unroll
        for (int i = 0; i < 4; ++i) {
            af[i]  = *(const bf16x8*)&Als[(wr * 64 + i * 16 + l15) * 40 + l4 * 8];
            bfr[i] = *(const bf16x8*)&Bls[(wc * 64 + i * 16 + l15) * 40 + l4 * 8];
        }
        #pragma unroll
        for (int i = 0; i < 4; ++i)
            #pragma unroll
            for (int j = 0; j < 4; ++j)
                acc[i][j] = __builtin_amdgcn_mfma_f32_16x16x32_bf16(
                    af[i], bfr[j], acc[i][j], 0, 0, 0);
        __syncthreads();
    }

    #pragma unroll
    for (int i = 0; i < 4; ++i) {
        #pragma unroll
        for (int j = 0; j < 4; ++j) {
            int n = n0 + wc * 64 + j * 16 + l15;
            #pragma unroll
            for (int r = 0; r < 4; ++r) {
                int m = m0 + wr * 64 + i * 16 + l4 * 4 + r;
                if (m < M) {
                    if (BF16OUT) ((u16*)Cp)[(long)m * ldc + n] = f2bf(acc[i][j][r]);
                    else         ((float*)Cp)[(long)m * ldc + n] = acc[i][j][r];
                }
            }
        }
    }
}

// ---------------- BN batch stats ----------------
__global__ __launch_bounds__(256) void k_bnstats(const u16* __restrict__ h,
                                                 float* __restrict__ sums,
                                                 float* __restrict__ sumsq) {
    int c = threadIdx.x;
    float s = 0.f, s2 = 0.f;
    for (long r = blockIdx.x; r < ROWS; r += gridDim.x) {
        float v = bf2f(h[r * 256 + c]);
        s += v; s2 += v * v;
    }
    atomicAdd(&sums[c], s);
    atomicAdd(&sumsq[c], s2);
}

__global__ __launch_bounds__(256) void k_bnfinal(const float* __restrict__ sums,
                                                 const float* __restrict__ sumsq,
                                                 const float* __restrict__ bn_w,
                                                 const float* __restrict__ bn_b,
                                                 float* __restrict__ scale,
                                                 float* __restrict__ shift) {
    int c = threadIdx.x;
    float mean = sums[c] / (float)ROWS;
    float var  = sumsq[c] / (float)ROWS - mean * mean;
    float inv  = rsqrtf(var + 1e-5f);
    float sc   = bn_w[c] * inv;
    scale[c] = sc;
    shift[c] = bn_b[c] - mean * sc;
}

// ---------------- in-place BN+ReLU ----------------
__global__ __launch_bounds__(256) void k_bnapply(u16* __restrict__ ht,
                                                 const float* __restrict__ scale,
                                                 const float* __restrict__ shift) {
    long i = ((long)blockIdx.x * 256 + threadIdx.x) * 8;
    int c = (int)(i & 255);
    float v[8];
    ld8bf(ht + i, v);
    float4 s0 = *(const float4*)(scale + c), s1 = *(const float4*)(scale + c + 4);
    float4 h0 = *(const float4*)(shift + c), h1 = *(const float4*)(shift + c + 4);
    v[0]=fmaxf(fmaf(v[0],s0.x,h0.x),0.f); v[1]=fmaxf(fmaf(v[1],s0.y,h0.y),0.f);
    v[2]=fmaxf(fmaf(v[2],s0.z,h0.z),0.f); v[3]=fmaxf(fmaf(v[3],s0.w,h0.w),0.f);
    v[4]=fmaxf(fmaf(v[4],s1.x,h1.x),0.f); v[5]=fmaxf(fmaf(v[5],s1.y,h1.y),0.f);
    v[6]=fmaxf(fmaf(v[6],s1.z,h1.z),0.f); v[7]=fmaxf(fmaf(v[7],s1.w,h1.w),0.f);
    st8bf(ht + i, v);
}

// ---------------- dt = softplus(u @ Wdt^T + dt_bias) ----------------
__global__ __launch_bounds__(256) void k_dtproj(const u16* __restrict__ u,
                                                const float* __restrict__ in_proj_w,
                                                const float* __restrict__ dt_bias,
                                                float* __restrict__ dtv) {
    long idx = (long)blockIdx.x * 256 + threadIdx.x;
    if (idx >= ROWS * 8) return;
    int h = (int)(idx & 7);
    long row = idx >> 3;
    const float* wr = in_proj_w + (long)(1280 + h) * 256;
    const u16* ar = u + row * 256;
    float acc = dt_bias[h];
    for (int k = 0; k < 256; ++k)
        acc = fmaf(bf2f(ar[k]), wr[k], acc);
    dtv[idx] = (acc > 20.f) ? acc : log1pf(expf(acc));
}

// ---------------- save 3-row halos ----------------
__global__ __launch_bounds__(256) void k_halo(const u16* __restrict__ xbc,
                                              u16* __restrict__ halo) {
    long idx = (long)blockIdx.x * 256 + threadIdx.x;
    if (idx >= 16L * 19 * 3 * 768) return;
    int ch = (int)(idx % 768);
    long t1 = idx / 768;
    int j = (int)(t1 % 3);
    long t2 = t1 / 3;
    int t = (int)(t2 % 19) + 1;
    int b = (int)(t2 / 19);
    halo[(((long)b * 20 + t) * 3 + j) * 768 + ch] =
        xbc[((long)b * L + t * 128 - 3 + j) * 768 + ch];
}

// ---------------- in-place depthwise causal conv1d + SiLU ----------------
__global__ __launch_bounds__(256) void k_dwip(u16* __restrict__ xbc,
                                              const u16* __restrict__ halo,
                                              const float* __restrict__ w,
                                              const float* __restrict__ bias) {
    int cg = blockIdx.x % 3;
    int t  = (blockIdx.x / 3) % 20;
    int b  = blockIdx.x / 60;
    int ch = cg * 256 + threadIdx.x;
    int l0 = t * 128, l1 = min(l0 + 128, L);
    float W0 = w[ch*4+0], W1 = w[ch*4+1], W2 = w[ch*4+2], W3 = w[ch*4+3];
    float bs = bias[ch];
    float p0 = 0.f, p1 = 0.f, p2 = 0.f;
    if (t > 0) {
        const u16* hp = halo + (((long)b * 20 + t) * 3) * 768 + ch;
        p0 = bf2f(hp[0]); p1 = bf2f(hp[768]); p2 = bf2f(hp[1536]);
    }
    u16* base = xbc + ((long)b * L + l0) * 768 + ch;
    for (int l = l0; l < l1; ++l) {
        float p3 = bf2f(*base);
        float acc = fmaf(p0, W0, fmaf(p1, W1, fmaf(p2, W2, fmaf(p3, W3, bs))));
        *base = f2bf(siluf(acc));
        p0 = p1; p1 = p2; p2 = p3;
        base += 768;
    }
}

// ---------------- per-chunk inclusive cumsum of dA (stored * log2e) ----------------
__global__ __launch_bounds__(128) void k_cs(const float* __restrict__ dtv,
                                            const float* __restrict__ A_log,
                                            float* __restrict__ cs) {
    int c = blockIdx.x % NC;
    int h = (blockIdx.x / NC) % NH;
    int b = blockIdx.x / (NC * NH);
    int q = threadIdx.x;
    int lg = c * 128 + q;
    float Av = -expf(A_log[h]);
    float dA = 0.f;
    if (lg < L) dA = dtv[((long)b * L + lg) * 8 + h] * Av;
    __shared__ float buf[128];
    buf[q] = dA;
    __syncthreads();
    for (int off = 1; off < 128; off <<= 1) {
        float add = (q >= off) ? buf[q - off] : 0.f;
        __syncthreads();
        buf[q] += add;
        __syncthreads();
    }
    cs[(long)blockIdx.x * 128 + q] = buf[q] * LOG2E;
}

// ---------------- cb[bl,c,l,s] = C[l]·B[s]  (MFMA) ----------------
__global__ __launch_bounds__(256) void k_cb(const u16* __restrict__ xbc,
                                            u16* __restrict__ cb, int bo) {
    int c = blockIdx.x % NC, bl = blockIdx.x / NC;
    int b = bo + bl;
    long bcl = blockIdx.x;
    __shared__ u16 Als[128 * 40];
    __shared__ u16 Bls[128 * 40];
    int tid = threadIdx.x;
    int wave = tid >> 6, lane = tid & 63;
    int wr = wave >> 1, wc = wave & 1;
    int l15 = lane & 15, l4 = lane >> 4;
    int srow = tid >> 1, scol = (tid & 1) * 16;

    f32x4 acc[4][4];
    #pragma unroll
    for (int i = 0; i < 4; ++i)
        #pragma unroll
        for (int j = 0; j < 4; ++j)
            acc[i][j] = (f32x4){0.f, 0.f, 0.f, 0.f};

    int lg = c * 128 + srow;
    const u16* prow = xbc + ((long)b * L + lg) * XBCD;

    for (int k0 = 0; k0 < 128; k0 += 32) {
        uint4 cv0 = {0,0,0,0}, cv1 = cv0, bv0 = cv0, bv1 = cv0;
        if (lg < L) {
            cv0 = *(const uint4*)(prow + 640 + k0 + scol);
            cv1 = *(const uint4*)(prow + 640 + k0 + scol + 8);
            bv0 = *(const uint4*)(prow + 512 + k0 + scol);
            bv1 = *(const uint4*)(prow + 512 + k0 + scol + 8);
        }
        *(uint4*)&Als[srow * 40 + scol]     = cv0;
        *(uint4*)&Als[srow * 40 + scol + 8] = cv1;
        *(uint4*)&Bls[srow * 40 + scol]     = bv0;
        *(uint4*)&Bls[srow * 40 + scol + 8] = bv1;
        __syncthreads();

        bf16x8 af[4], bfr[4];
        #pragma unroll
        for (int i = 0; i < 4; ++i) {
            af[i]  = *(const bf16x8*)&Als[(wr * 64 + i * 16 + l15) * 40 + l4 * 8];
            bfr[i] = *(const bf16x8*)&Bls[(wc * 64 + i * 16 + l15) * 40 + l4 * 8];
        }
        #pragma unroll
        for (int i = 0; i < 4; ++i)
            #pragma unroll
            for (int j = 0; j < 4; ++j)
                acc[i][j] = __builtin_amdgcn_mfma_f32_16x16x32_bf16(
                    af[i], bfr[j], acc[i][j], 0, 0, 0);
        __syncthreads();
    }

    #pragma unroll
    for (int i = 0; i < 4; ++i)
        #pragma unroll
        for (int j = 0; j < 4; ++j) {
            int n = wc * 64 + j * 16 + l15;
            #pragma unroll
            for (int r = 0; r < 4; ++r) {
                int m = wr * 64 + i * 16 + l4 * 4 + r;
                cb[(bcl * 128 + m) * 128 + n] = f2bf(acc[i][j][r]);
            }
        }
}

// ---------------- states S[n,p] (MFMA, split-K staging: 2 l-halves) ----------------
__global__ __launch_bounds__(256) void k_states(const u16* __restrict__ xbc,
                                                const float* __restrict__ dtv,
                                                const float* __restrict__ cs,
                                                u16* __restrict__ st, int bo) {
    int h = blockIdx.x & 7;
    int c = (blockIdx.x >> 3) % NC;
    int bl = blockIdx.x / (8 * NC);
    int b = bo + bl;
    __shared__ u16 At[128][72];   // Bw^T [n][l-half]
    __shared__ u16 Bt[64][72];    // xw^T [p][l-half]
    long csbase = (((long)b * 8 + h) * NC + c) * 128;
    float cs2Last = cs[csbase + 127];
    int tid = threadIdx.x;
    int lane = tid & 63, wave = tid >> 6;
    int wr = wave >> 1, wc = wave & 1;
    int l15 = lane & 15, l4 = lane >> 4;
    int pr = tid & 31, grp = tid >> 5;

    f32x4 acc[4][2];
    #pragma unroll
    for (int i = 0; i < 4; ++i)
        #pragma unroll
        for (int j = 0; j < 2; ++j)
            acc[i][j] = (f32x4){0.f, 0.f, 0.f, 0.f};

    #pragma unroll
    for (int lh = 0; lh < 2; ++lh) {
        int l0 = lh * 64 + 2 * pr, l1 = l0 + 1;
        int lg0 = c * 128 + l0, lg1 = lg0 + 1;
        long row0 = (long)b * L + lg0, row1 = row0 + 1;
        float wl0 = 0.f, wl1 = 0.f, dt0 = 0.f, dt1 = 0.f;
        if (lg0 < L) { wl0 = exp2f(cs2Last - cs[csbase + l0]); dt0 = dtv[row0 * 8 + h]; }
        if (lg1 < L) { wl1 = exp2f(cs2Last - cs[csbase + l1]); dt1 = dtv[row1 * 8 + h]; }

        #pragma unroll
        for (int nb = 0; nb < 2; ++nb) {
            int n0 = grp * 16 + nb * 8;
            float a0[8] = {0,0,0,0,0,0,0,0}, a1[8] = {0,0,0,0,0,0,0,0};
            if (lg0 < L) ld8bf(xbc + row0 * XBCD + 512 + n0, a0);
            if (lg1 < L) ld8bf(xbc + row1 * XBCD + 512 + n0, a1);
            #pragma unroll
            for (int i = 0; i < 8; ++i)
                *(unsigned int*)&At[n0 + i][2 * pr] = pk2(a0[i] * wl0, a1[i] * wl1);
        }
        {
            int p0 = grp * 8;
            float a0[8] = {0,0,0,0,0,0,0,0}, a1[8] = {0,0,0,0,0,0,0,0};
            if (lg0 < L) ld8bf(xbc + row0 * XBCD + h * 64 + p0, a0);
            if (lg1 < L) ld8bf(xbc + row1 * XBCD + h * 64 + p0, a1);
            #pragma unroll
            for (int i = 0; i < 8; ++i)
                *(unsigned int*)&Bt[p0 + i][2 * pr] = pk2(a0[i] * dt0, a1[i] * dt1);
        }
        __syncthreads();

        #pragma unroll
        for (int k0 = 0; k0 < 64; k0 += 32) {
            bf16x8 af[4], bfr[2];
            #pragma unroll
            for (int i = 0; i < 4; ++i)
                af[i] = *(const bf16x8*)&At[wr * 64 + i * 16 + l15][k0 + l4 * 8];
            #pragma unroll
            for (int j = 0; j < 2; ++j)
                bfr[j] = *(const bf16x8*)&Bt[wc * 32 + j * 16 + l15][k0 + l4 * 8];
            #pragma unroll
            for (int i = 0; i < 4; ++i)
                #pragma unroll
                for (int j = 0; j < 2; ++j)
                    acc[i][j] = __builtin_amdgcn_mfma_f32_16x16x32_bf16(
                        af[i], bfr[j], acc[i][j], 0, 0, 0);
        }
        __syncthreads();
    }

    long basep = (long)blockIdx.x * 8192;
    #pragma unroll
    for (int i = 0; i < 4; ++i)
        #pragma unroll
        for (int j = 0; j < 2; ++j) {
            int p = wc * 32 + j * 16 + l15;
            #pragma unroll
            for (int r = 0; r < 4; ++r) {
                int n = wr * 64 + i * 16 + l4 * 4 + r;
                st[basep + n * 64 + p] = f2bf(acc[i][j][r]);
            }
        }
}

// ---------------- inter-chunk scan (4x parallel: 256 blocks/half) ----------------
__global__ __launch_bounds__(256) void k_scan(const float* __restrict__ cs,
                                              u16* __restrict__ st, int bo) {
    int h = blockIdx.x & 7, bl = (blockIdx.x >> 3) & 7, q = blockIdx.x >> 6;
    int b = bo + bl;
    int tid = threadIdx.x;
    float carry[8];
    #pragma unroll
    for (int i = 0; i < 8; ++i) carry[i] = 0.f;
    long csbase = ((long)b * 8 + h) * NC * 128;
    for (int c = 0; c < NC; ++c) {
        float cd = exp2f(cs[csbase + c * 128 + 127]);
        u16* p = st + (((long)bl * NC + c) * 8 + h) * 8192 + q * 2048;
        #pragma unroll
        for (int i = 0; i < 8; ++i) {
            int e = tid + i * 256;
            float v = bf2f(p[e]);
            p[e] = f2bf(carry[i]);
            carry[i] = carry[i] * cd + v;
        }
    }
}

// ---------------- Ydiag + Yoff + D-skip (MFMA, 4 split-K sub-phases) ----------------
__global__ __launch_bounds__(256) void k_yout(u16* __restrict__ xbc,
                                              const float* __restrict__ dtv,
                                              const float* __restrict__ cs,
                                              const u16* __restrict__ cb,
                                              const u16* __restrict__ st,
                                              const float* __restrict__ Dv, int bo) {
    int h = blockIdx.x & 7;
    int c = (blockIdx.x >> 3) % NC;
    int bl = blockIdx.x / (8 * NC);
    int b = bo + bl;
    long bcl = (long)bl * NC + c;
    __shared__ u16 Am[128][72];   // phase1: masked decay CB [l][s-half]; phase2: C*ecs [l][n-half]
    __shared__ u16 Bt[64][72];    // phase1: xw^T [p][s-half]; phase2: prev^T [p][n-half]
    __shared__ float csb[128], ecs[128];
    int tid = threadIdx.x;
    long csbase = (((long)b * 8 + h) * NC + c) * 128;
    if (tid < 128) {
        float v = cs[csbase + tid];
        csb[tid] = v;
        ecs[tid] = exp2f(v);
    }
    __syncthreads();

    int lane = tid & 63, wave = tid >> 6;
    int wr = wave >> 1, wc = wave & 1;
    int l15 = lane & 15, l4 = lane >> 4;
    int lrow = tid >> 1, sh32 = (tid & 1) * 32;
    int pr = tid & 31, grp = tid >> 5;

    f32x4 acc[4][2];
    #pragma unroll
    for (int i = 0; i < 4; ++i)
        #pragma unroll
        for (int j = 0; j < 2; ++j)
            acc[i][j] = (f32x4){0.f, 0.f, 0.f, 0.f};

    // ---- phase 1: Ydiag over two s-halves ----
    #pragma unroll
    for (int sh2 = 0; sh2 < 2; ++sh2) {
        int sbase = sh2 * 64;
        {
            float cl = csb[lrow];
            const u16* cbrow = cb + (bcl * 128 + lrow) * 128 + sbase + sh32;
            #pragma unroll
            for (int sb = 0; sb < 4; ++sb) {
                float a[8];
                ld8bf(cbrow + sb * 8, a);
                #pragma unroll
                for (int i = 0; i < 8; ++i) {
                    int s = sbase + sh32 + sb * 8 + i;
                    float w = (s <= lrow) ? exp2f(cl - csb[s]) : 0.f;
                    a[i] *= w;
                }
                st8bf(&Am[lrow][sh32 + sb * 8], a);
            }
        }
        {
            int l0 = sbase + 2 * pr, l1 = l0 + 1;
            int lg0 = c * 128 + l0, lg1 = lg0 + 1;
            long row0 = (long)b * L + lg0, row1 = row0 + 1;
            float dt0 = 0.f, dt1 = 0.f;
            if (lg0 < L) dt0 = dtv[row0 * 8 + h];
            if (lg1 < L) dt1 = dtv[row1 * 8 + h];
            int p0 = grp * 8;
            float a0[8] = {0,0,0,0,0,0,0,0}, a1[8] = {0,0,0,0,0,0,0,0};
            if (lg0 < L) ld8bf(xbc + row0 * XBCD + h * 64 + p0, a0);
            if (lg1 < L) ld8bf(xbc + row1 * XBCD + h * 64 + p0, a1);
            #pragma unroll
            for (int i = 0; i < 8; ++i)
                *(unsigned int*)&Bt[p0 + i][2 * pr] = pk2(a0[i] * dt0, a1[i] * dt1);
        }
        __syncthreads();
        #pragma unroll
        for (int k0 = 0; k0 < 64; k0 += 32) {
            bf16x8 af[4], bfr[2];
            #pragma unroll
            for (int i = 0; i < 4; ++i)
                af[i] = *(const bf16x8*)&Am[wr * 64 + i * 16 + l15][k0 + l4 * 8];
            #pragma unroll
            for (int j = 0; j < 2; ++j)
                bfr[j] = *(const bf16x8*)&Bt[wc * 32 + j * 16 + l15][k0 + l4 * 8];
            #pragma unroll
            for (int i = 0; i < 4; ++i)
                #pragma unroll
                for (int j = 0; j < 2; ++j)
                    acc[i][j] = __builtin_amdgcn_mfma_f32_16x16x32_bf16(
                        af[i], bfr[j], acc[i][j], 0, 0, 0);
        }
        __syncthreads();
    }

    // ---- phase 2: Yoff over two n-halves ----
    #pragma unroll
    for (int nh2 = 0; nh2 < 2; ++nh2) {
        int nbase = nh2 * 64;
        {
            float el = ecs[lrow];
            int lgr = c * 128 + lrow;
            const u16* xr = xbc + ((long)b * L + lgr) * XBCD + 640 + nbase + sh32;
            #pragma unroll
            for (int sb = 0; sb < 4; ++sb) {
                float a[8] = {0,0,0,0,0,0,0,0};
                if (lgr < L) {
                    ld8bf(xr + sb * 8, a);
                    #pragma unroll
                    for (int i = 0; i < 8; ++i) a[i] *= el;
                }
                st8bf(&Am[lrow][sh32 + sb * 8], a);
            }
        }
        {
            int n0 = nbase + 2 * pr;
            const u16* pv = st + (bcl * 8 + h) * 8192;
            int p0 = grp * 8;
            float a0[8], a1[8];
            ld8bf(pv + (long)n0 * 64 + p0, a0);
            ld8bf(pv + (long)(n0 + 1) * 64 + p0, a1);
            #pragma unroll
            for (int i = 0; i < 8; ++i)
                *(unsigned int*)&Bt[p0 + i][2 * pr] = pk2(a0[i], a1[i]);
        }
        __syncthreads();
        #pragma unroll
        for (int k0 = 0; k0 < 64; k0 += 32) {
            bf16x8 af[4], bfr[2];
            #pragma unroll
            for (int i = 0; i < 4; ++i)
                af[i] = *(const bf16x8*)&Am[wr * 64 + i * 16 + l15][k0 + l4 * 8];
            #pragma unroll
            for (int j = 0; j < 2; ++j)
                bfr[j] = *(const bf16x8*)&Bt[wc * 32 + j * 16 + l15][k0 + l4 * 8];
            #pragma unroll
            for (int i = 0; i < 4; ++i)
                #pragma unroll
                for (int j = 0; j < 2; ++j)
                    acc[i][j] = __builtin_amdgcn_mfma_f32_16x16x32_bf16(
                        af[i], bfr[j], acc[i][j], 0, 0, 0);
        }
        __syncthreads();
    }

    // epilogue: + D*xh, overwrite x-part in place
    float Dh = Dv[h];
    #pragma unroll
    for (int i = 0; i < 4; ++i)
        #pragma unroll
        for (int r = 0; r < 4; ++r) {
            int l = wr * 64 + i * 16 + l4 * 4 + r;
            int lg = c * 128 + l;
            if (lg >= L) continue;
            long row = (long)b * L + lg;
            #pragma unroll
            for (int j = 0; j < 2; ++j) {
                int p = wc * 32 + j * 16 + l15;
                u16* xp = xbc + row * XBCD + h * 64 + p;
                float xv = bf2f(*xp);
                *xp = f2bf(fmaf(Dh, xv, acc[i][j][r]));
            }
        }
}

// ---------------- gated RMSNorm (wave per row) ----------------
__global__ __launch_bounds__(256) void k_rmsnorm(u16* __restrict__ y,
                                                 const u16* __restrict__ z,
                                                 const float* __restrict__ nw) {
    int wave = threadIdx.x >> 6, lane = threadIdx.x & 63;
    long r = (long)blockIdx.x * 4 + wave;     // 9996 blocks exact
    int c0 = lane * 8;
    float v[8], zv[8];
    ld8bf(y + r * XBCD + c0, v);
    ld8bf(z + r * DIN + c0, zv);
    float ss = 0.f;
    #pragma unroll
    for (int j = 0; j < 8; ++j) {
        v[j] *= siluf(zv[j]);
        ss += v[j] * v[j];
    }
    #pragma unroll
    for (int off = 32; off > 0; off >>= 1) ss += __shfl_xor(ss, off, 64);
    float sc = rsqrtf(ss / 512.f + 1e-5f);
    float4 w0 = *(const float4*)(nw + c0);
    float4 w1 = *(const float4*)(nw + c0 + 4);
    v[0] *= sc * w0.x; v[1] *= sc * w0.y; v[2] *= sc * w0.z; v[3] *= sc * w0.w;
    v[4] *= sc * w1.x; v[5] *= sc * w1.y; v[6] *= sc * w1.z; v[7] *= sc * w1.w;
    st8bf(y + r * XBCD + c0, v);
}

// ---------------- repack conv1_w ----------------
__global__ __launch_bounds__(256) void k_wpack(const float* __restrict__ w,
                                               u16* __restrict__ wp) {
    int idx = blockIdx.x * 256 + threadIdx.x;
    if (idx >= 8 * 256 * 16) return;
    int k = idx & 15;
    int cidx = (idx >> 4) & 255;
    int s = idx >> 12;
    wp[(s * 16 + k) * 256 + cidx] = f2bf(w[idx]);
}

// ---------------- conv1 combine (LDS-tiled, coalesced G reads) ----------------
// grid: b*20 + tile; G tile [143][128] staged in LDS (rows l0-7 .. l0+135)
__global__ __launch_bounds__(256) void k_conv1(const u16* __restrict__ G,
                                               const float* __restrict__ bias,
                                               u16* __restrict__ f) {
    int t = blockIdx.x % 20, b = blockIdx.x / 20;
    int l0 = t * 128;
    __shared__ u16 Gs[143][136];   // 136-u16 row stride: 16B-aligned, mild bank aliasing
    int tid = threadIdx.x;
    for (int c = tid; c < 143 * 16; c += 256) {
        int r = c >> 4, col8 = (c & 15) * 8;
        int lg = l0 - 7 + r;
        uint4 v = {0, 0, 0, 0};
        if (lg >= 0 && lg < L)
            v = *(const uint4*)(G + ((long)b * L + lg) * 128 + col8);
        *(uint4*)&Gs[r][col8] = v;
    }
    __syncthreads();
    int s = tid >> 5, li0 = tid & 31;
    float bs = bias[s];
    #pragma unroll
    for (int q = 0; q < 4; ++q) {
        int li = li0 + q * 32;
        int l = l0 + li;
        if (l >= L) continue;
        float acc = bs;
        #pragma unroll
        for (int k = 0; k < 16; ++k)
            acc += bf2f(Gs[li + k][s * 16 + k]);   // LDS row li+k = global l+(k-7)
        f[(long)b * FLATP + s * L + l] = f2bf(acc);
    }
    if (t == 19 && tid < 8)
        f[(long)b * FLATP + FLAT + tid] = 0;       // zero MFMA K-pad
}

// ---------------- MLP1: o1acc[16][512] += f[16][20000] @ w1b[512][20000]^T (MFMA) ----------------
__global__ __launch_bounds__(256) void k_mlp1(const u16* __restrict__ fb,
                                              const u16* __restrict__ w1b,
                                              float* __restrict__ o1acc) {
    int wave = threadIdx.x >> 6, lane = threadIdx.x & 63;
    int l15 = lane & 15, l4 = lane >> 4;
    int n0 = blockIdx.x * 64 + wave * 16;     // 8 x-blocks
    int k0 = blockIdx.y * 800;                // 25 y-blocks
    const u16* fp = fb + (long)l15 * FLATP + k0 + l4 * 8;
    const u16* wp = w1b + (long)(n0 + l15) * FLATP + k0 + l4 * 8;
    f32x4 acc = (f32x4){0.f, 0.f, 0.f, 0.f};
    #pragma unroll
    for (int kk = 0; kk < 25; ++kk) {
        bf16x8 af = *(const bf16x8*)fp;
        bf16x8 bf = *(const bf16x8*)wp;
        acc = __builtin_amdgcn_mfma_f32_16x16x32_bf16(af, bf, acc, 0, 0, 0);
        fp += 32; wp += 32;
    }
    #pragma unroll
    for (int r = 0; r < 4; ++r) {
        int b = l4 * 4 + r;
        atomicAdd(&o1acc[b * 512 + n0 + l15], acc[r]);
    }
}

__global__ __launch_bounds__(256) void k_mlp1fin(const float* __restrict__ o1acc,
                                                 const float* __restrict__ b1,
                                                 float* __restrict__ o1) {
    int i = blockIdx.x * 256 + threadIdx.x;   // 32 blocks, 8192 elems
    o1[i] = fmaxf(o1acc[i] + b1[i & 511], 0.f);
}

__global__ __launch_bounds__(256) void k_mlp2(const float* __restrict__ in,
                                              const float* __restrict__ w,
                                              const float* __restrict__ bias,
                                              float* __restrict__ out) {
    int b = blockIdx.x, n = threadIdx.x;
    const float* ir = in + b * 512;
    const float* wr = w + (long)n * 512;
    float acc = 0.f;
    for (int k = 0; k < 512; ++k) acc = fmaf(ir[k], wr[k], acc);
    out[b * 256 + n] = fmaxf(acc + bias[n], 0.f);
}

__global__ __launch_bounds__(64) void k_mlp3(const float* __restrict__ in,
                                             const float* __restrict__ w,
                                             const float* __restrict__ bias,
                                             float* __restrict__ out) {
    int b = blockIdx.x, n = threadIdx.x;
    const float* ir = in + b * 256;
    const float* wr = w + (long)n * 256;
    float acc = 0.f;
    for (int k = 0; k < 256; ++k) acc = fmaf(ir[k], wr[k], acc);
    out[b * 64 + n] = fmaxf(acc + bias[n], 0.f);
}

__global__ __launch_bounds__(64) void k_mlp4(const float* __restrict__ in,
                                             const float* __restrict__ w4,
                                             const float* __restrict__ b4,
                                             float* __restrict__ dout) {
    int b = blockIdx.x, k = threadIdx.x;
    float v = in[b * 64 + k] * w4[k];
    #pragma unroll
    for (int off = 32; off > 0; off >>= 1) v += __shfl_down(v, off);
    if (k == 0) dout[b] = v + b4[0];
}

// ---------------- host launcher ----------------
extern "C" void kernel_launch(void* const* d_in, const int* in_sizes, int n_in,
                              void* d_out, int out_size, void* d_ws, size_t ws_size,
                              hipStream_t stream) {
    (void)in_sizes; (void)n_in; (void)out_size;
    if (ws_size < WS_NEEDED) return;

    const float* x         = (const float*)d_in[0];
    const float* conv_w    = (const float*)d_in[1];
    // conv_b (d_in[2]) cancels under batch-stat BN — unused
    const float* bn_w      = (const float*)d_in[3];
    const float* bn_b      = (const float*)d_in[4];
    const float* in_proj_w = (const float*)d_in[5];
    const float* conv1d_w  = (const float*)d_in[6];
    const float* conv1d_b  = (const float*)d_in[7];
    const float* dt_bias   = (const float*)d_in[8];
    const float* A_log     = (const float*)d_in[9];
    const float* Dp        = (const float*)d_in[10];
    const float* norm_w    = (const float*)d_in[11];
    const float* out_proj_w= (const float*)d_in[12];
    const float* conv1_w   = (const float*)d_in[13];
    const float* conv1_b   = (const float*)d_in[14];
    const float* w1 = (const float*)d_in[15]; const float* b1 = (const float*)d_in[16];
    const float* w2 = (const float*)d_in[17]; const float* b2 = (const float*)d_in[18];
    const float* w3 = (const float*)d_in[19]; const float* b3 = (const float*)d_in[20];
    const float* w4 = (const float*)d_in[21]; const float* b4 = (const float*)d_in[22];

    char* base = (char*)d_ws;
    float* dtv  = (float*)(base + S_DTV);
    float* cs   = (float*)(base + S_CS);
    float* sums = (float*)(base + S_STAT);
    float* sumsq= sums + 256;
    float* scale= sums + 512;
    float* shift= sums + 768;
    u16*   cwbf = (u16*)(base + S_WPK);
    u16*   wbf  = (u16*)(base + S_HALO);
    u16*   halo = (u16*)(base + S_HALO);
    u16*   ht   = (u16*)(base + OFF_HT);
    u16*   xbc  = (u16*)(base + OFF_XBC);
    u16*   cb   = (u16*)(base + OFF_CBST + CB_OFF);
    u16*   st   = (u16*)(base + OFF_CBST + ST_OFF);
    u16*   zb   = (u16*)(base + OFF_CBST + Z_OFF);
    u16*   G    = (u16*)(base + OFF_XBC);
    u16*   fbuf = (u16*)(base + OFF_CBST + F_OFF);
    float* o1a  = (float*)(base + OFF_CBST + O1A_OFF);
    float* o1   = (float*)(base + OFF_CBST + O1_OFF);
    float* o2   = (float*)(base + OFF_CBST + O2_OFF);
    float* o3   = (float*)(base + OFF_CBST + O3_OFF);
    u16*   w1b  = (u16*)(base + OFF_CBST + W1B_OFF);
    u16*   yproj= ht;

    // 1-2. stem conv as fused-im2col MFMA GEMM
    k_wcvt<<<64, 256, 0, stream>>>(conv_w, cwbf, 256 * 64);
    gemm_mfma<true, true><<<dim3(313, 2), 256, 0, stream>>>(
        x, cwbf, ht, (int)ROWS, 256, 64, 0, 256);

    // 3. BN batch stats + in-place BN+ReLU
    k_zero<<<2, 256, 0, stream>>>(sums, 512);
    k_bnstats<<<256, 256, 0, stream>>>(ht, sums, sumsq);
    k_bnfinal<<<1, 256, 0, stream>>>(sums, sumsq, bn_w, bn_b, scale, shift);
    k_bnapply<<<4998, 256, 0, stream>>>(ht, scale, shift);

    // 4. xBC projection (MFMA); dt projection
    k_wcvt<<<768, 256, 0, stream>>>(in_proj_w + 512L * 256, wbf, 768 * 256);
    gemm_mfma<false, true><<<dim3(313, 6), 256, 0, stream>>>(
        ht, wbf, xbc, (int)ROWS, 768, 256, 256, 768);
    k_dtproj<<<1250, 256, 0, stream>>>(ht, in_proj_w, dt_bias, dtv);

    // 5. in-place depthwise conv + SiLU; cumsum (scaled by log2e)
    k_halo<<<2736, 256, 0, stream>>>(xbc, halo);
    k_dwip<<<960, 256, 0, stream>>>(xbc, halo, conv1d_w, conv1d_b);
    k_cs<<<2560, 128, 0, stream>>>(dtv, A_log, cs);

    // 6. SSD in two half-batches (all MFMA)
    for (int bh = 0; bh < 2; ++bh) {
        int bo = bh * 8;
        k_cb<<<160, 256, 0, stream>>>(xbc, cb, bo);
        k_states<<<1280, 256, 0, stream>>>(xbc, dtv, cs, st, bo);
        k_scan<<<256, 256, 0, stream>>>(cs, st, bo);
        k_yout<<<1280, 256, 0, stream>>>(xbc, dtv, cs, cb, st, Dp, bo);
    }

    // 6.9. z projection (MFMA)
    k_wcvt<<<512, 256, 0, stream>>>(in_proj_w, wbf, 512 * 256);
    gemm_mfma<false, true><<<dim3(313, 4), 256, 0, stream>>>(
        ht, wbf, zb, (int)ROWS, 512, 256, 256, 512);

    // 7-8. gated RMSNorm + out_proj (MFMA)
    k_rmsnorm<<<9996, 256, 0, stream>>>(xbc, zb, norm_w);
    k_wcvt<<<512, 256, 0, stream>>>(out_proj_w, wbf, 256 * 512);
    gemm_mfma<false, true><<<dim3(313, 2), 256, 0, stream>>>(
        xbc, wbf, yproj, (int)ROWS, 256, 512, 768, 256);

    // 9. conv1 as MFMA GEMM (G bf16) + LDS-tiled gather (fbuf bf16 padded)
    k_wpack<<<128, 256, 0, stream>>>(conv1_w, wbf);
    gemm_mfma<false, true><<<dim3(313, 1), 256, 0, stream>>>(
        yproj, wbf, G, (int)ROWS, 128, 256, 256, 128);
    k_conv1<<<320, 256, 0, stream>>>(G, conv1_b, fbuf);

    // 10. MLP head (mlp1 as bf16 MFMA split-K)
    k_w1cvt<<<5000, 256, 0, stream>>>(w1, w1b);
    k_zero<<<32, 256, 0, stream>>>(o1a, 8192);
    k_mlp1<<<dim3(8, 25), 256, 0, stream>>>(fbuf, w1b, o1a);
    k_mlp1fin<<<32, 256, 0, stream>>>(o1a, b1, o1);
    k_mlp2<<<16, 256, 0, stream>>>(o1, w2, b2, o2);
    k_mlp3<<<16, 64, 0, stream>>>(o2, w3, b3, o3);
    k_mlp4<<<16, 64, 0, stream>>>(o3, w4, b4, (float*)d_out);
}